// Round 1
// baseline (1592.916 us; speedup 1.0000x reference)
//
#include <hip/hip_runtime.h>

#define B_ 2
#define L_ 2048
#define HID_ 1024
#define H_ 4
#define D_ 256
#define NTOK 4096
#define CH 32
#define NCH 64

// ---------------------------------------------------------------------------
// Tiled fp32 GEMM: C[M][N] = act(A[M][K] @ W[N][K]^T + bias)
// Requires M%128==0, N%128==0, K%16==0.
// ACT: 0 = none, 1 = bias + exact GELU
// ---------------------------------------------------------------------------
template<int ACT>
__global__ __launch_bounds__(256)
void gemm128(const float* __restrict__ A, const float* __restrict__ W,
             const float* __restrict__ bias, float* __restrict__ C,
             int M, int N, int K)
{
  __shared__ float As[16][132];
  __shared__ float Bs[16][132];
  const int tid = threadIdx.x;
  const int n0 = blockIdx.x * 128;
  const int m0 = blockIdx.y * 128;
  const int lr = tid >> 2;          // 0..63
  const int lk = (tid & 3) << 2;    // 0,4,8,12
  const int tr = (tid >> 4) << 3;   // 0..120
  const int tc = (tid & 15) << 3;   // 0..120

  float acc[8][8];
#pragma unroll
  for (int i = 0; i < 8; i++)
#pragma unroll
    for (int j = 0; j < 8; j++) acc[i][j] = 0.f;

  for (int k0 = 0; k0 < K; k0 += 16) {
    float4 a0 = *(const float4*)(A + (long)(m0 + lr) * K + k0 + lk);
    float4 a1 = *(const float4*)(A + (long)(m0 + lr + 64) * K + k0 + lk);
    float4 b0 = *(const float4*)(W + (long)(n0 + lr) * K + k0 + lk);
    float4 b1 = *(const float4*)(W + (long)(n0 + lr + 64) * K + k0 + lk);
    __syncthreads();   // previous compute must finish before LDS overwrite
    As[lk + 0][lr] = a0.x; As[lk + 1][lr] = a0.y; As[lk + 2][lr] = a0.z; As[lk + 3][lr] = a0.w;
    As[lk + 0][lr + 64] = a1.x; As[lk + 1][lr + 64] = a1.y; As[lk + 2][lr + 64] = a1.z; As[lk + 3][lr + 64] = a1.w;
    Bs[lk + 0][lr] = b0.x; Bs[lk + 1][lr] = b0.y; Bs[lk + 2][lr] = b0.z; Bs[lk + 3][lr] = b0.w;
    Bs[lk + 0][lr + 64] = b1.x; Bs[lk + 1][lr + 64] = b1.y; Bs[lk + 2][lr + 64] = b1.z; Bs[lk + 3][lr + 64] = b1.w;
    __syncthreads();
#pragma unroll
    for (int kk = 0; kk < 16; kk++) {
      float4 x0 = *(const float4*)&As[kk][tr];
      float4 x1 = *(const float4*)&As[kk][tr + 4];
      float4 y0 = *(const float4*)&Bs[kk][tc];
      float4 y1 = *(const float4*)&Bs[kk][tc + 4];
      float xa[8] = {x0.x, x0.y, x0.z, x0.w, x1.x, x1.y, x1.z, x1.w};
      float yb[8] = {y0.x, y0.y, y0.z, y0.w, y1.x, y1.y, y1.z, y1.w};
#pragma unroll
      for (int i = 0; i < 8; i++)
#pragma unroll
        for (int j = 0; j < 8; j++)
          acc[i][j] = fmaf(xa[i], yb[j], acc[i][j]);
    }
  }

#pragma unroll
  for (int i = 0; i < 8; i++) {
    float out[8];
#pragma unroll
    for (int j = 0; j < 8; j++) {
      float v = acc[i][j];
      if (ACT == 1) {
        v += bias[n0 + tc + j];
        v = 0.5f * v * (1.f + erff(v * 0.70710678118654752f));
      }
      out[j] = v;
    }
    float4* cp = (float4*)(C + (long)(m0 + tr + i) * N + n0 + tc);
    cp[0] = make_float4(out[0], out[1], out[2], out[3]);
    cp[1] = make_float4(out[4], out[5], out[6], out[7]);
  }
}

// ---------------------------------------------------------------------------
// Depthwise causal conv (K=4) + SiLU.  x,y: [NTOK][HID], w: [HID][4]
// ---------------------------------------------------------------------------
__global__ __launch_bounds__(256)
void conv4_silu(const float* __restrict__ x, const float* __restrict__ w4,
                float* __restrict__ y)
{
  int id = blockIdx.x * 256 + threadIdx.x;
  int c = id & (HID_ - 1);
  int tok = id >> 10;
  int l = tok & (L_ - 1);
  float s = 0.f;
#pragma unroll
  for (int t = 0; t < 4; t++) {
    int lt = l - 3 + t;
    if (lt >= 0) s += x[(long)(tok - 3 + t) * HID_ + c] * w4[c * 4 + t];
  }
  y[id] = s / (1.f + expf(-s));
}

// ---------------------------------------------------------------------------
// beta = sigmoid(hs @ b_w^T): [NTOK][4]
// ---------------------------------------------------------------------------
__global__ __launch_bounds__(256)
void beta_proj(const float* __restrict__ hs, const float* __restrict__ bw,
               float* __restrict__ beta)
{
  int id = blockIdx.x * 256 + threadIdx.x;   // < NTOK*H_
  int h = id & 3;
  int tok = id >> 2;
  const float4* a = (const float4*)(hs + (long)tok * HID_);
  const float4* w = (const float4*)(bw + (long)h * HID_);
  float s = 0.f;
  for (int k = 0; k < HID_ / 4; k++) {
    float4 av = a[k], wv = w[k];
    s += av.x * wv.x + av.y * wv.y + av.z * wv.z + av.w * wv.w;
  }
  beta[id] = 1.f / (1.f + expf(-s));
}

// ---------------------------------------------------------------------------
// g1 weight pad: [2048][1084] -> [2048][1088] (zero fill)
// ---------------------------------------------------------------------------
__global__ __launch_bounds__(256)
void pad_g1w(const float* __restrict__ g1w, float* __restrict__ out)
{
  int id = blockIdx.x * 256 + threadIdx.x;   // < 2048*1088
  int k = id % 1088;
  int n = id / 1088;
  out[id] = (k < 1084) ? g1w[(long)n * 1084 + k] : 0.f;
}

// ---------------------------------------------------------------------------
// Delta-rule chunk prep: per (b,h,chunk): l2norm q/k, A, (I+A)^-1, u, w, attn
// ---------------------------------------------------------------------------
__global__ __launch_bounds__(256)
void delta_prep(const float* __restrict__ qc, const float* __restrict__ kc,
                const float* __restrict__ vc, const float* __restrict__ beta,
                float* __restrict__ qn, float* __restrict__ kn,
                float* __restrict__ ub, float* __restrict__ wb,
                float* __restrict__ attnb)
{
  __shared__ float qs[CH][260], ks[CH][260], vs[CH][260];
  __shared__ float Xs[CH][33], As[CH][33];
  __shared__ float red[CH][8];
  __shared__ float bet[CH], nf[CH];

  int bid = blockIdx.x;
  int ci = bid & 63, h = (bid >> 6) & 3, b = bid >> 8;
  int tid = threadIdx.x;
  long tok0 = (long)b * L_ + (long)ci * CH;
  const float* qsrc = qc + tok0 * HID_ + h * D_;
  const float* ksrc = kc + tok0 * HID_ + h * D_;
  const float* vsrc = vc + tok0 * HID_ + h * D_;
  int lr = tid >> 6;           // 0..3
  int dd = (tid & 63) << 2;    // 0..252

#pragma unroll
  for (int it = 0; it < 8; it++) {
    int row = lr + it * 4;
    *(float4*)&qs[row][dd] = *(const float4*)(qsrc + (long)row * HID_ + dd);
    *(float4*)&ks[row][dd] = *(const float4*)(ksrc + (long)row * HID_ + dd);
    *(float4*)&vs[row][dd] = *(const float4*)(vsrc + (long)row * HID_ + dd);
  }
  if (tid < CH) bet[tid] = beta[(tok0 + tid) * H_ + h];
  __syncthreads();

  // q row norms
  {
    int c = tid >> 3, p = tid & 7;
    float s = 0.f;
    for (int d = p * 32; d < p * 32 + 32; d++) { float v = qs[c][d]; s += v * v; }
    red[c][p] = s;
  }
  __syncthreads();
  if (tid < CH) {
    float s = 0.f;
    for (int p = 0; p < 8; p++) s += red[tid][p];
    nf[tid] = rsqrtf(s + 1e-6f);
  }
  __syncthreads();
#pragma unroll
  for (int it = 0; it < 8; it++) {
    int row = lr + it * 4;
    float f = nf[row];
    qs[row][dd] *= f; qs[row][dd + 1] *= f; qs[row][dd + 2] *= f; qs[row][dd + 3] *= f;
  }
  // k row norms (reuse red/nf; qs scaling above reads nf before the next sync)
  {
    int c = tid >> 3, p = tid & 7;
    float s = 0.f;
    for (int d = p * 32; d < p * 32 + 32; d++) { float v = ks[c][d]; s += v * v; }
    red[c][p] = s;
  }
  __syncthreads();
  if (tid < CH) {
    float s = 0.f;
    for (int p = 0; p < 8; p++) s += red[tid][p];
    nf[tid] = rsqrtf(s + 1e-6f);
  }
  __syncthreads();
#pragma unroll
  for (int it = 0; it < 8; it++) {
    int row = lr + it * 4;
    float f = nf[row];
    ks[row][dd] *= f; ks[row][dd + 1] *= f; ks[row][dd + 2] *= f; ks[row][dd + 3] *= f;
  }
  __syncthreads();

  // A = stril(beta_i * kn_i . kn_j),  attn = tril(qn_i . kn_j)
  long abase = ((long)(b * H_ + h) * NCH + ci) * (CH * CH);
#pragma unroll 1
  for (int r = 0; r < 4; r++) {
    int oid = tid + 256 * r;
    int i = oid >> 5, j = oid & 31;
    float skk = 0.f, sqk = 0.f;
    for (int d = 0; d < D_; d += 4) {
      float4 ki = *(const float4*)&ks[i][d];
      float4 kj = *(const float4*)&ks[j][d];
      float4 qi = *(const float4*)&qs[i][d];
      skk += ki.x * kj.x + ki.y * kj.y + ki.z * kj.z + ki.w * kj.w;
      sqk += qi.x * kj.x + qi.y * kj.y + qi.z * kj.z + qi.w * kj.w;
    }
    As[i][j] = (j < i) ? bet[i] * skk : 0.f;
    attnb[abase + oid] = (j <= i) ? sqk : 0.f;
  }
  __syncthreads();

  // X = (I+A)^{-1}, unit lower triangular; column-independent forward subst.
  if (tid < CH) {
    int j = tid;
    for (int i = 0; i < CH; i++) {
      if (i < j) { Xs[i][j] = 0.f; continue; }
      float x = (i == j) ? 1.f : 0.f;
      for (int m = j; m < i; m++) x -= As[i][m] * Xs[m][j];
      Xs[i][j] = x;
    }
  }
  __syncthreads();

  // fold beta into X: As[c][m] = X[c][m] * beta[m]
#pragma unroll
  for (int r = 0; r < 4; r++) {
    int oid = tid + 256 * r;
    int i = oid >> 5, m = oid & 31;
    As[i][m] = Xs[i][m] * bet[m];
  }
  __syncthreads();

  long cbase = ((long)(b * H_ + h) * NCH + ci) * (CH * D_);
#pragma unroll 1
  for (int c = 0; c < CH; c++) {
    float su = 0.f, sw = 0.f;
    for (int m = 0; m < CH; m++) {
      float xm = As[c][m];
      su = fmaf(xm, vs[m][tid], su);
      sw = fmaf(xm, ks[m][tid], sw);
    }
    ub[cbase + c * D_ + tid] = su;
    wb[cbase + c * D_ + tid] = sw;
  }
#pragma unroll 1
  for (int i = 0; i < CH; i++) {
    qn[cbase + i * D_ + tid] = qs[i][tid];
    kn[cbase + i * D_ + tid] = ks[i][tid];
  }
}

// ---------------------------------------------------------------------------
// Delta-rule scan: block = (b,h,slice of 8 dv cols); sequential over chunks.
// ---------------------------------------------------------------------------
__global__ __launch_bounds__(256)
void delta_scan(const float* __restrict__ qn, const float* __restrict__ kn,
                const float* __restrict__ ub, const float* __restrict__ wb,
                const float* __restrict__ attnb, float* __restrict__ dout)
{
  __shared__ float ST[8][260];       // S transposed: ST[j][dk]
  __shared__ float wch[CH][260], qch[CH][260], kch[CH][260];
  __shared__ float att[CH][33];
  __shared__ float ua[CH][8];
  __shared__ float usl[CH][8];

  int bid = blockIdx.x;
  int sl = bid & 31, h = (bid >> 5) & 3, b = bid >> 7;
  int tid = threadIdx.x;
  int J0 = sl * 8;
  long bh = (long)(b * H_ + h);

  for (int i = tid; i < 8 * 260; i += 256) (&ST[0][0])[i] = 0.f;

  int lr = tid >> 6;
  int dd = (tid & 63) << 2;
  int c = tid >> 3, j = tid & 7;

  for (int ci = 0; ci < NCH; ci++) {
    long cb = (bh * NCH + ci) * (CH * D_);
    const float* qg = qn + cb;
    const float* kg = kn + cb;
    const float* wg = wb + cb;
#pragma unroll
    for (int it = 0; it < 8; it++) {
      int row = lr + it * 4;
      *(float4*)&qch[row][dd] = *(const float4*)(qg + row * D_ + dd);
      *(float4*)&kch[row][dd] = *(const float4*)(kg + row * D_ + dd);
      *(float4*)&wch[row][dd] = *(const float4*)(wg + row * D_ + dd);
    }
    long ab = (bh * NCH + ci) * (CH * CH);
#pragma unroll
    for (int r = 0; r < 4; r++) {
      int oid = tid + 256 * r;
      att[oid >> 5][oid & 31] = attnb[ab + oid];
    }
    usl[c][j] = ub[cb + c * D_ + J0 + j];
    __syncthreads();

    // phase A: aw = w_c . S_j ; aq = q_c . S_j
    float aw = 0.f, aq = 0.f;
#pragma unroll 4
    for (int d = 0; d < D_; d += 4) {
      float4 sv = *(const float4*)&ST[j][d];
      float4 wv = *(const float4*)&wch[c][d];
      float4 qv = *(const float4*)&qch[c][d];
      aw += sv.x * wv.x + sv.y * wv.y + sv.z * wv.z + sv.w * wv.w;
      aq += sv.x * qv.x + sv.y * qv.y + sv.z * qv.z + sv.w * qv.w;
    }
    ua[c][j] = usl[c][j] - aw;
    __syncthreads();

    // phase B: o = aq + attn_c . ua_j
    float o = aq;
#pragma unroll
    for (int m = 0; m < CH; m++) o = fmaf(att[c][m], ua[m][j], o);
    dout[((long)b * L_ + ci * CH + c) * HID_ + h * D_ + J0 + j] = o;

    // phase C: S[dk=tid][0..7] += sum_c kn[c][dk] * ua[c][j]
    float acc2[8] = {0.f, 0.f, 0.f, 0.f, 0.f, 0.f, 0.f, 0.f};
#pragma unroll 1
    for (int cc = 0; cc < CH; cc++) {
      float kv = kch[cc][tid];
      float4 u0 = *(const float4*)&ua[cc][0];
      float4 u1 = *(const float4*)&ua[cc][4];
      acc2[0] = fmaf(kv, u0.x, acc2[0]); acc2[1] = fmaf(kv, u0.y, acc2[1]);
      acc2[2] = fmaf(kv, u0.z, acc2[2]); acc2[3] = fmaf(kv, u0.w, acc2[3]);
      acc2[4] = fmaf(kv, u1.x, acc2[4]); acc2[5] = fmaf(kv, u1.y, acc2[5]);
      acc2[6] = fmaf(kv, u1.z, acc2[6]); acc2[7] = fmaf(kv, u1.w, acc2[7]);
    }
#pragma unroll
    for (int jj = 0; jj < 8; jj++) ST[jj][tid] += acc2[jj];
    __syncthreads();
  }
}

// ---------------------------------------------------------------------------
// Fused 3-FIR depthwise causal conv on v (K=3,31,64). Tile 32 tok x 64 ch.
// ---------------------------------------------------------------------------
__global__ __launch_bounds__(256)
void fir3(const float* __restrict__ v, const float* __restrict__ fs_g,
          const float* __restrict__ fl_g, const float* __restrict__ fw_g,
          float* __restrict__ os, float* __restrict__ ol, float* __restrict__ ow)
{
  __shared__ float xs[95][64];
  __shared__ float fs[64][3];
  __shared__ float fl[64][31];
  __shared__ float fw[64][65];
  int bid = blockIdx.x;
  int ct = bid & 15, lt = bid >> 4;
  int c0 = ct * 64, tok0 = lt * 32;
  int bstart = (tok0 / L_) * L_;
  int tid = threadIdx.x;

  for (int idx = tid; idx < 95 * 64; idx += 256) {
    int r = idx >> 6, cc = idx & 63;
    int tok = tok0 - 63 + r;
    xs[r][cc] = (tok >= bstart) ? v[(long)tok * HID_ + c0 + cc] : 0.f;
  }
  for (int idx = tid; idx < 64 * 3; idx += 256) fs[idx / 3][idx % 3] = fs_g[(long)(c0 + idx / 3) * 3 + idx % 3];
  for (int idx = tid; idx < 64 * 31; idx += 256) fl[idx / 31][idx % 31] = fl_g[(long)(c0 + idx / 31) * 31 + idx % 31];
  for (int idx = tid; idx < 64 * 64; idx += 256) fw[idx >> 6][idx & 63] = fw_g[(long)(c0 + (idx >> 6)) * 64 + (idx & 63)];
  __syncthreads();

  int cc = tid & 63, lq = tid >> 6;    // wave-aligned: lane = cc
  int rb = lq * 8;
  float as8[8] = {0}, al8[8] = {0}, aw8[8] = {0};
#pragma unroll 1
  for (int t = 0; t < 64; t++) {
    float fv = fw[cc][t];
#pragma unroll
    for (int i = 0; i < 8; i++) aw8[i] = fmaf(xs[rb + i + t][cc], fv, aw8[i]);
  }
#pragma unroll 1
  for (int t = 0; t < 31; t++) {
    float fv = fl[cc][t];
#pragma unroll
    for (int i = 0; i < 8; i++) al8[i] = fmaf(xs[rb + 33 + i + t][cc], fv, al8[i]);
  }
#pragma unroll 1
  for (int t = 0; t < 3; t++) {
    float fv = fs[cc][t];
#pragma unroll
    for (int i = 0; i < 8; i++) as8[i] = fmaf(xs[rb + 61 + i + t][cc], fv, as8[i]);
  }
#pragma unroll
  for (int i = 0; i < 8; i++) {
    long o = (long)(tok0 + lq * 8 + i) * HID_ + c0 + cc;
    os[o] = as8[i]; ol[o] = al8[i]; ow[o] = aw8[i];
  }
}

// ---------------------------------------------------------------------------
// gate_in = [hs | stats(short) | stats(long) | stats(wide) | stats(delta) | stats(v)]
// row stride 1088 (cols 1084..1087 zeroed)
// ---------------------------------------------------------------------------
__global__ __launch_bounds__(256)
void build_gate(const float* __restrict__ hs, const float* __restrict__ sb,
                const float* __restrict__ lb, const float* __restrict__ wbb,
                const float* __restrict__ db, const float* __restrict__ vb,
                float* __restrict__ gate)
{
  int tok = blockIdx.x;
  int tid = threadIdx.x;
  float* g = gate + (long)tok * 1088;
  const float* hrow = hs + (long)tok * HID_;
#pragma unroll
  for (int i = 0; i < 4; i++) g[tid + 256 * i] = hrow[tid + 256 * i];
  if (tid < 4) g[1084 + tid] = 0.f;
  int h = tid >> 6, ln = tid & 63;
  const float* brs[5] = {sb, lb, wbb, db, vb};
#pragma unroll
  for (int bi = 0; bi < 5; bi++) {
    const float* x = brs[bi] + (long)tok * HID_ + h * D_;
    float s = 0.f, ss = 0.f, mx = 0.f;
#pragma unroll
    for (int i = 0; i < 4; i++) {
      float v = x[ln + 64 * i];
      s += v; ss += v * v; mx = fmaxf(mx, fabsf(v));
    }
#pragma unroll
    for (int off = 32; off >= 1; off >>= 1) {
      s += __shfl_xor(s, off);
      ss += __shfl_xor(ss, off);
      mx = fmaxf(mx, __shfl_xor(mx, off));
    }
    if (ln == 0) {
      g[1024 + bi * 12 + h] = s * (1.f / 256.f);
      g[1024 + bi * 12 + 4 + h] = sqrtf(fmaxf(ss * (1.f / 256.f), 1e-8f));
      g[1024 + bi * 12 + 8 + h] = mx;
    }
  }
}

// ---------------------------------------------------------------------------
// Fused g2 (4096x20x2048) + softmax/temperature/floor mix + per-head RMSNorm
// ---------------------------------------------------------------------------
__global__ __launch_bounds__(256)
void g2_mix(const float* __restrict__ hdn, const float* __restrict__ g2w,
            const float* __restrict__ g2b, const float* __restrict__ vbias,
            const float* __restrict__ ltemp, const float* __restrict__ flog,
            const float* __restrict__ onw,
            const float* __restrict__ sb, const float* __restrict__ lb,
            const float* __restrict__ wbb, const float* __restrict__ db,
            const float* __restrict__ vb, float* __restrict__ omix)
{
  __shared__ float hrow[2048];
  __shared__ float lg[20];
  int tok = blockIdx.x;
  int tid = threadIdx.x;
  const float* hp = hdn + (long)tok * 2048;
#pragma unroll
  for (int i = 0; i < 8; i++) hrow[tid + 256 * i] = hp[tid + 256 * i];
  __syncthreads();
  int w = tid >> 6, ln = tid & 63;
#pragma unroll 1
  for (int q = 0; q < 5; q++) {
    int jj = w * 5 + q;
    const float* wr = g2w + (long)jj * 2048;
    float s = 0.f;
    for (int i = 0; i < 32; i++) s += hrow[ln + 64 * i] * wr[ln + 64 * i];
#pragma unroll
    for (int off = 32; off >= 1; off >>= 1) s += __shfl_xor(s, off);
    if (ln == 0) lg[jj] = s + g2b[jj];
  }
  __syncthreads();
  int h = w;
  float l[5];
#pragma unroll
  for (int j = 0; j < 5; j++) l[j] = lg[h * 5 + j];
  l[4] += vbias[h];
  float it = expf(-ltemp[h]);
#pragma unroll
  for (int j = 0; j < 5; j++) l[j] *= it;
  float mx = fmaxf(fmaxf(fmaxf(l[0], l[1]), fmaxf(l[2], l[3])), l[4]);
  float e[5], se = 0.f;
#pragma unroll
  for (int j = 0; j < 5; j++) { e[j] = expf(l[j] - mx); se += e[j]; }
  float inv = 1.f / se;
  float f = 1.f / (1.f + expf(-flog[h]));
  float sc = 1.f - 4.f * f;
  float wt[5];
#pragma unroll
  for (int j = 0; j < 4; j++) wt[j] = f + sc * e[j] * inv;
  wt[4] = sc * e[4] * inv;

  long base = (long)tok * HID_ + h * D_;
  float o[4], ss = 0.f;
#pragma unroll
  for (int i = 0; i < 4; i++) {
    int d = ln + 64 * i;
    o[i] = wt[0] * sb[base + d] + wt[1] * lb[base + d] + wt[2] * wbb[base + d]
         + wt[3] * db[base + d] + wt[4] * vb[base + d];
    ss += o[i] * o[i];
  }
#pragma unroll
  for (int off = 32; off >= 1; off >>= 1) ss += __shfl_xor(ss, off);
  float r = rsqrtf(ss * (1.f / 256.f) + 1e-5f);
#pragma unroll
  for (int i = 0; i < 4; i++) {
    int d = ln + 64 * i;
    omix[base + d] = o[i] * r * onw[d];
  }
}

// ---------------------------------------------------------------------------
extern "C" void kernel_launch(void* const* d_in, const int* in_sizes, int n_in,
                              void* d_out, int out_size, void* d_ws, size_t ws_size,
                              hipStream_t stream)
{
  const float* hs    = (const float*)d_in[0];
  const float* q_w   = (const float*)d_in[1];
  const float* k_w   = (const float*)d_in[2];
  const float* v_w   = (const float*)d_in[3];
  const float* b_w   = (const float*)d_in[4];
  const float* convq = (const float*)d_in[5];
  const float* convk = (const float*)d_in[6];
  const float* convv = (const float*)d_in[7];
  const float* fir_s = (const float*)d_in[8];
  const float* fir_l = (const float*)d_in[9];
  const float* fir_w = (const float*)d_in[10];
  const float* g1w   = (const float*)d_in[11];
  const float* g1b   = (const float*)d_in[12];
  const float* g2w   = (const float*)d_in[13];
  const float* g2b   = (const float*)d_in[14];
  const float* vbias = (const float*)d_in[15];
  const float* ltemp = (const float*)d_in[16];
  const float* flog  = (const float*)d_in[17];
  const float* onw   = (const float*)d_in[18];
  const float* o_w   = (const float*)d_in[19];

  float* ws = (float*)d_ws;
  const long S1 = (long)NTOK * HID_;    // 4,194,304
  float* qp    = ws + 0 * S1;
  float* kp    = ws + 1 * S1;
  float* vp    = ws + 2 * S1;
  float* qcv   = ws + 3 * S1;
  float* kcv   = ws + 4 * S1;
  float* vcv   = ws + 5 * S1;
  float* qnb   = ws + 6 * S1;
  float* knb   = ws + 7 * S1;
  float* ub    = ws + 8 * S1;
  float* wbf   = ws + 9 * S1;
  float* attnb = ws + 10 * S1;                                  // 524288
  float* betab = attnb + (long)B_ * H_ * NCH * CH * CH;         // 16384
  float* deltab = betab + (long)NTOK * H_;                      // S1
  // reuse (all source regions dead by the time these are written):
  float* gateb = ws + 3 * S1;    // over qcv/kcv  (dead after delta_prep)
  float* hdnb  = ws + 6 * S1;    // over qnb/knb  (dead after delta_scan)
  float* omixb = ws + 8 * S1;    // over ub       (dead after delta_scan)
  float* g1wp  = ws + 9 * S1;    // over wbf      (dead after delta_scan)
  (void)in_sizes; (void)n_in; (void)out_size; (void)ws_size;

  dim3 blk(256);
  // projections
  gemm128<0><<<dim3(8, 32), blk, 0, stream>>>(hs, q_w, nullptr, qp, NTOK, HID_, HID_);
  gemm128<0><<<dim3(8, 32), blk, 0, stream>>>(hs, k_w, nullptr, kp, NTOK, HID_, HID_);
  gemm128<0><<<dim3(8, 32), blk, 0, stream>>>(hs, v_w, nullptr, vp, NTOK, HID_, HID_);
  // causal conv K=4 + silu
  conv4_silu<<<NTOK * HID_ / 256, blk, 0, stream>>>(qp, convq, qcv);
  conv4_silu<<<NTOK * HID_ / 256, blk, 0, stream>>>(kp, convk, kcv);
  conv4_silu<<<NTOK * HID_ / 256, blk, 0, stream>>>(vp, convv, vcv);
  // beta
  beta_proj<<<NTOK * H_ / 256, blk, 0, stream>>>(hs, b_w, betab);
  // delta rule
  delta_prep<<<B_ * H_ * NCH, blk, 0, stream>>>(qcv, kcv, vcv, betab, qnb, knb, ub, wbf, attnb);
  delta_scan<<<B_ * H_ * 32, blk, 0, stream>>>(qnb, knb, ub, wbf, attnb, deltab);
  // FIR branches (write over qp/kp/vp — dead after conv)
  fir3<<<(NTOK / 32) * (HID_ / 64), blk, 0, stream>>>(vcv, fir_s, fir_l, fir_w, qp, kp, vp);
  // gate input assembly
  build_gate<<<NTOK, blk, 0, stream>>>(hs, qp, kp, vp, deltab, vcv, gateb);
  // gate MLP
  pad_g1w<<<2048 * 1088 / 256, blk, 0, stream>>>(g1w, g1wp);
  gemm128<1><<<dim3(16, 32), blk, 0, stream>>>(gateb, g1wp, g1b, hdnb, NTOK, 2048, 1088);
  g2_mix<<<NTOK, blk, 0, stream>>>(hdnb, g2w, g2b, vbias, ltemp, flog, onw,
                                   qp, kp, vp, deltab, vcv, omixb);
  // output projection
  gemm128<0><<<dim3(8, 32), blk, 0, stream>>>(omixb, o_w, nullptr, (float*)d_out, NTOK, HID_, HID_);
}

// Round 2
// 1520.680 us; speedup vs baseline: 1.0475x; 1.0475x over previous
//
#include <hip/hip_runtime.h>

#define B_ 2
#define L_ 2048
#define HID_ 1024
#define H_ 4
#define D_ 256
#define NTOK 4096
#define CH 32
#define NCH 64

typedef short s16x8 __attribute__((ext_vector_type(8)));
typedef float f32x4 __attribute__((ext_vector_type(4)));
typedef unsigned short u16;
typedef unsigned int u32;

__device__ __forceinline__ u16 f2b(float f) {  // RNE fp32->bf16
  u32 u = __float_as_uint(f);
  u32 r = (u + 0x7fffu + ((u >> 16) & 1u)) >> 16;
  return (u16)r;
}
__device__ __forceinline__ float blo(u32 u) { return __uint_as_float(u << 16); }
__device__ __forceinline__ float bhi(u32 u) { return __uint_as_float(u & 0xffff0000u); }

// ---------------------------------------------------------------------------
// cast fp32 -> bf16, n multiple of 4
// ---------------------------------------------------------------------------
__global__ __launch_bounds__(256)
void cast_bf(const float* __restrict__ in, u16* __restrict__ out, int n)
{
  int id = (blockIdx.x * 256 + threadIdx.x) * 4;
  if (id >= n) return;
  float4 v = *(const float4*)(in + id);
  ushort4 o;
  o.x = f2b(v.x); o.y = f2b(v.y); o.z = f2b(v.z); o.w = f2b(v.w);
  *(ushort4*)(out + id) = o;
}

// ---------------------------------------------------------------------------
// bf16 MFMA GEMM: C[M][N](f32) = act(A_bf[M][K] @ W_bf[N][K]^T + bias)
// M%128==0, N%128==0, K%64==0.  ACT: 0=none, 1=bias+exact GELU
// 128x128 tile, BK=64, 4 waves (each 64x64), 16x16x32 bf16 MFMA.
// LDS [128][64] bf16 with 16B-slot XOR swizzle: slot = (k/8) ^ (row&7).
// ---------------------------------------------------------------------------
template<int ACT>
__global__ __launch_bounds__(256)
void gemm_bf16(const u16* __restrict__ A, const u16* __restrict__ W,
               const float* __restrict__ bias, float* __restrict__ C,
               int M, int N, int K)
{
  __shared__ u16 Als[128][64];
  __shared__ u16 Bls[128][64];
  const int tid = threadIdx.x;
  const int n0 = blockIdx.x * 128;
  const int m0 = blockIdx.y * 128;
  const int l = tid & 63, w = tid >> 6;
  const int wm = w >> 1, wn = w & 1;
  const int r15 = l & 15, g = l >> 4;
  const int srow = tid >> 1, sh = tid & 1;

  f32x4 acc[4][4];
#pragma unroll
  for (int i = 0; i < 4; i++)
#pragma unroll
    for (int j = 0; j < 4; j++) acc[i][j] = (f32x4){0.f, 0.f, 0.f, 0.f};

  const long arowoff = (long)(m0 + srow) * K + sh * 32;
  const long browoff = (long)(n0 + srow) * K + sh * 32;
  uint4 ra[4], rb[4];
#pragma unroll
  for (int j2 = 0; j2 < 4; j2++) {
    ra[j2] = *(const uint4*)(A + arowoff + j2 * 8);
    rb[j2] = *(const uint4*)(W + browoff + j2 * 8);
  }
  const int NS = K >> 6;
  for (int s = 0; s < NS; ++s) {
    __syncthreads();
#pragma unroll
    for (int j2 = 0; j2 < 4; j2++) {
      int slot = (sh * 4 + j2) ^ (srow & 7);
      *(uint4*)&Als[srow][slot * 8] = ra[j2];
      *(uint4*)&Bls[srow][slot * 8] = rb[j2];
    }
    __syncthreads();
    if (s + 1 < NS) {
      long k0 = (long)(s + 1) * 64;
#pragma unroll
      for (int j2 = 0; j2 < 4; j2++) {
        ra[j2] = *(const uint4*)(A + arowoff + k0 + j2 * 8);
        rb[j2] = *(const uint4*)(W + browoff + k0 + j2 * 8);
      }
    }
#pragma unroll
    for (int kk2 = 0; kk2 < 2; kk2++) {
      s16x8 af[4], bf[4];
      int slot = ((kk2 * 4 + g) ^ (r15 & 7)) * 8;
#pragma unroll
      for (int mt = 0; mt < 4; mt++)
        af[mt] = *(const s16x8*)&Als[64 * wm + mt * 16 + r15][slot];
#pragma unroll
      for (int nt = 0; nt < 4; nt++)
        bf[nt] = *(const s16x8*)&Bls[64 * wn + nt * 16 + r15][slot];
#pragma unroll
      for (int mt = 0; mt < 4; mt++)
#pragma unroll
        for (int nt = 0; nt < 4; nt++)
          acc[mt][nt] = __builtin_amdgcn_mfma_f32_16x16x32_bf16(af[mt], bf[nt], acc[mt][nt], 0, 0, 0);
    }
  }

#pragma unroll
  for (int mt = 0; mt < 4; mt++) {
#pragma unroll
    for (int nt = 0; nt < 4; nt++) {
      int m = m0 + 64 * wm + mt * 16 + g * 4;
      int n = n0 + 64 * wn + nt * 16 + r15;
      float bv = (ACT == 1) ? bias[n] : 0.f;
#pragma unroll
      for (int r = 0; r < 4; r++) {
        float v = acc[mt][nt][r];
        if (ACT == 1) {
          v += bv;
          v = 0.5f * v * (1.f + erff(v * 0.70710678118654752f));
        }
        C[(long)(m + r) * N + n] = v;
      }
    }
  }
}

// ---------------------------------------------------------------------------
// Depthwise causal conv (K=4) + SiLU.  x,y: [NTOK][HID], w: [HID][4]
// ---------------------------------------------------------------------------
__global__ __launch_bounds__(256)
void conv4_silu(const float* __restrict__ x, const float* __restrict__ w4,
                float* __restrict__ y)
{
  int id = blockIdx.x * 256 + threadIdx.x;
  int c = id & (HID_ - 1);
  int tok = id >> 10;
  int l = tok & (L_ - 1);
  float s = 0.f;
#pragma unroll
  for (int t = 0; t < 4; t++) {
    int lt = l - 3 + t;
    if (lt >= 0) s += x[(long)(tok - 3 + t) * HID_ + c] * w4[c * 4 + t];
  }
  y[id] = s / (1.f + expf(-s));
}

// ---------------------------------------------------------------------------
// beta = sigmoid(hs @ b_w^T): [NTOK][4]
// ---------------------------------------------------------------------------
__global__ __launch_bounds__(256)
void beta_proj(const float* __restrict__ hs, const float* __restrict__ bw,
               float* __restrict__ beta)
{
  int id = blockIdx.x * 256 + threadIdx.x;   // < NTOK*H_
  int h = id & 3;
  int tok = id >> 2;
  const float4* a = (const float4*)(hs + (long)tok * HID_);
  const float4* w = (const float4*)(bw + (long)h * HID_);
  float s = 0.f;
  for (int k = 0; k < HID_ / 4; k++) {
    float4 av = a[k], wv = w[k];
    s += av.x * wv.x + av.y * wv.y + av.z * wv.z + av.w * wv.w;
  }
  beta[id] = 1.f / (1.f + expf(-s));
}

// ---------------------------------------------------------------------------
// g1 weight pad+cast: [2048][1084] f32 -> [2048][1088] bf16 (zero fill)
// ---------------------------------------------------------------------------
__global__ __launch_bounds__(256)
void pad_g1w(const float* __restrict__ g1w, u16* __restrict__ out)
{
  int id = blockIdx.x * 256 + threadIdx.x;   // < 2048*1088
  int k = id % 1088;
  int n = id / 1088;
  out[id] = (k < 1084) ? f2b(g1w[(long)n * 1084 + k]) : (u16)0;
}

// ---------------------------------------------------------------------------
// Delta-rule chunk prep: per (b,h,chunk): l2norm q/k, A, (I+A)^-1, u, w, attn
// qn,kn,wb outputs bf16; ub, attn fp32.
// ---------------------------------------------------------------------------
__global__ __launch_bounds__(256)
void delta_prep(const float* __restrict__ qc, const float* __restrict__ kc,
                const float* __restrict__ vc, const float* __restrict__ beta,
                u16* __restrict__ qn, u16* __restrict__ kn,
                float* __restrict__ ub, u16* __restrict__ wb,
                float* __restrict__ attnb)
{
  __shared__ float qs[CH][260], ks[CH][260], vs[CH][260];
  __shared__ float Xs[CH][33], As[CH][33];
  __shared__ float red[CH][8];
  __shared__ float bet[CH], nf[CH];

  int bid = blockIdx.x;
  int ci = bid & 63, h = (bid >> 6) & 3, b = bid >> 8;
  int tid = threadIdx.x;
  long tok0 = (long)b * L_ + (long)ci * CH;
  const float* qsrc = qc + tok0 * HID_ + h * D_;
  const float* ksrc = kc + tok0 * HID_ + h * D_;
  const float* vsrc = vc + tok0 * HID_ + h * D_;
  int lr = tid >> 6;
  int dd = (tid & 63) << 2;

#pragma unroll
  for (int it = 0; it < 8; it++) {
    int row = lr + it * 4;
    *(float4*)&qs[row][dd] = *(const float4*)(qsrc + (long)row * HID_ + dd);
    *(float4*)&ks[row][dd] = *(const float4*)(ksrc + (long)row * HID_ + dd);
    *(float4*)&vs[row][dd] = *(const float4*)(vsrc + (long)row * HID_ + dd);
  }
  if (tid < CH) bet[tid] = beta[(tok0 + tid) * H_ + h];
  __syncthreads();

  {
    int c = tid >> 3, p = tid & 7;
    float s = 0.f;
    for (int d = p * 32; d < p * 32 + 32; d++) { float v = qs[c][d]; s += v * v; }
    red[c][p] = s;
  }
  __syncthreads();
  if (tid < CH) {
    float s = 0.f;
    for (int p = 0; p < 8; p++) s += red[tid][p];
    nf[tid] = rsqrtf(s + 1e-6f);
  }
  __syncthreads();
#pragma unroll
  for (int it = 0; it < 8; it++) {
    int row = lr + it * 4;
    float f = nf[row];
    qs[row][dd] *= f; qs[row][dd + 1] *= f; qs[row][dd + 2] *= f; qs[row][dd + 3] *= f;
  }
  {
    int c = tid >> 3, p = tid & 7;
    float s = 0.f;
    for (int d = p * 32; d < p * 32 + 32; d++) { float v = ks[c][d]; s += v * v; }
    red[c][p] = s;
  }
  __syncthreads();
  if (tid < CH) {
    float s = 0.f;
    for (int p = 0; p < 8; p++) s += red[tid][p];
    nf[tid] = rsqrtf(s + 1e-6f);
  }
  __syncthreads();
#pragma unroll
  for (int it = 0; it < 8; it++) {
    int row = lr + it * 4;
    float f = nf[row];
    ks[row][dd] *= f; ks[row][dd + 1] *= f; ks[row][dd + 2] *= f; ks[row][dd + 3] *= f;
  }
  __syncthreads();

  long abase = ((long)(b * H_ + h) * NCH + ci) * (CH * CH);
#pragma unroll 1
  for (int r = 0; r < 4; r++) {
    int oid = tid + 256 * r;
    int i = oid >> 5, j = oid & 31;
    float skk = 0.f, sqk = 0.f;
    for (int d = 0; d < D_; d += 4) {
      float4 ki = *(const float4*)&ks[i][d];
      float4 kj = *(const float4*)&ks[j][d];
      float4 qi = *(const float4*)&qs[i][d];
      skk += ki.x * kj.x + ki.y * kj.y + ki.z * kj.z + ki.w * kj.w;
      sqk += qi.x * kj.x + qi.y * kj.y + qi.z * kj.z + qi.w * kj.w;
    }
    As[i][j] = (j < i) ? bet[i] * skk : 0.f;
    attnb[abase + oid] = (j <= i) ? sqk : 0.f;
  }
  __syncthreads();

  if (tid < CH) {
    int j = tid;
    for (int i = 0; i < CH; i++) {
      if (i < j) { Xs[i][j] = 0.f; continue; }
      float x = (i == j) ? 1.f : 0.f;
      for (int m = j; m < i; m++) x -= As[i][m] * Xs[m][j];
      Xs[i][j] = x;
    }
  }
  __syncthreads();

#pragma unroll
  for (int r = 0; r < 4; r++) {
    int oid = tid + 256 * r;
    int i = oid >> 5, m = oid & 31;
    As[i][m] = Xs[i][m] * bet[m];
  }
  __syncthreads();

  long cbase = ((long)(b * H_ + h) * NCH + ci) * (CH * D_);
#pragma unroll 1
  for (int c = 0; c < CH; c++) {
    float su = 0.f, sw = 0.f;
    for (int m = 0; m < CH; m++) {
      float xm = As[c][m];
      su = fmaf(xm, vs[m][tid], su);
      sw = fmaf(xm, ks[m][tid], sw);
    }
    ub[cbase + c * D_ + tid] = su;
    wb[cbase + c * D_ + tid] = f2b(sw);
  }
#pragma unroll 1
  for (int i = 0; i < CH; i++) {
    qn[cbase + i * D_ + tid] = f2b(qs[i][tid]);
    kn[cbase + i * D_ + tid] = f2b(ks[i][tid]);
  }
}

// ---------------------------------------------------------------------------
// Delta-rule scan: block = (b,h,slice of 8 dv cols); sequential over chunks.
// q,w staged bf16 in LDS; k read straight from global (bf16, coalesced);
// next chunk's q/w/attn/u prefetched into registers during compute.
// ---------------------------------------------------------------------------
__global__ __launch_bounds__(256)
void delta_scan(const u16* __restrict__ qn, const u16* __restrict__ kn,
                const float* __restrict__ ub, const u16* __restrict__ wb,
                const float* __restrict__ attnb, float* __restrict__ dout)
{
  __shared__ float ST[8][260];        // S transposed: ST[j][dk]
  __shared__ u16 qch[CH][264];
  __shared__ u16 wch[CH][264];
  __shared__ float att[CH][36];
  __shared__ float ua[CH][8];

  int bid = blockIdx.x;
  int sl = bid & 31, h = (bid >> 5) & 3, b = bid >> 7;
  int tid = threadIdx.x;
  int J0 = sl * 8;
  long bh = (long)(b * H_ + h);

  for (int i = tid; i < 8 * 260; i += 256) (&ST[0][0])[i] = 0.f;

  const int c = tid >> 3, j = tid & 7;
  const int srow = tid >> 3, sseg = (tid & 7) * 32;
  const int ai = tid >> 3, aj = (tid * 4) & 31;

  uint4 qr[4], wr[4];
  float4 ar;
  float ur;
  {
    long cb = (bh * NCH + 0) * (CH * D_);
    long ab = (bh * NCH + 0) * (CH * CH);
    const u16* qg = qn + cb + srow * D_ + sseg;
    const u16* wg = wb + cb + srow * D_ + sseg;
#pragma unroll
    for (int j2 = 0; j2 < 4; j2++) {
      qr[j2] = *(const uint4*)(qg + j2 * 8);
      wr[j2] = *(const uint4*)(wg + j2 * 8);
    }
    ar = *(const float4*)(attnb + ab + tid * 4);
    ur = ub[cb + c * D_ + J0 + j];
  }

  for (int ci = 0; ci < NCH; ci++) {
    __syncthreads();   // prev chunk compute done; LDS safe to overwrite
#pragma unroll
    for (int j2 = 0; j2 < 4; j2++) {
      *(uint4*)&qch[srow][sseg + j2 * 8] = qr[j2];
      *(uint4*)&wch[srow][sseg + j2 * 8] = wr[j2];
    }
    *(float4*)&att[ai][aj] = ar;
    float u_cur = ur;
    long cb_cur = (bh * NCH + ci) * (CH * D_);
    __syncthreads();   // staged data visible

    if (ci + 1 < NCH) {
      long cb = (bh * NCH + ci + 1) * (CH * D_);
      long ab = (bh * NCH + ci + 1) * (CH * CH);
      const u16* qg = qn + cb + srow * D_ + sseg;
      const u16* wg = wb + cb + srow * D_ + sseg;
#pragma unroll
      for (int j2 = 0; j2 < 4; j2++) {
        qr[j2] = *(const uint4*)(qg + j2 * 8);
        wr[j2] = *(const uint4*)(wg + j2 * 8);
      }
      ar = *(const float4*)(attnb + ab + tid * 4);
      ur = ub[cb + c * D_ + J0 + j];
    }

    // phase A: aw = w_c . S_j ; aq = q_c . S_j
    float aw = 0.f, aq = 0.f;
#pragma unroll 4
    for (int d = 0; d < D_; d += 8) {
      float4 s0 = *(const float4*)&ST[j][d];
      float4 s1 = *(const float4*)&ST[j][d + 4];
      uint4 wv = *(const uint4*)&wch[c][d];
      uint4 qv = *(const uint4*)&qch[c][d];
      aw = fmaf(blo(wv.x), s0.x, aw); aw = fmaf(bhi(wv.x), s0.y, aw);
      aw = fmaf(blo(wv.y), s0.z, aw); aw = fmaf(bhi(wv.y), s0.w, aw);
      aw = fmaf(blo(wv.z), s1.x, aw); aw = fmaf(bhi(wv.z), s1.y, aw);
      aw = fmaf(blo(wv.w), s1.z, aw); aw = fmaf(bhi(wv.w), s1.w, aw);
      aq = fmaf(blo(qv.x), s0.x, aq); aq = fmaf(bhi(qv.x), s0.y, aq);
      aq = fmaf(blo(qv.y), s0.z, aq); aq = fmaf(bhi(qv.y), s0.w, aq);
      aq = fmaf(blo(qv.z), s1.x, aq); aq = fmaf(bhi(qv.z), s1.y, aq);
      aq = fmaf(blo(qv.w), s1.z, aq); aq = fmaf(bhi(qv.w), s1.w, aq);
    }
    ua[c][j] = u_cur - aw;
    __syncthreads();

    // phase B: o = aq + attn_c . ua_j
    float o = aq;
#pragma unroll
    for (int m = 0; m < CH; m++) o = fmaf(att[c][m], ua[m][j], o);
    dout[((long)b * L_ + ci * CH + c) * HID_ + h * D_ + J0 + j] = o;

    // phase C: S[dk=tid][0..7] += sum_c kn[c][dk] * ua[c][j]  (k from global)
    const u16* kg = kn + cb_cur;
    float acc2[8] = {0.f, 0.f, 0.f, 0.f, 0.f, 0.f, 0.f, 0.f};
#pragma unroll 1
    for (int cc = 0; cc < CH; cc++) {
      float kv = blo((u32)kg[cc * D_ + tid] << 16 >> 16 | ((u32)kg[cc * D_ + tid] << 16));
      kv = __uint_as_float(((u32)kg[cc * D_ + tid]) << 16);
      float4 u0 = *(const float4*)&ua[cc][0];
      float4 u1 = *(const float4*)&ua[cc][4];
      acc2[0] = fmaf(kv, u0.x, acc2[0]); acc2[1] = fmaf(kv, u0.y, acc2[1]);
      acc2[2] = fmaf(kv, u0.z, acc2[2]); acc2[3] = fmaf(kv, u0.w, acc2[3]);
      acc2[4] = fmaf(kv, u1.x, acc2[4]); acc2[5] = fmaf(kv, u1.y, acc2[5]);
      acc2[6] = fmaf(kv, u1.z, acc2[6]); acc2[7] = fmaf(kv, u1.w, acc2[7]);
    }
#pragma unroll
    for (int jj = 0; jj < 8; jj++) ST[jj][tid] += acc2[jj];
  }
}

// ---------------------------------------------------------------------------
// Fused 3-FIR depthwise causal conv on v (K=3,31,64). Tile 32 tok x 64 ch.
// ---------------------------------------------------------------------------
__global__ __launch_bounds__(256)
void fir3(const float* __restrict__ v, const float* __restrict__ fs_g,
          const float* __restrict__ fl_g, const float* __restrict__ fw_g,
          float* __restrict__ os, float* __restrict__ ol, float* __restrict__ ow)
{
  __shared__ float xs[95][64];
  __shared__ float fs[64][3];
  __shared__ float fl[64][31];
  __shared__ float fw[64][65];
  int bid = blockIdx.x;
  int ct = bid & 15, lt = bid >> 4;
  int c0 = ct * 64, tok0 = lt * 32;
  int bstart = (tok0 / L_) * L_;
  int tid = threadIdx.x;

  for (int idx = tid; idx < 95 * 64; idx += 256) {
    int r = idx >> 6, cc = idx & 63;
    int tok = tok0 - 63 + r;
    xs[r][cc] = (tok >= bstart) ? v[(long)tok * HID_ + c0 + cc] : 0.f;
  }
  for (int idx = tid; idx < 64 * 3; idx += 256) fs[idx / 3][idx % 3] = fs_g[(long)(c0 + idx / 3) * 3 + idx % 3];
  for (int idx = tid; idx < 64 * 31; idx += 256) fl[idx / 31][idx % 31] = fl_g[(long)(c0 + idx / 31) * 31 + idx % 31];
  for (int idx = tid; idx < 64 * 64; idx += 256) fw[idx >> 6][idx & 63] = fw_g[(long)(c0 + (idx >> 6)) * 64 + (idx & 63)];
  __syncthreads();

  int cc = tid & 63, lq = tid >> 6;
  int rb = lq * 8;
  float as8[8] = {0}, al8[8] = {0}, aw8[8] = {0};
#pragma unroll 1
  for (int t = 0; t < 64; t++) {
    float fv = fw[cc][t];
#pragma unroll
    for (int i = 0; i < 8; i++) aw8[i] = fmaf(xs[rb + i + t][cc], fv, aw8[i]);
  }
#pragma unroll 1
  for (int t = 0; t < 31; t++) {
    float fv = fl[cc][t];
#pragma unroll
    for (int i = 0; i < 8; i++) al8[i] = fmaf(xs[rb + 33 + i + t][cc], fv, al8[i]);
  }
#pragma unroll 1
  for (int t = 0; t < 3; t++) {
    float fv = fs[cc][t];
#pragma unroll
    for (int i = 0; i < 8; i++) as8[i] = fmaf(xs[rb + 61 + i + t][cc], fv, as8[i]);
  }
#pragma unroll
  for (int i = 0; i < 8; i++) {
    long o = (long)(tok0 + lq * 8 + i) * HID_ + c0 + cc;
    os[o] = as8[i]; ol[o] = al8[i]; ow[o] = aw8[i];
  }
}

// ---------------------------------------------------------------------------
// gate_in (bf16) = [hs | stats(short) | stats(long) | stats(wide) | stats(delta) | stats(v)]
// row stride 1088 (cols 1084..1087 zeroed)
// ---------------------------------------------------------------------------
__global__ __launch_bounds__(256)
void build_gate(const float* __restrict__ hs, const float* __restrict__ sb,
                const float* __restrict__ lb, const float* __restrict__ wbb,
                const float* __restrict__ db, const float* __restrict__ vb,
                u16* __restrict__ gate)
{
  int tok = blockIdx.x;
  int tid = threadIdx.x;
  u16* g = gate + (long)tok * 1088;
  const float* hrow = hs + (long)tok * HID_;
#pragma unroll
  for (int i = 0; i < 4; i++) g[tid + 256 * i] = f2b(hrow[tid + 256 * i]);
  if (tid < 4) g[1084 + tid] = 0;
  int h = tid >> 6, ln = tid & 63;
  const float* brs[5] = {sb, lb, wbb, db, vb};
#pragma unroll
  for (int bi = 0; bi < 5; bi++) {
    const float* x = brs[bi] + (long)tok * HID_ + h * D_;
    float s = 0.f, ss = 0.f, mx = 0.f;
#pragma unroll
    for (int i = 0; i < 4; i++) {
      float v = x[ln + 64 * i];
      s += v; ss += v * v; mx = fmaxf(mx, fabsf(v));
    }
#pragma unroll
    for (int off = 32; off >= 1; off >>= 1) {
      s += __shfl_xor(s, off);
      ss += __shfl_xor(ss, off);
      mx = fmaxf(mx, __shfl_xor(mx, off));
    }
    if (ln == 0) {
      g[1024 + bi * 12 + h] = f2b(s * (1.f / 256.f));
      g[1024 + bi * 12 + 4 + h] = f2b(sqrtf(fmaxf(ss * (1.f / 256.f), 1e-8f)));
      g[1024 + bi * 12 + 8 + h] = f2b(mx);
    }
  }
}

// ---------------------------------------------------------------------------
// Fused g2 (4096x20x2048) + softmax/temperature/floor mix + per-head RMSNorm
// Output omix in bf16.
// ---------------------------------------------------------------------------
__global__ __launch_bounds__(256)
void g2_mix(const float* __restrict__ hdn, const float* __restrict__ g2w,
            const float* __restrict__ g2b, const float* __restrict__ vbias,
            const float* __restrict__ ltemp, const float* __restrict__ flog,
            const float* __restrict__ onw,
            const float* __restrict__ sb, const float* __restrict__ lb,
            const float* __restrict__ wbb, const float* __restrict__ db,
            const float* __restrict__ vb, u16* __restrict__ omix)
{
  __shared__ float hrow[2048];
  __shared__ float lg[20];
  int tok = blockIdx.x;
  int tid = threadIdx.x;
  const float* hp = hdn + (long)tok * 2048;
#pragma unroll
  for (int i = 0; i < 8; i++) hrow[tid + 256 * i] = hp[tid + 256 * i];
  __syncthreads();
  int w = tid >> 6, ln = tid & 63;
#pragma unroll 1
  for (int q = 0; q < 5; q++) {
    int jj = w * 5 + q;
    const float* wr = g2w + (long)jj * 2048;
    float s = 0.f;
    for (int i = 0; i < 32; i++) s += hrow[ln + 64 * i] * wr[ln + 64 * i];
#pragma unroll
    for (int off = 32; off >= 1; off >>= 1) s += __shfl_xor(s, off);
    if (ln == 0) lg[jj] = s + g2b[jj];
  }
  __syncthreads();
  int h = w;
  float l[5];
#pragma unroll
  for (int j = 0; j < 5; j++) l[j] = lg[h * 5 + j];
  l[4] += vbias[h];
  float it = expf(-ltemp[h]);
#pragma unroll
  for (int j = 0; j < 5; j++) l[j] *= it;
  float mx = fmaxf(fmaxf(fmaxf(l[0], l[1]), fmaxf(l[2], l[3])), l[4]);
  float e[5], se = 0.f;
#pragma unroll
  for (int j = 0; j < 5; j++) { e[j] = expf(l[j] - mx); se += e[j]; }
  float inv = 1.f / se;
  float f = 1.f / (1.f + expf(-flog[h]));
  float sc = 1.f - 4.f * f;
  float wt[5];
#pragma unroll
  for (int j = 0; j < 4; j++) wt[j] = f + sc * e[j] * inv;
  wt[4] = sc * e[4] * inv;

  long base = (long)tok * HID_ + h * D_;
  float o[4], ss = 0.f;
#pragma unroll
  for (int i = 0; i < 4; i++) {
    int d = ln + 64 * i;
    o[i] = wt[0] * sb[base + d] + wt[1] * lb[base + d] + wt[2] * wbb[base + d]
         + wt[3] * db[base + d] + wt[4] * vb[base + d];
    ss += o[i] * o[i];
  }
#pragma unroll
  for (int off = 32; off >= 1; off >>= 1) ss += __shfl_xor(ss, off);
  float r = rsqrtf(ss * (1.f / 256.f) + 1e-5f);
#pragma unroll
  for (int i = 0; i < 4; i++) {
    int d = ln + 64 * i;
    omix[base + d] = f2b(o[i] * r * onw[d]);
  }
}

// ---------------------------------------------------------------------------
extern "C" void kernel_launch(void* const* d_in, const int* in_sizes, int n_in,
                              void* d_out, int out_size, void* d_ws, size_t ws_size,
                              hipStream_t stream)
{
  const float* hs    = (const float*)d_in[0];
  const float* q_w   = (const float*)d_in[1];
  const float* k_w   = (const float*)d_in[2];
  const float* v_w   = (const float*)d_in[3];
  const float* b_w   = (const float*)d_in[4];
  const float* convq = (const float*)d_in[5];
  const float* convk = (const float*)d_in[6];
  const float* convv = (const float*)d_in[7];
  const float* fir_s = (const float*)d_in[8];
  const float* fir_l = (const float*)d_in[9];
  const float* fir_w = (const float*)d_in[10];
  const float* g1w   = (const float*)d_in[11];
  const float* g1b   = (const float*)d_in[12];
  const float* g2w   = (const float*)d_in[13];
  const float* g2b   = (const float*)d_in[14];
  const float* vbias = (const float*)d_in[15];
  const float* ltemp = (const float*)d_in[16];
  const float* flog  = (const float*)d_in[17];
  const float* onw   = (const float*)d_in[18];
  const float* o_w   = (const float*)d_in[19];

  float* ws = (float*)d_ws;
  const long S1 = (long)NTOK * HID_;          // 4,194,304 floats
  float* qp     = ws + 0 * S1;
  float* kp     = ws + 1 * S1;
  float* vp     = ws + 2 * S1;
  float* qcv    = ws + 3 * S1;
  float* kcv    = ws + 4 * S1;
  float* vcv    = ws + 5 * S1;
  float* ubb    = ws + 6 * S1;
  float* deltab = ws + 7 * S1;
  u16*   qn_bf  = (u16*)(ws + 8 * S1);                  // 4M u16
  u16*   kn_bf  = (u16*)(ws + 8 * S1 + S1 / 2);
  u16*   wb_bf  = (u16*)(ws + 9 * S1);
  float* attnb  = ws + 9 * S1 + S1 / 2;                 // 524288 f32
  float* betab  = attnb + (long)B_ * H_ * NCH * CH * CH; // 16384 f32
  u16*   hs_bf  = (u16*)(ws + 10 * S1);                 // 4M u16
  u16*   qw_bf  = (u16*)(ws + 10 * S1 + S1 / 2);        // 1M u16 each
  u16*   kw_bf  = qw_bf + S1 / 4;
  u16*   vw_bf  = kw_bf + S1 / 4;
  u16*   ow_bf  = vw_bf + S1 / 4;
  u16*   g1w_bf = ow_bf + S1 / 4;                       // 2048*1088 u16
  // overlays (sources dead at time of write):
  u16*   gate_bf = (u16*)qcv;        // dead after delta_prep
  u16*   omix_bf = (u16*)kcv;        // dead after delta_prep
  float* hdnb    = ws + 8 * S1;      // over qn/kn/wb/attnb/betab (dead after scan)
  (void)in_sizes; (void)n_in; (void)out_size; (void)ws_size;

  dim3 blk(256);
  // precasts
  cast_bf<<<(NTOK * HID_) / 1024, blk, 0, stream>>>(hs, hs_bf, NTOK * HID_);
  cast_bf<<<(HID_ * HID_) / 1024, blk, 0, stream>>>(q_w, qw_bf, HID_ * HID_);
  cast_bf<<<(HID_ * HID_) / 1024, blk, 0, stream>>>(k_w, kw_bf, HID_ * HID_);
  cast_bf<<<(HID_ * HID_) / 1024, blk, 0, stream>>>(v_w, vw_bf, HID_ * HID_);
  cast_bf<<<(HID_ * HID_) / 1024, blk, 0, stream>>>(o_w, ow_bf, HID_ * HID_);
  pad_g1w<<<2048 * 1088 / 256, blk, 0, stream>>>(g1w, g1w_bf);
  // projections (bf16 MFMA)
  gemm_bf16<0><<<dim3(8, 32), blk, 0, stream>>>(hs_bf, qw_bf, nullptr, qp, NTOK, HID_, HID_);
  gemm_bf16<0><<<dim3(8, 32), blk, 0, stream>>>(hs_bf, kw_bf, nullptr, kp, NTOK, HID_, HID_);
  gemm_bf16<0><<<dim3(8, 32), blk, 0, stream>>>(hs_bf, vw_bf, nullptr, vp, NTOK, HID_, HID_);
  // causal conv K=4 + silu
  conv4_silu<<<NTOK * HID_ / 256, blk, 0, stream>>>(qp, convq, qcv);
  conv4_silu<<<NTOK * HID_ / 256, blk, 0, stream>>>(kp, convk, kcv);
  conv4_silu<<<NTOK * HID_ / 256, blk, 0, stream>>>(vp, convv, vcv);
  // beta
  beta_proj<<<NTOK * H_ / 256, blk, 0, stream>>>(hs, b_w, betab);
  // delta rule
  delta_prep<<<B_ * H_ * NCH, blk, 0, stream>>>(qcv, kcv, vcv, betab, qn_bf, kn_bf, ubb, wb_bf, attnb);
  delta_scan<<<B_ * H_ * 32, blk, 0, stream>>>(qn_bf, kn_bf, ubb, wb_bf, attnb, deltab);
  // FIR branches (write over qp/kp/vp — dead after conv)
  fir3<<<(NTOK / 32) * (HID_ / 64), blk, 0, stream>>>(vcv, fir_s, fir_l, fir_w, qp, kp, vp);
  // gate input assembly (bf16)
  build_gate<<<NTOK, blk, 0, stream>>>(hs, qp, kp, vp, deltab, vcv, gate_bf);
  // gate MLP (bf16 MFMA + GELU)
  gemm_bf16<1><<<dim3(16, 32), blk, 0, stream>>>(gate_bf, g1w_bf, g1b, hdnb, NTOK, 2048, 1088);
  g2_mix<<<NTOK, blk, 0, stream>>>(hdnb, g2w, g2b, vbias, ltemp, flog, onw,
                                   qp, kp, vp, deltab, vcv, omix_bf);
  // output projection
  gemm_bf16<0><<<dim3(8, 32), blk, 0, stream>>>(omix_bf, ow_bf, nullptr, (float*)d_out, NTOK, HID_, HID_);
}

// Round 3
// 1145.890 us; speedup vs baseline: 1.3901x; 1.3271x over previous
//
#include <hip/hip_runtime.h>

#define B_ 2
#define L_ 2048
#define HID_ 1024
#define H_ 4
#define D_ 256
#define NTOK 4096
#define CH 32
#define NCH 64

typedef short s16x8 __attribute__((ext_vector_type(8)));
typedef float f32x4 __attribute__((ext_vector_type(4)));
typedef unsigned short u16;
typedef unsigned int u32;

__device__ __forceinline__ u16 f2b(float f) {  // RNE fp32->bf16
  u32 u = __float_as_uint(f);
  u32 r = (u + 0x7fffu + ((u >> 16) & 1u)) >> 16;
  return (u16)r;
}
__device__ __forceinline__ float blo(u32 u) { return __uint_as_float(u << 16); }
__device__ __forceinline__ float bhi(u32 u) { return __uint_as_float(u & 0xffff0000u); }

// ---------------------------------------------------------------------------
// cast fp32 -> bf16, n multiple of 4
// ---------------------------------------------------------------------------
__global__ __launch_bounds__(256)
void cast_bf(const float* __restrict__ in, u16* __restrict__ out, int n)
{
  int id = (blockIdx.x * 256 + threadIdx.x) * 4;
  if (id >= n) return;
  float4 v = *(const float4*)(in + id);
  ushort4 o;
  o.x = f2b(v.x); o.y = f2b(v.y); o.z = f2b(v.z); o.w = f2b(v.w);
  *(ushort4*)(out + id) = o;
}

// ---------------------------------------------------------------------------
// bf16 MFMA GEMM: C[M][N](f32) = act(A_bf[M][K] @ W_bf[N][K]^T + bias)
// M%128==0, N%128==0, K%64==0.  ACT: 0=none, 1=bias+exact GELU
// ---------------------------------------------------------------------------
template<int ACT>
__global__ __launch_bounds__(256)
void gemm_bf16(const u16* __restrict__ A, const u16* __restrict__ W,
               const float* __restrict__ bias, float* __restrict__ C,
               int M, int N, int K)
{
  __shared__ u16 Als[128][64];
  __shared__ u16 Bls[128][64];
  const int tid = threadIdx.x;
  const int n0 = blockIdx.x * 128;
  const int m0 = blockIdx.y * 128;
  const int l = tid & 63, w = tid >> 6;
  const int wm = w >> 1, wn = w & 1;
  const int r15 = l & 15, g = l >> 4;
  const int srow = tid >> 1, sh = tid & 1;

  f32x4 acc[4][4];
#pragma unroll
  for (int i = 0; i < 4; i++)
#pragma unroll
    for (int j = 0; j < 4; j++) acc[i][j] = (f32x4){0.f, 0.f, 0.f, 0.f};

  const long arowoff = (long)(m0 + srow) * K + sh * 32;
  const long browoff = (long)(n0 + srow) * K + sh * 32;
  uint4 ra[4], rb[4];
#pragma unroll
  for (int j2 = 0; j2 < 4; j2++) {
    ra[j2] = *(const uint4*)(A + arowoff + j2 * 8);
    rb[j2] = *(const uint4*)(W + browoff + j2 * 8);
  }
  const int NS = K >> 6;
  for (int s = 0; s < NS; ++s) {
    __syncthreads();
#pragma unroll
    for (int j2 = 0; j2 < 4; j2++) {
      int slot = (sh * 4 + j2) ^ (srow & 7);
      *(uint4*)&Als[srow][slot * 8] = ra[j2];
      *(uint4*)&Bls[srow][slot * 8] = rb[j2];
    }
    __syncthreads();
    if (s + 1 < NS) {
      long k0 = (long)(s + 1) * 64;
#pragma unroll
      for (int j2 = 0; j2 < 4; j2++) {
        ra[j2] = *(const uint4*)(A + arowoff + k0 + j2 * 8);
        rb[j2] = *(const uint4*)(W + browoff + k0 + j2 * 8);
      }
    }
#pragma unroll
    for (int kk2 = 0; kk2 < 2; kk2++) {
      s16x8 af[4], bf[4];
      int slot = ((kk2 * 4 + g) ^ (r15 & 7)) * 8;
#pragma unroll
      for (int mt = 0; mt < 4; mt++)
        af[mt] = *(const s16x8*)&Als[64 * wm + mt * 16 + r15][slot];
#pragma unroll
      for (int nt = 0; nt < 4; nt++)
        bf[nt] = *(const s16x8*)&Bls[64 * wn + nt * 16 + r15][slot];
#pragma unroll
      for (int mt = 0; mt < 4; mt++)
#pragma unroll
        for (int nt = 0; nt < 4; nt++)
          acc[mt][nt] = __builtin_amdgcn_mfma_f32_16x16x32_bf16(af[mt], bf[nt], acc[mt][nt], 0, 0, 0);
    }
  }

#pragma unroll
  for (int mt = 0; mt < 4; mt++) {
#pragma unroll
    for (int nt = 0; nt < 4; nt++) {
      int m = m0 + 64 * wm + mt * 16 + g * 4;
      int n = n0 + 64 * wn + nt * 16 + r15;
      float bv = (ACT == 1) ? bias[n] : 0.f;
#pragma unroll
      for (int r = 0; r < 4; r++) {
        float v = acc[mt][nt][r];
        if (ACT == 1) {
          v += bv;
          v = 0.5f * v * (1.f + erff(v * 0.70710678118654752f));
        }
        C[(long)(m + r) * N + n] = v;
      }
    }
  }
}

// ---------------------------------------------------------------------------
// Depthwise causal conv (K=4) + SiLU.  x,y: [NTOK][HID], w: [HID][4]
// ---------------------------------------------------------------------------
__global__ __launch_bounds__(256)
void conv4_silu(const float* __restrict__ x, const float* __restrict__ w4,
                float* __restrict__ y)
{
  int id = blockIdx.x * 256 + threadIdx.x;
  int c = id & (HID_ - 1);
  int tok = id >> 10;
  int l = tok & (L_ - 1);
  float s = 0.f;
#pragma unroll
  for (int t = 0; t < 4; t++) {
    int lt = l - 3 + t;
    if (lt >= 0) s += x[(long)(tok - 3 + t) * HID_ + c] * w4[c * 4 + t];
  }
  y[id] = s / (1.f + expf(-s));
}

// ---------------------------------------------------------------------------
// beta = sigmoid(hs @ b_w^T): [NTOK][4]
// ---------------------------------------------------------------------------
__global__ __launch_bounds__(256)
void beta_proj(const float* __restrict__ hs, const float* __restrict__ bw,
               float* __restrict__ beta)
{
  int id = blockIdx.x * 256 + threadIdx.x;   // < NTOK*H_
  int h = id & 3;
  int tok = id >> 2;
  const float4* a = (const float4*)(hs + (long)tok * HID_);
  const float4* w = (const float4*)(bw + (long)h * HID_);
  float s = 0.f;
  for (int k = 0; k < HID_ / 4; k++) {
    float4 av = a[k], wv = w[k];
    s += av.x * wv.x + av.y * wv.y + av.z * wv.z + av.w * wv.w;
  }
  beta[id] = 1.f / (1.f + expf(-s));
}

// ---------------------------------------------------------------------------
// g1 weight pad+cast: [2048][1084] f32 -> [2048][1088] bf16 (zero fill)
// ---------------------------------------------------------------------------
__global__ __launch_bounds__(256)
void pad_g1w(const float* __restrict__ g1w, u16* __restrict__ out)
{
  int id = blockIdx.x * 256 + threadIdx.x;   // < 2048*1088
  int k = id % 1088;
  int n = id / 1088;
  out[id] = (k < 1084) ? f2b(g1w[(long)n * 1084 + k]) : (u16)0;
}

// ---------------------------------------------------------------------------
// Delta-rule chunk prep: per (b,h,chunk): l2norm q/k, A, (I+A)^-1, u, w, attn
// qn,kn,wb outputs bf16; ub, attn fp32.
// ---------------------------------------------------------------------------
__global__ __launch_bounds__(256)
void delta_prep(const float* __restrict__ qc, const float* __restrict__ kc,
                const float* __restrict__ vc, const float* __restrict__ beta,
                u16* __restrict__ qn, u16* __restrict__ kn,
                float* __restrict__ ub, u16* __restrict__ wb,
                float* __restrict__ attnb)
{
  __shared__ float qs[CH][260], ks[CH][260], vs[CH][260];
  __shared__ float Xs[CH][33], As[CH][33];
  __shared__ float red[CH][8];
  __shared__ float bet[CH], nf[CH];

  int bid = blockIdx.x;
  int ci = bid & 63, h = (bid >> 6) & 3, b = bid >> 8;
  int tid = threadIdx.x;
  long tok0 = (long)b * L_ + (long)ci * CH;
  const float* qsrc = qc + tok0 * HID_ + h * D_;
  const float* ksrc = kc + tok0 * HID_ + h * D_;
  const float* vsrc = vc + tok0 * HID_ + h * D_;
  int lr = tid >> 6;
  int dd = (tid & 63) << 2;

#pragma unroll
  for (int it = 0; it < 8; it++) {
    int row = lr + it * 4;
    *(float4*)&qs[row][dd] = *(const float4*)(qsrc + (long)row * HID_ + dd);
    *(float4*)&ks[row][dd] = *(const float4*)(ksrc + (long)row * HID_ + dd);
    *(float4*)&vs[row][dd] = *(const float4*)(vsrc + (long)row * HID_ + dd);
  }
  if (tid < CH) bet[tid] = beta[(tok0 + tid) * H_ + h];
  __syncthreads();

  {
    int c = tid >> 3, p = tid & 7;
    float s = 0.f;
    for (int d = p * 32; d < p * 32 + 32; d++) { float v = qs[c][d]; s += v * v; }
    red[c][p] = s;
  }
  __syncthreads();
  if (tid < CH) {
    float s = 0.f;
    for (int p = 0; p < 8; p++) s += red[tid][p];
    nf[tid] = rsqrtf(s + 1e-6f);
  }
  __syncthreads();
#pragma unroll
  for (int it = 0; it < 8; it++) {
    int row = lr + it * 4;
    float f = nf[row];
    qs[row][dd] *= f; qs[row][dd + 1] *= f; qs[row][dd + 2] *= f; qs[row][dd + 3] *= f;
  }
  {
    int c = tid >> 3, p = tid & 7;
    float s = 0.f;
    for (int d = p * 32; d < p * 32 + 32; d++) { float v = ks[c][d]; s += v * v; }
    red[c][p] = s;
  }
  __syncthreads();
  if (tid < CH) {
    float s = 0.f;
    for (int p = 0; p < 8; p++) s += red[tid][p];
    nf[tid] = rsqrtf(s + 1e-6f);
  }
  __syncthreads();
#pragma unroll
  for (int it = 0; it < 8; it++) {
    int row = lr + it * 4;
    float f = nf[row];
    ks[row][dd] *= f; ks[row][dd + 1] *= f; ks[row][dd + 2] *= f; ks[row][dd + 3] *= f;
  }
  __syncthreads();

  long abase = ((long)(b * H_ + h) * NCH + ci) * (CH * CH);
#pragma unroll 1
  for (int r = 0; r < 4; r++) {
    int oid = tid + 256 * r;
    int i = oid >> 5, jj = oid & 31;
    float skk = 0.f, sqk = 0.f;
    for (int d = 0; d < D_; d += 4) {
      float4 ki = *(const float4*)&ks[i][d];
      float4 kj = *(const float4*)&ks[jj][d];
      float4 qi = *(const float4*)&qs[i][d];
      skk += ki.x * kj.x + ki.y * kj.y + ki.z * kj.z + ki.w * kj.w;
      sqk += qi.x * kj.x + qi.y * kj.y + qi.z * kj.z + qi.w * kj.w;
    }
    As[i][jj] = (jj < i) ? bet[i] * skk : 0.f;
    attnb[abase + oid] = (jj <= i) ? sqk : 0.f;
  }
  __syncthreads();

  if (tid < CH) {
    int jj = tid;
    for (int i = 0; i < CH; i++) {
      if (i < jj) { Xs[i][jj] = 0.f; continue; }
      float x = (i == jj) ? 1.f : 0.f;
      for (int m = jj; m < i; m++) x -= As[i][m] * Xs[m][jj];
      Xs[i][jj] = x;
    }
  }
  __syncthreads();

#pragma unroll
  for (int r = 0; r < 4; r++) {
    int oid = tid + 256 * r;
    int i = oid >> 5, m = oid & 31;
    As[i][m] = Xs[i][m] * bet[m];
  }
  __syncthreads();

  long cbase = ((long)(b * H_ + h) * NCH + ci) * (CH * D_);
#pragma unroll 1
  for (int c = 0; c < CH; c++) {
    float su = 0.f, sw = 0.f;
    for (int m = 0; m < CH; m++) {
      float xm = As[c][m];
      su = fmaf(xm, vs[m][tid], su);
      sw = fmaf(xm, ks[m][tid], sw);
    }
    ub[cbase + c * D_ + tid] = su;
    wb[cbase + c * D_ + tid] = f2b(sw);
  }
#pragma unroll 1
  for (int i = 0; i < CH; i++) {
    qn[cbase + i * D_ + tid] = f2b(qs[i][tid]);
    kn[cbase + i * D_ + tid] = f2b(ks[i][tid]);
  }
}

// ---------------------------------------------------------------------------
// Delta-rule scan v3: block = (b,h, 8-wide dv slice). Wave-local phases:
// lane identity c = l&31 (token row / dk group), j = 2*wave + (l>>5) (dv col).
// S rows are wave-private; u_adj in registers shared by __shfl.
// bf16 q/w/k staged in LDS with 5-bit XOR slot swizzle; double-buffered;
// ONE __syncthreads per chunk; register prefetch of chunk i+1.
// ---------------------------------------------------------------------------
__global__ __launch_bounds__(256)
void delta_scan(const u16* __restrict__ qn, const u16* __restrict__ kn,
                const float* __restrict__ ub, const u16* __restrict__ wb,
                const float* __restrict__ attnb, float* __restrict__ dout)
{
  __shared__ u16 qch[2][CH][256];
  __shared__ u16 wch[2][CH][256];
  __shared__ u16 kch[2][CH][256];
  __shared__ float att[2][CH][33];
  __shared__ float ST[8][264];

  const int bid = blockIdx.x;
  const int sl = bid & 31, h = (bid >> 5) & 3, b = bid >> 7;
  const int tid = threadIdx.x;
  const int wv = tid >> 6, l = tid & 63;
  const int c = l & 31;             // token row (A,B) and dk-group (C)
  const int j = 2 * wv + (l >> 5);  // dv column owned by this lane
  const int half = l & 32;          // shfl source offset
  const int J0 = sl * 8;
  const long bh = (long)(b * H_ + h);

  for (int i = tid; i < 8 * 264; i += 256) (&ST[0][0])[i] = 0.f;

  const int srow = tid >> 3;        // staging row 0..31
  const int s0 = (tid & 7) * 4;     // staging base slot

  uint4 qr[4], wr[4], kr[4];
  float4 ar;
  float ur;

  {
    const long cb = (bh * NCH) * (CH * D_);
    const long ab = (bh * NCH) * (CH * CH);
    const u16* qg = qn + cb + srow * D_;
    const u16* wg = wb + cb + srow * D_;
    const u16* kg = kn + cb + srow * D_;
#pragma unroll
    for (int t = 0; t < 4; t++) {
      qr[t] = *(const uint4*)(qg + (s0 + t) * 8);
      wr[t] = *(const uint4*)(wg + (s0 + t) * 8);
      kr[t] = *(const uint4*)(kg + (s0 + t) * 8);
    }
    ar = *(const float4*)(attnb + ab + tid * 4);
    ur = ub[cb + c * D_ + J0 + j];
  }

  for (int ci = 0; ci < NCH; ci++) {
    const int buf = ci & 1;
    // write prefetched chunk to LDS (swizzled)
#pragma unroll
    for (int t = 0; t < 4; t++) {
      const int sw = ((s0 + t) ^ srow) * 8;
      *(uint4*)&qch[buf][srow][sw] = qr[t];
      *(uint4*)&wch[buf][srow][sw] = wr[t];
      *(uint4*)&kch[buf][srow][sw] = kr[t];
    }
    att[buf][srow][s0 + 0] = ar.x;
    att[buf][srow][s0 + 1] = ar.y;
    att[buf][srow][s0 + 2] = ar.z;
    att[buf][srow][s0 + 3] = ar.w;
    const float u_cur = ur;
    __syncthreads();

    // prefetch next chunk into registers (hidden under compute)
    if (ci + 1 < NCH) {
      const long cb = (bh * NCH + ci + 1) * (CH * D_);
      const long ab = (bh * NCH + ci + 1) * (CH * CH);
      const u16* qg = qn + cb + srow * D_;
      const u16* wg = wb + cb + srow * D_;
      const u16* kg = kn + cb + srow * D_;
#pragma unroll
      for (int t = 0; t < 4; t++) {
        qr[t] = *(const uint4*)(qg + (s0 + t) * 8);
        wr[t] = *(const uint4*)(wg + (s0 + t) * 8);
        kr[t] = *(const uint4*)(kg + (s0 + t) * 8);
      }
      ar = *(const float4*)(attnb + ab + tid * 4);
      ur = ub[cb + c * D_ + J0 + j];
    }

    // phase A: aw = w_c . S_j ; aq = q_c . S_j   (S rows wave-private)
    float aw = 0.f, aq = 0.f;
#pragma unroll 8
    for (int s = 0; s < 32; s++) {
      const int sw = (s ^ c) * 8;
      const uint4 wvv = *(const uint4*)&wch[buf][c][sw];
      const uint4 qvv = *(const uint4*)&qch[buf][c][sw];
      const float4 sv0 = *(const float4*)&ST[j][s * 8];
      const float4 sv1 = *(const float4*)&ST[j][s * 8 + 4];
      aw = fmaf(blo(wvv.x), sv0.x, aw); aw = fmaf(bhi(wvv.x), sv0.y, aw);
      aw = fmaf(blo(wvv.y), sv0.z, aw); aw = fmaf(bhi(wvv.y), sv0.w, aw);
      aw = fmaf(blo(wvv.z), sv1.x, aw); aw = fmaf(bhi(wvv.z), sv1.y, aw);
      aw = fmaf(blo(wvv.w), sv1.z, aw); aw = fmaf(bhi(wvv.w), sv1.w, aw);
      aq = fmaf(blo(qvv.x), sv0.x, aq); aq = fmaf(bhi(qvv.x), sv0.y, aq);
      aq = fmaf(blo(qvv.y), sv0.z, aq); aq = fmaf(bhi(qvv.y), sv0.w, aq);
      aq = fmaf(blo(qvv.z), sv1.x, aq); aq = fmaf(bhi(qvv.z), sv1.y, aq);
      aq = fmaf(blo(qvv.w), sv1.z, aq); aq = fmaf(bhi(qvv.w), sv1.w, aq);
    }
    const float ua_r = u_cur - aw;   // u_adj[c][J0+j], in register

    // phase B+C fused: o = aq + sum_m att[c][m]*ua[m][j];
    //                  Sacc[dk0+r] = sum_cc k[cc][dk0+r]*ua[cc][j]
    float o = aq;
    float a0 = 0.f, a1 = 0.f, a2 = 0.f, a3 = 0.f;
    float a4 = 0.f, a5 = 0.f, a6 = 0.f, a7 = 0.f;
#pragma unroll 8
    for (int cc = 0; cc < 32; cc++) {
      const float av = __shfl(ua_r, cc + half);
      o = fmaf(att[buf][c][cc], av, o);
      const uint4 kv = *(const uint4*)&kch[buf][cc][(c ^ cc) * 8];
      a0 = fmaf(blo(kv.x), av, a0); a1 = fmaf(bhi(kv.x), av, a1);
      a2 = fmaf(blo(kv.y), av, a2); a3 = fmaf(bhi(kv.y), av, a3);
      a4 = fmaf(blo(kv.z), av, a4); a5 = fmaf(bhi(kv.z), av, a5);
      a6 = fmaf(blo(kv.w), av, a6); a7 = fmaf(bhi(kv.w), av, a7);
    }
    dout[((long)b * L_ + ci * CH + c) * HID_ + h * D_ + J0 + j] = o;

    // S update: wave-private row j, lane-private dk group
    float4* sp0 = (float4*)&ST[j][c * 8];
    float4* sp1 = (float4*)&ST[j][c * 8 + 4];
    float4 v0 = *sp0, v1 = *sp1;
    v0.x += a0; v0.y += a1; v0.z += a2; v0.w += a3;
    v1.x += a4; v1.y += a5; v1.z += a6; v1.w += a7;
    *sp0 = v0; *sp1 = v1;
  }
}

// ---------------------------------------------------------------------------
// Fused 3-FIR depthwise causal conv on v (K=3,31,64). Tile 32 tok x 64 ch.
// ---------------------------------------------------------------------------
__global__ __launch_bounds__(256)
void fir3(const float* __restrict__ v, const float* __restrict__ fs_g,
          const float* __restrict__ fl_g, const float* __restrict__ fw_g,
          float* __restrict__ os, float* __restrict__ ol, float* __restrict__ ow)
{
  __shared__ float xs[95][64];
  __shared__ float fs[64][3];
  __shared__ float fl[64][31];
  __shared__ float fw[64][65];
  int bid = blockIdx.x;
  int ct = bid & 15, lt = bid >> 4;
  int c0 = ct * 64, tok0 = lt * 32;
  int bstart = (tok0 / L_) * L_;
  int tid = threadIdx.x;

  for (int idx = tid; idx < 95 * 64; idx += 256) {
    int r = idx >> 6, cc = idx & 63;
    int tok = tok0 - 63 + r;
    xs[r][cc] = (tok >= bstart) ? v[(long)tok * HID_ + c0 + cc] : 0.f;
  }
  for (int idx = tid; idx < 64 * 3; idx += 256) fs[idx / 3][idx % 3] = fs_g[(long)(c0 + idx / 3) * 3 + idx % 3];
  for (int idx = tid; idx < 64 * 31; idx += 256) fl[idx / 31][idx % 31] = fl_g[(long)(c0 + idx / 31) * 31 + idx % 31];
  for (int idx = tid; idx < 64 * 64; idx += 256) fw[idx >> 6][idx & 63] = fw_g[(long)(c0 + (idx >> 6)) * 64 + (idx & 63)];
  __syncthreads();

  int cc = tid & 63, lq = tid >> 6;
  int rb = lq * 8;
  float as8[8] = {0}, al8[8] = {0}, aw8[8] = {0};
#pragma unroll 1
  for (int t = 0; t < 64; t++) {
    float fv = fw[cc][t];
#pragma unroll
    for (int i = 0; i < 8; i++) aw8[i] = fmaf(xs[rb + i + t][cc], fv, aw8[i]);
  }
#pragma unroll 1
  for (int t = 0; t < 31; t++) {
    float fv = fl[cc][t];
#pragma unroll
    for (int i = 0; i < 8; i++) al8[i] = fmaf(xs[rb + 33 + i + t][cc], fv, al8[i]);
  }
#pragma unroll 1
  for (int t = 0; t < 3; t++) {
    float fv = fs[cc][t];
#pragma unroll
    for (int i = 0; i < 8; i++) as8[i] = fmaf(xs[rb + 61 + i + t][cc], fv, as8[i]);
  }
#pragma unroll
  for (int i = 0; i < 8; i++) {
    long o = (long)(tok0 + lq * 8 + i) * HID_ + c0 + cc;
    os[o] = as8[i]; ol[o] = al8[i]; ow[o] = aw8[i];
  }
}

// ---------------------------------------------------------------------------
// gate_in (bf16) = [hs | stats(short) | stats(long) | stats(wide) | stats(delta) | stats(v)]
// row stride 1088 (cols 1084..1087 zeroed)
// ---------------------------------------------------------------------------
__global__ __launch_bounds__(256)
void build_gate(const float* __restrict__ hs, const float* __restrict__ sb,
                const float* __restrict__ lb, const float* __restrict__ wbb,
                const float* __restrict__ db, const float* __restrict__ vb,
                u16* __restrict__ gate)
{
  int tok = blockIdx.x;
  int tid = threadIdx.x;
  u16* g = gate + (long)tok * 1088;
  const float* hrow = hs + (long)tok * HID_;
#pragma unroll
  for (int i = 0; i < 4; i++) g[tid + 256 * i] = f2b(hrow[tid + 256 * i]);
  if (tid < 4) g[1084 + tid] = 0;
  int h = tid >> 6, ln = tid & 63;
  const float* brs[5] = {sb, lb, wbb, db, vb};
#pragma unroll
  for (int bi = 0; bi < 5; bi++) {
    const float* x = brs[bi] + (long)tok * HID_ + h * D_;
    float s = 0.f, ss = 0.f, mx = 0.f;
#pragma unroll
    for (int i = 0; i < 4; i++) {
      float v = x[ln + 64 * i];
      s += v; ss += v * v; mx = fmaxf(mx, fabsf(v));
    }
#pragma unroll
    for (int off = 32; off >= 1; off >>= 1) {
      s += __shfl_xor(s, off);
      ss += __shfl_xor(ss, off);
      mx = fmaxf(mx, __shfl_xor(mx, off));
    }
    if (ln == 0) {
      g[1024 + bi * 12 + h] = f2b(s * (1.f / 256.f));
      g[1024 + bi * 12 + 4 + h] = f2b(sqrtf(fmaxf(ss * (1.f / 256.f), 1e-8f)));
      g[1024 + bi * 12 + 8 + h] = f2b(mx);
    }
  }
}

// ---------------------------------------------------------------------------
// Fused g2 (4096x20x2048) + softmax/temperature/floor mix + per-head RMSNorm
// Output omix in bf16.
// ---------------------------------------------------------------------------
__global__ __launch_bounds__(256)
void g2_mix(const float* __restrict__ hdn, const float* __restrict__ g2w,
            const float* __restrict__ g2b, const float* __restrict__ vbias,
            const float* __restrict__ ltemp, const float* __restrict__ flog,
            const float* __restrict__ onw,
            const float* __restrict__ sb, const float* __restrict__ lb,
            const float* __restrict__ wbb, const float* __restrict__ db,
            const float* __restrict__ vb, u16* __restrict__ omix)
{
  __shared__ float hrow[2048];
  __shared__ float lg[20];
  int tok = blockIdx.x;
  int tid = threadIdx.x;
  const float* hp = hdn + (long)tok * 2048;
#pragma unroll
  for (int i = 0; i < 8; i++) hrow[tid + 256 * i] = hp[tid + 256 * i];
  __syncthreads();
  int w = tid >> 6, ln = tid & 63;
#pragma unroll 1
  for (int q = 0; q < 5; q++) {
    int jj = w * 5 + q;
    const float* wr = g2w + (long)jj * 2048;
    float s = 0.f;
    for (int i = 0; i < 32; i++) s += hrow[ln + 64 * i] * wr[ln + 64 * i];
#pragma unroll
    for (int off = 32; off >= 1; off >>= 1) s += __shfl_xor(s, off);
    if (ln == 0) lg[jj] = s + g2b[jj];
  }
  __syncthreads();
  int h = w;
  float l[5];
#pragma unroll
  for (int j = 0; j < 5; j++) l[j] = lg[h * 5 + j];
  l[4] += vbias[h];
  float it = expf(-ltemp[h]);
#pragma unroll
  for (int j = 0; j < 5; j++) l[j] *= it;
  float mx = fmaxf(fmaxf(fmaxf(l[0], l[1]), fmaxf(l[2], l[3])), l[4]);
  float e[5], se = 0.f;
#pragma unroll
  for (int j = 0; j < 5; j++) { e[j] = expf(l[j] - mx); se += e[j]; }
  float inv = 1.f / se;
  float f = 1.f / (1.f + expf(-flog[h]));
  float sc = 1.f - 4.f * f;
  float wt[5];
#pragma unroll
  for (int j = 0; j < 4; j++) wt[j] = f + sc * e[j] * inv;
  wt[4] = sc * e[4] * inv;

  long base = (long)tok * HID_ + h * D_;
  float o[4], ss = 0.f;
#pragma unroll
  for (int i = 0; i < 4; i++) {
    int d = ln + 64 * i;
    o[i] = wt[0] * sb[base + d] + wt[1] * lb[base + d] + wt[2] * wbb[base + d]
         + wt[3] * db[base + d] + wt[4] * vb[base + d];
    ss += o[i] * o[i];
  }
#pragma unroll
  for (int off = 32; off >= 1; off >>= 1) ss += __shfl_xor(ss, off);
  float r = rsqrtf(ss * (1.f / 256.f) + 1e-5f);
#pragma unroll
  for (int i = 0; i < 4; i++) {
    int d = ln + 64 * i;
    omix[base + d] = f2b(o[i] * r * onw[d]);
  }
}

// ---------------------------------------------------------------------------
extern "C" void kernel_launch(void* const* d_in, const int* in_sizes, int n_in,
                              void* d_out, int out_size, void* d_ws, size_t ws_size,
                              hipStream_t stream)
{
  const float* hs    = (const float*)d_in[0];
  const float* q_w   = (const float*)d_in[1];
  const float* k_w   = (const float*)d_in[2];
  const float* v_w   = (const float*)d_in[3];
  const float* b_w   = (const float*)d_in[4];
  const float* convq = (const float*)d_in[5];
  const float* convk = (const float*)d_in[6];
  const float* convv = (const float*)d_in[7];
  const float* fir_s = (const float*)d_in[8];
  const float* fir_l = (const float*)d_in[9];
  const float* fir_w = (const float*)d_in[10];
  const float* g1w   = (const float*)d_in[11];
  const float* g1b   = (const float*)d_in[12];
  const float* g2w   = (const float*)d_in[13];
  const float* g2b   = (const float*)d_in[14];
  const float* vbias = (const float*)d_in[15];
  const float* ltemp = (const float*)d_in[16];
  const float* flog  = (const float*)d_in[17];
  const float* onw   = (const float*)d_in[18];
  const float* o_w   = (const float*)d_in[19];

  float* ws = (float*)d_ws;
  const long S1 = (long)NTOK * HID_;          // 4,194,304 floats
  float* qp     = ws + 0 * S1;
  float* kp     = ws + 1 * S1;
  float* vp     = ws + 2 * S1;
  float* qcv    = ws + 3 * S1;
  float* kcv    = ws + 4 * S1;
  float* vcv    = ws + 5 * S1;
  float* ubb    = ws + 6 * S1;
  float* deltab = ws + 7 * S1;
  u16*   qn_bf  = (u16*)(ws + 8 * S1);                  // 4M u16
  u16*   kn_bf  = (u16*)(ws + 8 * S1 + S1 / 2);
  u16*   wb_bf  = (u16*)(ws + 9 * S1);
  float* attnb  = ws + 9 * S1 + S1 / 2;                 // 524288 f32
  float* betab  = attnb + (long)B_ * H_ * NCH * CH * CH; // 16384 f32
  u16*   hs_bf  = (u16*)(ws + 10 * S1);                 // 4M u16
  u16*   qw_bf  = (u16*)(ws + 10 * S1 + S1 / 2);        // 1M u16 each
  u16*   kw_bf  = qw_bf + S1 / 4;
  u16*   vw_bf  = kw_bf + S1 / 4;
  u16*   ow_bf  = vw_bf + S1 / 4;
  u16*   g1w_bf = ow_bf + S1 / 4;                       // 2048*1088 u16
  // overlays (sources dead at time of write):
  u16*   gate_bf = (u16*)qcv;        // dead after delta_prep
  u16*   omix_bf = (u16*)kcv;        // dead after delta_prep
  float* hdnb    = ws + 8 * S1;      // over qn/kn/wb/attnb/betab (dead after scan)
  (void)in_sizes; (void)n_in; (void)out_size; (void)ws_size;

  dim3 blk(256);
  // precasts
  cast_bf<<<(NTOK * HID_) / 1024, blk, 0, stream>>>(hs, hs_bf, NTOK * HID_);
  cast_bf<<<(HID_ * HID_) / 1024, blk, 0, stream>>>(q_w, qw_bf, HID_ * HID_);
  cast_bf<<<(HID_ * HID_) / 1024, blk, 0, stream>>>(k_w, kw_bf, HID_ * HID_);
  cast_bf<<<(HID_ * HID_) / 1024, blk, 0, stream>>>(v_w, vw_bf, HID_ * HID_);
  cast_bf<<<(HID_ * HID_) / 1024, blk, 0, stream>>>(o_w, ow_bf, HID_ * HID_);
  pad_g1w<<<2048 * 1088 / 256, blk, 0, stream>>>(g1w, g1w_bf);
  // projections (bf16 MFMA)
  gemm_bf16<0><<<dim3(8, 32), blk, 0, stream>>>(hs_bf, qw_bf, nullptr, qp, NTOK, HID_, HID_);
  gemm_bf16<0><<<dim3(8, 32), blk, 0, stream>>>(hs_bf, kw_bf, nullptr, kp, NTOK, HID_, HID_);
  gemm_bf16<0><<<dim3(8, 32), blk, 0, stream>>>(hs_bf, vw_bf, nullptr, vp, NTOK, HID_, HID_);
  // causal conv K=4 + silu
  conv4_silu<<<NTOK * HID_ / 256, blk, 0, stream>>>(qp, convq, qcv);
  conv4_silu<<<NTOK * HID_ / 256, blk, 0, stream>>>(kp, convk, kcv);
  conv4_silu<<<NTOK * HID_ / 256, blk, 0, stream>>>(vp, convv, vcv);
  // beta
  beta_proj<<<NTOK * H_ / 256, blk, 0, stream>>>(hs, b_w, betab);
  // delta rule
  delta_prep<<<B_ * H_ * NCH, blk, 0, stream>>>(qcv, kcv, vcv, betab, qn_bf, kn_bf, ubb, wb_bf, attnb);
  delta_scan<<<B_ * H_ * 32, blk, 0, stream>>>(qn_bf, kn_bf, ubb, wb_bf, attnb, deltab);
  // FIR branches (write over qp/kp/vp — dead after conv)
  fir3<<<(NTOK / 32) * (HID_ / 64), blk, 0, stream>>>(vcv, fir_s, fir_l, fir_w, qp, kp, vp);
  // gate input assembly (bf16)
  build_gate<<<NTOK, blk, 0, stream>>>(hs, qp, kp, vp, deltab, vcv, gate_bf);
  // gate MLP (bf16 MFMA + GELU)
  gemm_bf16<1><<<dim3(16, 32), blk, 0, stream>>>(gate_bf, g1w_bf, g1b, hdnb, NTOK, 2048, 1088);
  g2_mix<<<NTOK, blk, 0, stream>>>(hdnb, g2w, g2b, vbias, ltemp, flog, onw,
                                   qp, kp, vp, deltab, vcv, omix_bf);
  // output projection
  gemm_bf16<0><<<dim3(8, 32), blk, 0, stream>>>(omix_bf, ow_bf, nullptr, (float*)d_out, NTOK, HID_, HID_);
}

// Round 6
// 954.692 us; speedup vs baseline: 1.6685x; 1.2003x over previous
//
#include <hip/hip_runtime.h>

#define B_ 2
#define L_ 2048
#define HID_ 1024
#define H_ 4
#define D_ 256
#define NTOK 4096
#define CH 32
#define NCH 64

typedef short s16x8 __attribute__((ext_vector_type(8)));
typedef float f32x4 __attribute__((ext_vector_type(4)));
typedef unsigned short u16;
typedef unsigned int u32;

__device__ __forceinline__ u16 f2b(float f) {  // RNE fp32->bf16
  u32 u = __float_as_uint(f);
  u32 r = (u + 0x7fffu + ((u >> 16) & 1u)) >> 16;
  return (u16)r;
}
__device__ __forceinline__ float b2f(u16 h) { return __uint_as_float((u32)h << 16); }
__device__ __forceinline__ float blo(u32 u) { return __uint_as_float(u << 16); }
__device__ __forceinline__ float bhi(u32 u) { return __uint_as_float(u & 0xffff0000u); }

union U4S8 { uint4 u; s16x8 s; };
__device__ __forceinline__ s16x8 as_s16x8(uint4 u) { U4S8 x; x.u = u; return x.s; }

// ---------------------------------------------------------------------------
// cast fp32 -> bf16, n multiple of 4
// ---------------------------------------------------------------------------
__global__ __launch_bounds__(256)
void cast_bf(const float* __restrict__ in, u16* __restrict__ out, int n)
{
  int id = (blockIdx.x * 256 + threadIdx.x) * 4;
  if (id >= n) return;
  float4 v = *(const float4*)(in + id);
  ushort4 o;
  o.x = f2b(v.x); o.y = f2b(v.y); o.z = f2b(v.z); o.w = f2b(v.w);
  *(ushort4*)(out + id) = o;
}

// ---------------------------------------------------------------------------
// bf16 MFMA GEMM: C[M][N](f32) = act(A_bf[M][K] @ W_bf[N][K]^T + bias)
// ---------------------------------------------------------------------------
template<int ACT>
__global__ __launch_bounds__(256)
void gemm_bf16(const u16* __restrict__ A, const u16* __restrict__ W,
               const float* __restrict__ bias, float* __restrict__ C,
               int M, int N, int K)
{
  __shared__ u16 Als[128][64];
  __shared__ u16 Bls[128][64];
  const int tid = threadIdx.x;
  const int n0 = blockIdx.x * 128;
  const int m0 = blockIdx.y * 128;
  const int l = tid & 63, w = tid >> 6;
  const int wm = w >> 1, wn = w & 1;
  const int r15 = l & 15, g = l >> 4;
  const int srow = tid >> 1, sh = tid & 1;

  f32x4 acc[4][4];
#pragma unroll
  for (int i = 0; i < 4; i++)
#pragma unroll
    for (int j = 0; j < 4; j++) acc[i][j] = (f32x4){0.f, 0.f, 0.f, 0.f};

  const long arowoff = (long)(m0 + srow) * K + sh * 32;
  const long browoff = (long)(n0 + srow) * K + sh * 32;
  uint4 ra[4], rb[4];
#pragma unroll
  for (int j2 = 0; j2 < 4; j2++) {
    ra[j2] = *(const uint4*)(A + arowoff + j2 * 8);
    rb[j2] = *(const uint4*)(W + browoff + j2 * 8);
  }
  const int NS = K >> 6;
  for (int s = 0; s < NS; ++s) {
    __syncthreads();
#pragma unroll
    for (int j2 = 0; j2 < 4; j2++) {
      int slot = (sh * 4 + j2) ^ (srow & 7);
      *(uint4*)&Als[srow][slot * 8] = ra[j2];
      *(uint4*)&Bls[srow][slot * 8] = rb[j2];
    }
    __syncthreads();
    if (s + 1 < NS) {
      long k0 = (long)(s + 1) * 64;
#pragma unroll
      for (int j2 = 0; j2 < 4; j2++) {
        ra[j2] = *(const uint4*)(A + arowoff + k0 + j2 * 8);
        rb[j2] = *(const uint4*)(W + browoff + k0 + j2 * 8);
      }
    }
#pragma unroll
    for (int kk2 = 0; kk2 < 2; kk2++) {
      s16x8 af[4], bf[4];
      int slot = ((kk2 * 4 + g) ^ (r15 & 7)) * 8;
#pragma unroll
      for (int mt = 0; mt < 4; mt++)
        af[mt] = *(const s16x8*)&Als[64 * wm + mt * 16 + r15][slot];
#pragma unroll
      for (int nt = 0; nt < 4; nt++)
        bf[nt] = *(const s16x8*)&Bls[64 * wn + nt * 16 + r15][slot];
#pragma unroll
      for (int mt = 0; mt < 4; mt++)
#pragma unroll
        for (int nt = 0; nt < 4; nt++)
          acc[mt][nt] = __builtin_amdgcn_mfma_f32_16x16x32_bf16(af[mt], bf[nt], acc[mt][nt], 0, 0, 0);
    }
  }

#pragma unroll
  for (int mt = 0; mt < 4; mt++) {
#pragma unroll
    for (int nt = 0; nt < 4; nt++) {
      int m = m0 + 64 * wm + mt * 16 + g * 4;
      int n = n0 + 64 * wn + nt * 16 + r15;
      float bv = (ACT == 1) ? bias[n] : 0.f;
#pragma unroll
      for (int r = 0; r < 4; r++) {
        float v = acc[mt][nt][r];
        if (ACT == 1) {
          v += bv;
          v = 0.5f * v * (1.f + erff(v * 0.70710678118654752f));
        }
        C[(long)(m + r) * N + n] = v;
      }
    }
  }
}

// ---------------------------------------------------------------------------
// Depthwise causal conv (K=4) + SiLU.  x,y: [NTOK][HID], w: [HID][4]
// ---------------------------------------------------------------------------
__global__ __launch_bounds__(256)
void conv4_silu(const float* __restrict__ x, const float* __restrict__ w4,
                float* __restrict__ y)
{
  int id = blockIdx.x * 256 + threadIdx.x;
  int c = id & (HID_ - 1);
  int tok = id >> 10;
  int l = tok & (L_ - 1);
  float s = 0.f;
#pragma unroll
  for (int t = 0; t < 4; t++) {
    int lt = l - 3 + t;
    if (lt >= 0) s += x[(long)(tok - 3 + t) * HID_ + c] * w4[c * 4 + t];
  }
  y[id] = s / (1.f + expf(-s));
}

// ---------------------------------------------------------------------------
// beta = sigmoid(hs @ b_w^T): [NTOK][4]
// ---------------------------------------------------------------------------
__global__ __launch_bounds__(256)
void beta_proj(const float* __restrict__ hs, const float* __restrict__ bw,
               float* __restrict__ beta)
{
  int id = blockIdx.x * 256 + threadIdx.x;   // < NTOK*H_
  int h = id & 3;
  int tok = id >> 2;
  const float4* a = (const float4*)(hs + (long)tok * HID_);
  const float4* w = (const float4*)(bw + (long)h * HID_);
  float s = 0.f;
  for (int k = 0; k < HID_ / 4; k++) {
    float4 av = a[k], wv = w[k];
    s += av.x * wv.x + av.y * wv.y + av.z * wv.z + av.w * wv.w;
  }
  beta[id] = 1.f / (1.f + expf(-s));
}

// ---------------------------------------------------------------------------
// g1 weight pad+cast: [2048][1084] f32 -> [2048][1088] bf16 (zero fill)
// ---------------------------------------------------------------------------
__global__ __launch_bounds__(256)
void pad_g1w(const float* __restrict__ g1w, u16* __restrict__ out)
{
  int id = blockIdx.x * 256 + threadIdx.x;   // < 2048*1088
  int k = id % 1088;
  int n = id / 1088;
  out[id] = (k < 1084) ? f2b(g1w[(long)n * 1084 + k]) : (u16)0;
}

// ---------------------------------------------------------------------------
// Delta-rule chunk prep: per (b,h,chunk): l2norm q/k, A, (I+A)^-1, u, w, attn.
// Outputs: qn,wb bf16 [c][256]; ktb bf16 [dk=256][c=32]; attn hi/lo bf16
// [32][32]; ub f32 [c][256].
// ---------------------------------------------------------------------------
__global__ __launch_bounds__(256)
void delta_prep(const float* __restrict__ qc, const float* __restrict__ kc,
                const float* __restrict__ vc, const float* __restrict__ beta,
                u16* __restrict__ qn, u16* __restrict__ ktb,
                float* __restrict__ ub, u16* __restrict__ wb,
                u16* __restrict__ attnb, u16* __restrict__ attnlo)
{
  __shared__ float qs[CH][260], ks[CH][260], vs[CH][260];
  __shared__ float Xs[CH][33], As[CH][33];
  __shared__ float red[CH][8];
  __shared__ float bet[CH], nf[CH];

  int bid = blockIdx.x;
  int ci = bid & 63, h = (bid >> 6) & 3, b = bid >> 8;
  int tid = threadIdx.x;
  long tok0 = (long)b * L_ + (long)ci * CH;
  const float* qsrc = qc + tok0 * HID_ + h * D_;
  const float* ksrc = kc + tok0 * HID_ + h * D_;
  const float* vsrc = vc + tok0 * HID_ + h * D_;
  int lr = tid >> 6;
  int dd = (tid & 63) << 2;

#pragma unroll
  for (int it = 0; it < 8; it++) {
    int row = lr + it * 4;
    *(float4*)&qs[row][dd] = *(const float4*)(qsrc + (long)row * HID_ + dd);
    *(float4*)&ks[row][dd] = *(const float4*)(ksrc + (long)row * HID_ + dd);
    *(float4*)&vs[row][dd] = *(const float4*)(vsrc + (long)row * HID_ + dd);
  }
  if (tid < CH) bet[tid] = beta[(tok0 + tid) * H_ + h];
  __syncthreads();

  {
    int c = tid >> 3, p = tid & 7;
    float s = 0.f;
    for (int d = p * 32; d < p * 32 + 32; d++) { float v = qs[c][d]; s += v * v; }
    red[c][p] = s;
  }
  __syncthreads();
  if (tid < CH) {
    float s = 0.f;
    for (int p = 0; p < 8; p++) s += red[tid][p];
    nf[tid] = rsqrtf(s + 1e-6f);
  }
  __syncthreads();
#pragma unroll
  for (int it = 0; it < 8; it++) {
    int row = lr + it * 4;
    float f = nf[row];
    qs[row][dd] *= f; qs[row][dd + 1] *= f; qs[row][dd + 2] *= f; qs[row][dd + 3] *= f;
  }
  {
    int c = tid >> 3, p = tid & 7;
    float s = 0.f;
    for (int d = p * 32; d < p * 32 + 32; d++) { float v = ks[c][d]; s += v * v; }
    red[c][p] = s;
  }
  __syncthreads();
  if (tid < CH) {
    float s = 0.f;
    for (int p = 0; p < 8; p++) s += red[tid][p];
    nf[tid] = rsqrtf(s + 1e-6f);
  }
  __syncthreads();
#pragma unroll
  for (int it = 0; it < 8; it++) {
    int row = lr + it * 4;
    float f = nf[row];
    ks[row][dd] *= f; ks[row][dd + 1] *= f; ks[row][dd + 2] *= f; ks[row][dd + 3] *= f;
  }
  __syncthreads();

  long abase = ((long)(b * H_ + h) * NCH + ci) * (CH * CH);
#pragma unroll 1
  for (int r = 0; r < 4; r++) {
    int oid = tid + 256 * r;
    int i = oid >> 5, jj = oid & 31;
    float skk = 0.f, sqk = 0.f;
    for (int d = 0; d < D_; d += 4) {
      float4 ki = *(const float4*)&ks[i][d];
      float4 kj = *(const float4*)&ks[jj][d];
      float4 qi = *(const float4*)&qs[i][d];
      skk += ki.x * kj.x + ki.y * kj.y + ki.z * kj.z + ki.w * kj.w;
      sqk += qi.x * kj.x + qi.y * kj.y + qi.z * kj.z + qi.w * kj.w;
    }
    As[i][jj] = (jj < i) ? bet[i] * skk : 0.f;
    float sv = (jj <= i) ? sqk : 0.f;
    u16 hi16 = f2b(sv);
    attnb[abase + oid] = hi16;
    attnlo[abase + oid] = f2b(sv - b2f(hi16));
  }
  __syncthreads();

  if (tid < CH) {
    int jj = tid;
    for (int i = 0; i < CH; i++) {
      if (i < jj) { Xs[i][jj] = 0.f; continue; }
      float x = (i == jj) ? 1.f : 0.f;
      for (int m = jj; m < i; m++) x -= As[i][m] * Xs[m][jj];
      Xs[i][jj] = x;
    }
  }
  __syncthreads();

#pragma unroll
  for (int r = 0; r < 4; r++) {
    int oid = tid + 256 * r;
    int i = oid >> 5, m = oid & 31;
    As[i][m] = Xs[i][m] * bet[m];
  }
  __syncthreads();

  long cbase = ((long)(b * H_ + h) * NCH + ci) * (CH * D_);
#pragma unroll 1
  for (int c = 0; c < CH; c++) {
    float su = 0.f, sw = 0.f;
    for (int m = 0; m < CH; m++) {
      float xm = As[c][m];
      su = fmaf(xm, vs[m][tid], su);
      sw = fmaf(xm, ks[m][tid], sw);
    }
    ub[cbase + c * D_ + tid] = su;
    wb[cbase + c * D_ + tid] = f2b(sw);
  }
#pragma unroll 1
  for (int i = 0; i < CH; i++) {
    qn[cbase + i * D_ + tid] = f2b(qs[i][tid]);
  }
  // kt[dk=tid][c] = kn[c][dk] (bf16, packed pairs)
  {
    u32 pk[16];
#pragma unroll
    for (int c2 = 0; c2 < 16; c2++) {
      float a = ks[2 * c2][tid], b2 = ks[2 * c2 + 1][tid];
      asm("v_cvt_pk_bf16_f32 %0, %1, %2" : "=v"(pk[c2]) : "v"(a), "v"(b2));
    }
    u16* kq = ktb + ((long)(b * H_ + h) * NCH + ci) * (D_ * CH) + (long)tid * CH;
    *(uint4*)(kq + 0)  = make_uint4(pk[0], pk[1], pk[2], pk[3]);
    *(uint4*)(kq + 8)  = make_uint4(pk[4], pk[5], pk[6], pk[7]);
    *(uint4*)(kq + 16) = make_uint4(pk[8], pk[9], pk[10], pk[11]);
    *(uint4*)(kq + 24) = make_uint4(pk[12], pk[13], pk[14], pk[15]);
  }
}

// ---------------------------------------------------------------------------
// D-layout (two 16x16 f32 tiles) -> hi/lo bf16 B-operand fragments.
// FIX (R5 bug): tile select must happen AFTER the shuffle — __shfl returns the
// SOURCE lane's pre-selected value, and source tsel != dest tsel. Shuffle both
// tiles, then v_cndmask by the destination's hi>>1.
// ---------------------------------------------------------------------------
__device__ __forceinline__ void d2b2(f32x4 Ta, f32x4 Tb, int v, int hi,
                                     s16x8* hiF, s16x8* loF)
{
  const bool tb = (hi >> 1) != 0;
  const int base = v + ((hi & 1) << 5);
  float y[8];
#pragma unroll
  for (int r = 0; r < 4; r++) {
    float a0 = __shfl(Ta[r], base);
    float b0 = __shfl(Tb[r], base);
    float a1 = __shfl(Ta[r], base + 16);
    float b1 = __shfl(Tb[r], base + 16);
    y[r] = tb ? b0 : a0;
    y[4 + r] = tb ? b1 : a1;
  }
  u32 h0, h1, h2, h3;
  asm("v_cvt_pk_bf16_f32 %0, %1, %2" : "=v"(h0) : "v"(y[0]), "v"(y[1]));
  asm("v_cvt_pk_bf16_f32 %0, %1, %2" : "=v"(h1) : "v"(y[2]), "v"(y[3]));
  asm("v_cvt_pk_bf16_f32 %0, %1, %2" : "=v"(h2) : "v"(y[4]), "v"(y[5]));
  asm("v_cvt_pk_bf16_f32 %0, %1, %2" : "=v"(h3) : "v"(y[6]), "v"(y[7]));
  float z0 = y[0] - blo(h0), z1 = y[1] - bhi(h0);
  float z2 = y[2] - blo(h1), z3 = y[3] - bhi(h1);
  float z4 = y[4] - blo(h2), z5 = y[5] - bhi(h2);
  float z6 = y[6] - blo(h3), z7 = y[7] - bhi(h3);
  u32 l0, l1, l2, l3;
  asm("v_cvt_pk_bf16_f32 %0, %1, %2" : "=v"(l0) : "v"(z0), "v"(z1));
  asm("v_cvt_pk_bf16_f32 %0, %1, %2" : "=v"(l1) : "v"(z2), "v"(z3));
  asm("v_cvt_pk_bf16_f32 %0, %1, %2" : "=v"(l2) : "v"(z4), "v"(z5));
  asm("v_cvt_pk_bf16_f32 %0, %1, %2" : "=v"(l3) : "v"(z6), "v"(z7));
  U4S8 xh; xh.u = make_uint4(h0, h1, h2, h3);
  U4S8 xl; xl.u = make_uint4(l0, l1, l2, l3);
  *hiF = xh.s; *loF = xl.s;
}

// ---------------------------------------------------------------------------
// Delta-rule scan v6 (MFMA, split precision, fixed d2b2).
// 1 wave per (b,h,16 dv cols). S[256dk x 16dv] in 16 f32x4 accumulators.
// ---------------------------------------------------------------------------
__global__ __launch_bounds__(64, 1)
void delta_scan(const u16* __restrict__ qn, const u16* __restrict__ ktb,
                const float* __restrict__ ub, const u16* __restrict__ wb,
                const u16* __restrict__ attnb, const u16* __restrict__ attnlo,
                float* __restrict__ dout)
{
  const int bid = blockIdx.x;                 // 128
  const int sl = bid & 15, h = (bid >> 4) & 3, b = bid >> 6;
  const int l = threadIdx.x;
  const int v = l & 15, hi = l >> 4;
  const int dv0 = sl * 16;
  const long bh = (long)(b * H_ + h);

  f32x4 St[16];
#pragma unroll
  for (int t = 0; t < 16; t++) St[t] = (f32x4){0.f, 0.f, 0.f, 0.f};

#pragma unroll 1
  for (int ci = 0; ci < NCH; ci++) {
    const long cb = (bh * NCH + ci) * (CH * D_);
    const long kb = (bh * NCH + ci) * (D_ * CH);
    const long ab = (bh * NCH + ci) * (CH * CH);

    // ---- issue all global loads for this chunk ----
    uint4 Wf[2][8], Qf[2][8], KTf[16], ATh[2], ATl[2];
    float Uld[2][4];
#pragma unroll
    for (int mt = 0; mt < 2; mt++)
#pragma unroll
      for (int kt = 0; kt < 8; kt++) {
        const long ro = cb + (long)(mt * 16 + v) * D_ + kt * 32 + hi * 8;
        Wf[mt][kt] = *(const uint4*)(wb + ro);
        Qf[mt][kt] = *(const uint4*)(qn + ro);
      }
#pragma unroll
    for (int t = 0; t < 16; t++)
      KTf[t] = *(const uint4*)(ktb + kb + (long)(t * 16 + v) * CH + hi * 8);
#pragma unroll
    for (int mt = 0; mt < 2; mt++) {
      ATh[mt] = *(const uint4*)(attnb + ab + (long)(mt * 16 + v) * CH + hi * 8);
      ATl[mt] = *(const uint4*)(attnlo + ab + (long)(mt * 16 + v) * CH + hi * 8);
    }
#pragma unroll
    for (int mt = 0; mt < 2; mt++)
#pragma unroll
      for (int r = 0; r < 4; r++)
        Uld[mt][r] = ub[cb + (long)(mt * 16 + hi * 4 + r) * D_ + dv0 + v];

    // ---- convert S: D-layout accumulators -> hi/lo bf16 B-fragments ----
    s16x8 Sbh[8], Sbl[8];
#pragma unroll
    for (int kt = 0; kt < 8; kt++)
      d2b2(St[2 * kt], St[2 * kt + 1], v, hi, &Sbh[kt], &Sbl[kt]);

    // ---- aw = W@S, aq = Q@S (hi+lo) ----
    f32x4 awt[2], aqt[2];
#pragma unroll
    for (int mt = 0; mt < 2; mt++) { awt[mt] = (f32x4){0.f,0.f,0.f,0.f}; aqt[mt] = (f32x4){0.f,0.f,0.f,0.f}; }
#pragma unroll
    for (int kt = 0; kt < 8; kt++) {
#pragma unroll
      for (int mt = 0; mt < 2; mt++) {
        awt[mt] = __builtin_amdgcn_mfma_f32_16x16x32_bf16(as_s16x8(Wf[mt][kt]), Sbh[kt], awt[mt], 0, 0, 0);
        awt[mt] = __builtin_amdgcn_mfma_f32_16x16x32_bf16(as_s16x8(Wf[mt][kt]), Sbl[kt], awt[mt], 0, 0, 0);
        aqt[mt] = __builtin_amdgcn_mfma_f32_16x16x32_bf16(as_s16x8(Qf[mt][kt]), Sbh[kt], aqt[mt], 0, 0, 0);
        aqt[mt] = __builtin_amdgcn_mfma_f32_16x16x32_bf16(as_s16x8(Qf[mt][kt]), Sbl[kt], aqt[mt], 0, 0, 0);
      }
    }

    // ---- u_adj = u - aw (D-layout), convert to hi/lo B-frags ----
    f32x4 ua0, ua1;
#pragma unroll
    for (int r = 0; r < 4; r++) { ua0[r] = Uld[0][r] - awt[0][r]; ua1[r] = Uld[1][r] - awt[1][r]; }
    s16x8 UAh, UAl;
    d2b2(ua0, ua1, v, hi, &UAh, &UAl);

    // ---- o = aq + attn @ u_adj ; store ----
    f32x4 ot[2];
#pragma unroll
    for (int mt = 0; mt < 2; mt++) {
      ot[mt] = __builtin_amdgcn_mfma_f32_16x16x32_bf16(as_s16x8(ATh[mt]), UAh, aqt[mt], 0, 0, 0);
      ot[mt] = __builtin_amdgcn_mfma_f32_16x16x32_bf16(as_s16x8(ATh[mt]), UAl, ot[mt], 0, 0, 0);
      ot[mt] = __builtin_amdgcn_mfma_f32_16x16x32_bf16(as_s16x8(ATl[mt]), UAh, ot[mt], 0, 0, 0);
    }
#pragma unroll
    for (int mt = 0; mt < 2; mt++)
#pragma unroll
      for (int r = 0; r < 4; r++)
        dout[((long)b * L_ + ci * CH + mt * 16 + hi * 4 + r) * HID_ + h * D_ + dv0 + v] = ot[mt][r];

    // ---- S += K^T @ u_adj (hi+lo, accumulate in place) ----
#pragma unroll
    for (int t = 0; t < 16; t++) {
      St[t] = __builtin_amdgcn_mfma_f32_16x16x32_bf16(as_s16x8(KTf[t]), UAh, St[t], 0, 0, 0);
      St[t] = __builtin_amdgcn_mfma_f32_16x16x32_bf16(as_s16x8(KTf[t]), UAl, St[t], 0, 0, 0);
    }
  }
}

// ---------------------------------------------------------------------------
// Fused 3-FIR depthwise causal conv on v (K=3,31,64). Tile 32 tok x 64 ch.
// ---------------------------------------------------------------------------
__global__ __launch_bounds__(256)
void fir3(const float* __restrict__ v, const float* __restrict__ fs_g,
          const float* __restrict__ fl_g, const float* __restrict__ fw_g,
          float* __restrict__ os, float* __restrict__ ol, float* __restrict__ ow)
{
  __shared__ float xs[95][64];
  __shared__ float fs[64][3];
  __shared__ float fl[64][31];
  __shared__ float fw[64][65];
  int bid = blockIdx.x;
  int ct = bid & 15, lt = bid >> 4;
  int c0 = ct * 64, tok0 = lt * 32;
  int bstart = (tok0 / L_) * L_;
  int tid = threadIdx.x;

  for (int idx = tid; idx < 95 * 64; idx += 256) {
    int r = idx >> 6, cc = idx & 63;
    int tok = tok0 - 63 + r;
    xs[r][cc] = (tok >= bstart) ? v[(long)tok * HID_ + c0 + cc] : 0.f;
  }
  for (int idx = tid; idx < 64 * 3; idx += 256) fs[idx / 3][idx % 3] = fs_g[(long)(c0 + idx / 3) * 3 + idx % 3];
  for (int idx = tid; idx < 64 * 31; idx += 256) fl[idx / 31][idx % 31] = fl_g[(long)(c0 + idx / 31) * 31 + idx % 31];
  for (int idx = tid; idx < 64 * 64; idx += 256) fw[idx >> 6][idx & 63] = fw_g[(long)(c0 + (idx >> 6)) * 64 + (idx & 63)];
  __syncthreads();

  int cc = tid & 63, lq = tid >> 6;
  int rb = lq * 8;
  float as8[8] = {0}, al8[8] = {0}, aw8[8] = {0};
#pragma unroll 1
  for (int t = 0; t < 64; t++) {
    float fv = fw[cc][t];
#pragma unroll
    for (int i = 0; i < 8; i++) aw8[i] = fmaf(xs[rb + i + t][cc], fv, aw8[i]);
  }
#pragma unroll 1
  for (int t = 0; t < 31; t++) {
    float fv = fl[cc][t];
#pragma unroll
    for (int i = 0; i < 8; i++) al8[i] = fmaf(xs[rb + 33 + i + t][cc], fv, al8[i]);
  }
#pragma unroll 1
  for (int t = 0; t < 3; t++) {
    float fv = fs[cc][t];
#pragma unroll
    for (int i = 0; i < 8; i++) as8[i] = fmaf(xs[rb + 61 + i + t][cc], fv, as8[i]);
  }
#pragma unroll
  for (int i = 0; i < 8; i++) {
    long o = (long)(tok0 + lq * 8 + i) * HID_ + c0 + cc;
    os[o] = as8[i]; ol[o] = al8[i]; ow[o] = aw8[i];
  }
}

// ---------------------------------------------------------------------------
// gate_in (bf16) = [hs | stats x5], row stride 1088 (cols 1084..1087 zero)
// ---------------------------------------------------------------------------
__global__ __launch_bounds__(256)
void build_gate(const float* __restrict__ hs, const float* __restrict__ sb,
                const float* __restrict__ lb, const float* __restrict__ wbb,
                const float* __restrict__ db, const float* __restrict__ vb,
                u16* __restrict__ gate)
{
  int tok = blockIdx.x;
  int tid = threadIdx.x;
  u16* g = gate + (long)tok * 1088;
  const float* hrow = hs + (long)tok * HID_;
#pragma unroll
  for (int i = 0; i < 4; i++) g[tid + 256 * i] = f2b(hrow[tid + 256 * i]);
  if (tid < 4) g[1084 + tid] = 0;
  int h = tid >> 6, ln = tid & 63;
  const float* brs[5] = {sb, lb, wbb, db, vb};
#pragma unroll
  for (int bi = 0; bi < 5; bi++) {
    const float* x = brs[bi] + (long)tok * HID_ + h * D_;
    float s = 0.f, ss = 0.f, mx = 0.f;
#pragma unroll
    for (int i = 0; i < 4; i++) {
      float v = x[ln + 64 * i];
      s += v; ss += v * v; mx = fmaxf(mx, fabsf(v));
    }
#pragma unroll
    for (int off = 32; off >= 1; off >>= 1) {
      s += __shfl_xor(s, off);
      ss += __shfl_xor(ss, off);
      mx = fmaxf(mx, __shfl_xor(mx, off));
    }
    if (ln == 0) {
      g[1024 + bi * 12 + h] = f2b(s * (1.f / 256.f));
      g[1024 + bi * 12 + 4 + h] = f2b(sqrtf(fmaxf(ss * (1.f / 256.f), 1e-8f)));
      g[1024 + bi * 12 + 8 + h] = f2b(mx);
    }
  }
}

// ---------------------------------------------------------------------------
// Fused g2 (4096x20x2048) + softmax/temperature/floor mix + per-head RMSNorm
// ---------------------------------------------------------------------------
__global__ __launch_bounds__(256)
void g2_mix(const float* __restrict__ hdn, const float* __restrict__ g2w,
            const float* __restrict__ g2b, const float* __restrict__ vbias,
            const float* __restrict__ ltemp, const float* __restrict__ flog,
            const float* __restrict__ onw,
            const float* __restrict__ sb, const float* __restrict__ lb,
            const float* __restrict__ wbb, const float* __restrict__ db,
            const float* __restrict__ vb, u16* __restrict__ omix)
{
  __shared__ float hrow[2048];
  __shared__ float lg[20];
  int tok = blockIdx.x;
  int tid = threadIdx.x;
  const float* hp = hdn + (long)tok * 2048;
#pragma unroll
  for (int i = 0; i < 8; i++) hrow[tid + 256 * i] = hp[tid + 256 * i];
  __syncthreads();
  int w = tid >> 6, ln = tid & 63;
#pragma unroll 1
  for (int q = 0; q < 5; q++) {
    int jj = w * 5 + q;
    const float* wr = g2w + (long)jj * 2048;
    float s = 0.f;
    for (int i = 0; i < 32; i++) s += hrow[ln + 64 * i] * wr[ln + 64 * i];
#pragma unroll
    for (int off = 32; off >= 1; off >>= 1) s += __shfl_xor(s, off);
    if (ln == 0) lg[jj] = s + g2b[jj];
  }
  __syncthreads();
  int h = w;
  float l[5];
#pragma unroll
  for (int j = 0; j < 5; j++) l[j] = lg[h * 5 + j];
  l[4] += vbias[h];
  float it = expf(-ltemp[h]);
#pragma unroll
  for (int j = 0; j < 5; j++) l[j] *= it;
  float mx = fmaxf(fmaxf(fmaxf(l[0], l[1]), fmaxf(l[2], l[3])), l[4]);
  float e[5], se = 0.f;
#pragma unroll
  for (int j = 0; j < 5; j++) { e[j] = expf(l[j] - mx); se += e[j]; }
  float inv = 1.f / se;
  float f = 1.f / (1.f + expf(-flog[h]));
  float sc = 1.f - 4.f * f;
  float wt[5];
#pragma unroll
  for (int j = 0; j < 4; j++) wt[j] = f + sc * e[j] * inv;
  wt[4] = sc * e[4] * inv;

  long base = (long)tok * HID_ + h * D_;
  float o[4], ss = 0.f;
#pragma unroll
  for (int i = 0; i < 4; i++) {
    int d = ln + 64 * i;
    o[i] = wt[0] * sb[base + d] + wt[1] * lb[base + d] + wt[2] * wbb[base + d]
         + wt[3] * db[base + d] + wt[4] * vb[base + d];
    ss += o[i] * o[i];
  }
#pragma unroll
  for (int off = 32; off >= 1; off >>= 1) ss += __shfl_xor(ss, off);
  float r = rsqrtf(ss * (1.f / 256.f) + 1e-5f);
#pragma unroll
  for (int i = 0; i < 4; i++) {
    int d = ln + 64 * i;
    omix[base + d] = f2b(o[i] * r * onw[d]);
  }
}

// ---------------------------------------------------------------------------
extern "C" void kernel_launch(void* const* d_in, const int* in_sizes, int n_in,
                              void* d_out, int out_size, void* d_ws, size_t ws_size,
                              hipStream_t stream)
{
  const float* hs    = (const float*)d_in[0];
  const float* q_w   = (const float*)d_in[1];
  const float* k_w   = (const float*)d_in[2];
  const float* v_w   = (const float*)d_in[3];
  const float* b_w   = (const float*)d_in[4];
  const float* convq = (const float*)d_in[5];
  const float* convk = (const float*)d_in[6];
  const float* convv = (const float*)d_in[7];
  const float* fir_s = (const float*)d_in[8];
  const float* fir_l = (const float*)d_in[9];
  const float* fir_w = (const float*)d_in[10];
  const float* g1w   = (const float*)d_in[11];
  const float* g1b   = (const float*)d_in[12];
  const float* g2w   = (const float*)d_in[13];
  const float* g2b   = (const float*)d_in[14];
  const float* vbias = (const float*)d_in[15];
  const float* ltemp = (const float*)d_in[16];
  const float* flog  = (const float*)d_in[17];
  const float* onw   = (const float*)d_in[18];
  const float* o_w   = (const float*)d_in[19];

  float* ws = (float*)d_ws;
  const long S1 = (long)NTOK * HID_;          // 4,194,304 floats
  float* qp     = ws + 0 * S1;
  float* kp     = ws + 1 * S1;
  float* vp     = ws + 2 * S1;
  float* qcv    = ws + 3 * S1;
  float* kcv    = ws + 4 * S1;
  float* vcv    = ws + 5 * S1;
  float* ubb    = ws + 6 * S1;
  float* deltab = ws + 7 * S1;
  u16*   qn_bf  = (u16*)(ws + 8 * S1);                   // S1 u16
  u16*   kt_bf  = (u16*)(ws + 8 * S1 + S1 / 2);          // S1 u16 (transposed k)
  u16*   wb_bf  = (u16*)(ws + 9 * S1);                   // S1 u16
  u16*   attn_bf = (u16*)(ws + 9 * S1 + S1 / 2);         // 524288 u16
  float* betab  = (float*)(attn_bf + (long)B_ * H_ * NCH * CH * CH); // 16384 f32
  u16*   attn_lo = (u16*)(betab + 16384);                // 524288 u16
  u16*   hs_bf  = (u16*)(ws + 10 * S1);                  // 4M u16
  u16*   qw_bf  = (u16*)(ws + 10 * S1 + S1 / 2);
  u16*   kw_bf  = qw_bf + S1 / 4;
  u16*   vw_bf  = kw_bf + S1 / 4;
  u16*   ow_bf  = vw_bf + S1 / 4;
  u16*   g1w_bf = ow_bf + S1 / 4;                        // 2048*1088 u16
  // overlays (sources dead at time of write):
  u16*   gate_bf = (u16*)qcv;        // dead after delta_prep
  u16*   omix_bf = (u16*)kcv;        // dead after delta_prep
  float* hdnb    = ws + 8 * S1;      // over qn/kt/wb/attn/beta (dead after scan)
  (void)in_sizes; (void)n_in; (void)out_size; (void)ws_size;

  dim3 blk(256);
  // precasts
  cast_bf<<<(NTOK * HID_) / 1024, blk, 0, stream>>>(hs, hs_bf, NTOK * HID_);
  cast_bf<<<(HID_ * HID_) / 1024, blk, 0, stream>>>(q_w, qw_bf, HID_ * HID_);
  cast_bf<<<(HID_ * HID_) / 1024, blk, 0, stream>>>(k_w, kw_bf, HID_ * HID_);
  cast_bf<<<(HID_ * HID_) / 1024, blk, 0, stream>>>(v_w, vw_bf, HID_ * HID_);
  cast_bf<<<(HID_ * HID_) / 1024, blk, 0, stream>>>(o_w, ow_bf, HID_ * HID_);
  pad_g1w<<<2048 * 1088 / 256, blk, 0, stream>>>(g1w, g1w_bf);
  // projections (bf16 MFMA)
  gemm_bf16<0><<<dim3(8, 32), blk, 0, stream>>>(hs_bf, qw_bf, nullptr, qp, NTOK, HID_, HID_);
  gemm_bf16<0><<<dim3(8, 32), blk, 0, stream>>>(hs_bf, kw_bf, nullptr, kp, NTOK, HID_, HID_);
  gemm_bf16<0><<<dim3(8, 32), blk, 0, stream>>>(hs_bf, vw_bf, nullptr, vp, NTOK, HID_, HID_);
  // causal conv K=4 + silu
  conv4_silu<<<NTOK * HID_ / 256, blk, 0, stream>>>(qp, convq, qcv);
  conv4_silu<<<NTOK * HID_ / 256, blk, 0, stream>>>(kp, convk, kcv);
  conv4_silu<<<NTOK * HID_ / 256, blk, 0, stream>>>(vp, convv, vcv);
  // beta
  beta_proj<<<NTOK * H_ / 256, blk, 0, stream>>>(hs, b_w, betab);
  // delta rule
  delta_prep<<<B_ * H_ * NCH, blk, 0, stream>>>(qcv, kcv, vcv, betab, qn_bf, kt_bf, ubb, wb_bf, attn_bf, attn_lo);
  delta_scan<<<B_ * H_ * 16, dim3(64), 0, stream>>>(qn_bf, kt_bf, ubb, wb_bf, attn_bf, attn_lo, deltab);
  // FIR branches (write over qp/kp/vp — dead after conv)
  fir3<<<(NTOK / 32) * (HID_ / 64), blk, 0, stream>>>(vcv, fir_s, fir_l, fir_w, qp, kp, vp);
  // gate input assembly (bf16)
  build_gate<<<NTOK, blk, 0, stream>>>(hs, qp, kp, vp, deltab, vcv, gate_bf);
  // gate MLP (bf16 MFMA + GELU)
  gemm_bf16<1><<<dim3(16, 32), blk, 0, stream>>>(gate_bf, g1w_bf, g1b, hdnb, NTOK, 2048, 1088);
  g2_mix<<<NTOK, blk, 0, stream>>>(hdnb, g2w, g2b, vbias, ltemp, flog, onw,
                                   qp, kp, vp, deltab, vcv, omix_bf);
  // output projection
  gemm_bf16<0><<<dim3(8, 32), blk, 0, stream>>>(omix_bf, ow_bf, nullptr, (float*)d_out, NTOK, HID_, HID_);
}

// Round 7
// 886.743 us; speedup vs baseline: 1.7964x; 1.0766x over previous
//
#include <hip/hip_runtime.h>

#define B_ 2
#define L_ 2048
#define HID_ 1024
#define H_ 4
#define D_ 256
#define NTOK 4096
#define CH 32
#define NCH 64

typedef short s16x8 __attribute__((ext_vector_type(8)));
typedef float f32x4 __attribute__((ext_vector_type(4)));
typedef unsigned short u16;
typedef unsigned int u32;

__device__ __forceinline__ u16 f2b(float f) {  // RNE fp32->bf16
  u32 u = __float_as_uint(f);
  u32 r = (u + 0x7fffu + ((u >> 16) & 1u)) >> 16;
  return (u16)r;
}
__device__ __forceinline__ float b2f(u16 h) { return __uint_as_float((u32)h << 16); }
__device__ __forceinline__ float blo(u32 u) { return __uint_as_float(u << 16); }
__device__ __forceinline__ float bhi(u32 u) { return __uint_as_float(u & 0xffff0000u); }

union U4S8 { uint4 u; s16x8 s; };
__device__ __forceinline__ s16x8 as_s16x8(uint4 u) { U4S8 x; x.u = u; return x.s; }

// ---------------------------------------------------------------------------
// Fused cast of hs + 4 weight matrices into one contiguous bf16 region.
// Destinations are contiguous: [hs 4M | qw 1M | kw 1M | vw 1M | ow 1M] u16.
// ---------------------------------------------------------------------------
__global__ __launch_bounds__(256)
void cast5(const float* __restrict__ hs, const float* __restrict__ qw,
           const float* __restrict__ kw, const float* __restrict__ vw,
           const float* __restrict__ ow, u16* __restrict__ out)
{
  const long M4 = (long)NTOK * HID_;          // 4M
  const long M1 = (long)HID_ * HID_;          // 1M
  long id = ((long)blockIdx.x * 256 + threadIdx.x) * 4;
  const float* src; long off;
  if (id < M4)               { src = hs; off = id; }
  else if (id < M4 + M1)     { src = qw; off = id - M4; }
  else if (id < M4 + 2 * M1) { src = kw; off = id - M4 - M1; }
  else if (id < M4 + 3 * M1) { src = vw; off = id - M4 - 2 * M1; }
  else                       { src = ow; off = id - M4 - 3 * M1; }
  float4 v = *(const float4*)(src + off);
  ushort4 o;
  o.x = f2b(v.x); o.y = f2b(v.y); o.z = f2b(v.z); o.w = f2b(v.w);
  *(ushort4*)(out + id) = o;
}

// ---------------------------------------------------------------------------
// bf16 MFMA GEMM: C[M][N](f32) = act(A_bf[M][K] @ W_bf[N][K]^T + bias)
// ---------------------------------------------------------------------------
template<int ACT>
__global__ __launch_bounds__(256)
void gemm_bf16(const u16* __restrict__ A, const u16* __restrict__ W,
               const float* __restrict__ bias, float* __restrict__ C,
               int M, int N, int K)
{
  __shared__ u16 Als[128][64];
  __shared__ u16 Bls[128][64];
  const int tid = threadIdx.x;
  const int n0 = blockIdx.x * 128;
  const int m0 = blockIdx.y * 128;
  const int l = tid & 63, w = tid >> 6;
  const int wm = w >> 1, wn = w & 1;
  const int r15 = l & 15, g = l >> 4;
  const int srow = tid >> 1, sh = tid & 1;

  f32x4 acc[4][4];
#pragma unroll
  for (int i = 0; i < 4; i++)
#pragma unroll
    for (int j = 0; j < 4; j++) acc[i][j] = (f32x4){0.f, 0.f, 0.f, 0.f};

  const long arowoff = (long)(m0 + srow) * K + sh * 32;
  const long browoff = (long)(n0 + srow) * K + sh * 32;
  uint4 ra[4], rb[4];
#pragma unroll
  for (int j2 = 0; j2 < 4; j2++) {
    ra[j2] = *(const uint4*)(A + arowoff + j2 * 8);
    rb[j2] = *(const uint4*)(W + browoff + j2 * 8);
  }
  const int NS = K >> 6;
  for (int s = 0; s < NS; ++s) {
    __syncthreads();
#pragma unroll
    for (int j2 = 0; j2 < 4; j2++) {
      int slot = (sh * 4 + j2) ^ (srow & 7);
      *(uint4*)&Als[srow][slot * 8] = ra[j2];
      *(uint4*)&Bls[srow][slot * 8] = rb[j2];
    }
    __syncthreads();
    if (s + 1 < NS) {
      long k0 = (long)(s + 1) * 64;
#pragma unroll
      for (int j2 = 0; j2 < 4; j2++) {
        ra[j2] = *(const uint4*)(A + arowoff + k0 + j2 * 8);
        rb[j2] = *(const uint4*)(W + browoff + k0 + j2 * 8);
      }
    }
#pragma unroll
    for (int kk2 = 0; kk2 < 2; kk2++) {
      s16x8 af[4], bf[4];
      int slot = ((kk2 * 4 + g) ^ (r15 & 7)) * 8;
#pragma unroll
      for (int mt = 0; mt < 4; mt++)
        af[mt] = *(const s16x8*)&Als[64 * wm + mt * 16 + r15][slot];
#pragma unroll
      for (int nt = 0; nt < 4; nt++)
        bf[nt] = *(const s16x8*)&Bls[64 * wn + nt * 16 + r15][slot];
#pragma unroll
      for (int mt = 0; mt < 4; mt++)
#pragma unroll
        for (int nt = 0; nt < 4; nt++)
          acc[mt][nt] = __builtin_amdgcn_mfma_f32_16x16x32_bf16(af[mt], bf[nt], acc[mt][nt], 0, 0, 0);
    }
  }

#pragma unroll
  for (int mt = 0; mt < 4; mt++) {
#pragma unroll
    for (int nt = 0; nt < 4; nt++) {
      int m = m0 + 64 * wm + mt * 16 + g * 4;
      int n = n0 + 64 * wn + nt * 16 + r15;
      float bv = (ACT == 1) ? bias[n] : 0.f;
#pragma unroll
      for (int r = 0; r < 4; r++) {
        float v = acc[mt][nt][r];
        if (ACT == 1) {
          v += bv;
          v = 0.5f * v * (1.f + erff(v * 0.70710678118654752f));
        }
        C[(long)(m + r) * N + n] = v;
      }
    }
  }
}

// ---------------------------------------------------------------------------
// Fused depthwise causal conv (K=4) + SiLU over the packed QKV buffer.
// qkv: [NTOK][3072]; outputs yq/yk/yv [NTOK][HID].
// ---------------------------------------------------------------------------
__global__ __launch_bounds__(256)
void conv4_silu3(const float* __restrict__ qkv, const float* __restrict__ wq,
                 const float* __restrict__ wk, const float* __restrict__ wv,
                 float* __restrict__ yq, float* __restrict__ yk, float* __restrict__ yv)
{
  long id = (long)blockIdx.x * 256 + threadIdx.x;   // < NTOK*3072
  int col = (int)(id % 3072);
  int tok = (int)(id / 3072);
  int g = col >> 10, c = col & 1023;
  int l = tok & (L_ - 1);
  const float* w4 = (g == 0 ? wq : g == 1 ? wk : wv) + c * 4;
  float s = 0.f;
#pragma unroll
  for (int t = 0; t < 4; t++) {
    int lt = l - 3 + t;
    if (lt >= 0) s += qkv[(long)(tok - 3 + t) * 3072 + col] * w4[t];
  }
  float r = s / (1.f + expf(-s));
  float* y = (g == 0 ? yq : g == 1 ? yk : yv);
  y[(long)tok * HID_ + c] = r;
}

// ---------------------------------------------------------------------------
// beta = sigmoid(hs @ b_w^T): [NTOK][4]
// ---------------------------------------------------------------------------
__global__ __launch_bounds__(256)
void beta_proj(const float* __restrict__ hs, const float* __restrict__ bw,
               float* __restrict__ beta)
{
  int id = blockIdx.x * 256 + threadIdx.x;   // < NTOK*H_
  int h = id & 3;
  int tok = id >> 2;
  const float4* a = (const float4*)(hs + (long)tok * HID_);
  const float4* w = (const float4*)(bw + (long)h * HID_);
  float s = 0.f;
  for (int k = 0; k < HID_ / 4; k++) {
    float4 av = a[k], wv = w[k];
    s += av.x * wv.x + av.y * wv.y + av.z * wv.z + av.w * wv.w;
  }
  beta[id] = 1.f / (1.f + expf(-s));
}

// ---------------------------------------------------------------------------
// g1 weight pad+cast: [2048][1084] f32 -> [2048][1088] bf16 (zero fill)
// ---------------------------------------------------------------------------
__global__ __launch_bounds__(256)
void pad_g1w(const float* __restrict__ g1w, u16* __restrict__ out)
{
  int id = blockIdx.x * 256 + threadIdx.x;   // < 2048*1088
  int k = id % 1088;
  int n = id / 1088;
  out[id] = (k < 1084) ? f2b(g1w[(long)n * 1084 + k]) : (u16)0;
}

// ---------------------------------------------------------------------------
// Delta-rule chunk prep (unchanged from R6)
// ---------------------------------------------------------------------------
__global__ __launch_bounds__(256)
void delta_prep(const float* __restrict__ qc, const float* __restrict__ kc,
                const float* __restrict__ vc, const float* __restrict__ beta,
                u16* __restrict__ qn, u16* __restrict__ ktb,
                float* __restrict__ ub, u16* __restrict__ wb,
                u16* __restrict__ attnb, u16* __restrict__ attnlo)
{
  __shared__ float qs[CH][260], ks[CH][260], vs[CH][260];
  __shared__ float Xs[CH][33], As[CH][33];
  __shared__ float red[CH][8];
  __shared__ float bet[CH], nf[CH];

  int bid = blockIdx.x;
  int ci = bid & 63, h = (bid >> 6) & 3, b = bid >> 8;
  int tid = threadIdx.x;
  long tok0 = (long)b * L_ + (long)ci * CH;
  const float* qsrc = qc + tok0 * HID_ + h * D_;
  const float* ksrc = kc + tok0 * HID_ + h * D_;
  const float* vsrc = vc + tok0 * HID_ + h * D_;
  int lr = tid >> 6;
  int dd = (tid & 63) << 2;

#pragma unroll
  for (int it = 0; it < 8; it++) {
    int row = lr + it * 4;
    *(float4*)&qs[row][dd] = *(const float4*)(qsrc + (long)row * HID_ + dd);
    *(float4*)&ks[row][dd] = *(const float4*)(ksrc + (long)row * HID_ + dd);
    *(float4*)&vs[row][dd] = *(const float4*)(vsrc + (long)row * HID_ + dd);
  }
  if (tid < CH) bet[tid] = beta[(tok0 + tid) * H_ + h];
  __syncthreads();

  {
    int c = tid >> 3, p = tid & 7;
    float s = 0.f;
    for (int d = p * 32; d < p * 32 + 32; d++) { float v = qs[c][d]; s += v * v; }
    red[c][p] = s;
  }
  __syncthreads();
  if (tid < CH) {
    float s = 0.f;
    for (int p = 0; p < 8; p++) s += red[tid][p];
    nf[tid] = rsqrtf(s + 1e-6f);
  }
  __syncthreads();
#pragma unroll
  for (int it = 0; it < 8; it++) {
    int row = lr + it * 4;
    float f = nf[row];
    qs[row][dd] *= f; qs[row][dd + 1] *= f; qs[row][dd + 2] *= f; qs[row][dd + 3] *= f;
  }
  {
    int c = tid >> 3, p = tid & 7;
    float s = 0.f;
    for (int d = p * 32; d < p * 32 + 32; d++) { float v = ks[c][d]; s += v * v; }
    red[c][p] = s;
  }
  __syncthreads();
  if (tid < CH) {
    float s = 0.f;
    for (int p = 0; p < 8; p++) s += red[tid][p];
    nf[tid] = rsqrtf(s + 1e-6f);
  }
  __syncthreads();
#pragma unroll
  for (int it = 0; it < 8; it++) {
    int row = lr + it * 4;
    float f = nf[row];
    ks[row][dd] *= f; ks[row][dd + 1] *= f; ks[row][dd + 2] *= f; ks[row][dd + 3] *= f;
  }
  __syncthreads();

  long abase = ((long)(b * H_ + h) * NCH + ci) * (CH * CH);
#pragma unroll 1
  for (int r = 0; r < 4; r++) {
    int oid = tid + 256 * r;
    int i = oid >> 5, jj = oid & 31;
    float skk = 0.f, sqk = 0.f;
    for (int d = 0; d < D_; d += 4) {
      float4 ki = *(const float4*)&ks[i][d];
      float4 kj = *(const float4*)&ks[jj][d];
      float4 qi = *(const float4*)&qs[i][d];
      skk += ki.x * kj.x + ki.y * kj.y + ki.z * kj.z + ki.w * kj.w;
      sqk += qi.x * kj.x + qi.y * kj.y + qi.z * kj.z + qi.w * kj.w;
    }
    As[i][jj] = (jj < i) ? bet[i] * skk : 0.f;
    float sv = (jj <= i) ? sqk : 0.f;
    u16 hi16 = f2b(sv);
    attnb[abase + oid] = hi16;
    attnlo[abase + oid] = f2b(sv - b2f(hi16));
  }
  __syncthreads();

  if (tid < CH) {
    int jj = tid;
    for (int i = 0; i < CH; i++) {
      if (i < jj) { Xs[i][jj] = 0.f; continue; }
      float x = (i == jj) ? 1.f : 0.f;
      for (int m = jj; m < i; m++) x -= As[i][m] * Xs[m][jj];
      Xs[i][jj] = x;
    }
  }
  __syncthreads();

#pragma unroll
  for (int r = 0; r < 4; r++) {
    int oid = tid + 256 * r;
    int i = oid >> 5, m = oid & 31;
    As[i][m] = Xs[i][m] * bet[m];
  }
  __syncthreads();

  long cbase = ((long)(b * H_ + h) * NCH + ci) * (CH * D_);
#pragma unroll 1
  for (int c = 0; c < CH; c++) {
    float su = 0.f, sw = 0.f;
    for (int m = 0; m < CH; m++) {
      float xm = As[c][m];
      su = fmaf(xm, vs[m][tid], su);
      sw = fmaf(xm, ks[m][tid], sw);
    }
    ub[cbase + c * D_ + tid] = su;
    wb[cbase + c * D_ + tid] = f2b(sw);
  }
#pragma unroll 1
  for (int i = 0; i < CH; i++) {
    qn[cbase + i * D_ + tid] = f2b(qs[i][tid]);
  }
  {
    u32 pk[16];
#pragma unroll
    for (int c2 = 0; c2 < 16; c2++) {
      float a = ks[2 * c2][tid], b2 = ks[2 * c2 + 1][tid];
      asm("v_cvt_pk_bf16_f32 %0, %1, %2" : "=v"(pk[c2]) : "v"(a), "v"(b2));
    }
    u16* kq = ktb + ((long)(b * H_ + h) * NCH + ci) * (D_ * CH) + (long)tid * CH;
    *(uint4*)(kq + 0)  = make_uint4(pk[0], pk[1], pk[2], pk[3]);
    *(uint4*)(kq + 8)  = make_uint4(pk[4], pk[5], pk[6], pk[7]);
    *(uint4*)(kq + 16) = make_uint4(pk[8], pk[9], pk[10], pk[11]);
    *(uint4*)(kq + 24) = make_uint4(pk[12], pk[13], pk[14], pk[15]);
  }
}

// ---------------------------------------------------------------------------
// D-layout (two 16x16 f32 tiles) -> hi/lo bf16 B-operand fragments.
// Tile select AFTER the shuffle (R5 lesson).
// ---------------------------------------------------------------------------
__device__ __forceinline__ void d2b2(f32x4 Ta, f32x4 Tb, int v, int hi,
                                     s16x8* hiF, s16x8* loF)
{
  const bool tb = (hi >> 1) != 0;
  const int base = v + ((hi & 1) << 5);
  float y[8];
#pragma unroll
  for (int r = 0; r < 4; r++) {
    float a0 = __shfl(Ta[r], base);
    float b0 = __shfl(Tb[r], base);
    float a1 = __shfl(Ta[r], base + 16);
    float b1 = __shfl(Tb[r], base + 16);
    y[r] = tb ? b0 : a0;
    y[4 + r] = tb ? b1 : a1;
  }
  u32 h0, h1, h2, h3;
  asm("v_cvt_pk_bf16_f32 %0, %1, %2" : "=v"(h0) : "v"(y[0]), "v"(y[1]));
  asm("v_cvt_pk_bf16_f32 %0, %1, %2" : "=v"(h1) : "v"(y[2]), "v"(y[3]));
  asm("v_cvt_pk_bf16_f32 %0, %1, %2" : "=v"(h2) : "v"(y[4]), "v"(y[5]));
  asm("v_cvt_pk_bf16_f32 %0, %1, %2" : "=v"(h3) : "v"(y[6]), "v"(y[7]));
  float z0 = y[0] - blo(h0), z1 = y[1] - bhi(h0);
  float z2 = y[2] - blo(h1), z3 = y[3] - bhi(h1);
  float z4 = y[4] - blo(h2), z5 = y[5] - bhi(h2);
  float z6 = y[6] - blo(h3), z7 = y[7] - bhi(h3);
  u32 l0, l1, l2, l3;
  asm("v_cvt_pk_bf16_f32 %0, %1, %2" : "=v"(l0) : "v"(z0), "v"(z1));
  asm("v_cvt_pk_bf16_f32 %0, %1, %2" : "=v"(l1) : "v"(z2), "v"(z3));
  asm("v_cvt_pk_bf16_f32 %0, %1, %2" : "=v"(l2) : "v"(z4), "v"(z5));
  asm("v_cvt_pk_bf16_f32 %0, %1, %2" : "=v"(l3) : "v"(z6), "v"(z7));
  U4S8 xh; xh.u = make_uint4(h0, h1, h2, h3);
  U4S8 xl; xl.u = make_uint4(l0, l1, l2, l3);
  *hiF = xh.s; *loF = xl.s;
}

// ---------------------------------------------------------------------------
// Delta-rule scan v7: software-pipelined. W/Q fragments double-buffered
// (prefetch chunk ci+1 issued before chunk ci's MFMAs); KT/AT/U reloaded into
// just-consumed registers right after last use. S converted per-k-tile.
// Prefetch at ci=63 reads one chunk past each logical buffer — stays inside
// the workspace (regions are adjacent), values unused.
// ---------------------------------------------------------------------------
__global__ __launch_bounds__(64, 1)
void delta_scan(const u16* __restrict__ qn, const u16* __restrict__ ktb,
                const float* __restrict__ ub, const u16* __restrict__ wb,
                const u16* __restrict__ attnb, const u16* __restrict__ attnlo,
                float* __restrict__ dout)
{
  const int bid = blockIdx.x;                 // 128
  const int sl = bid & 15, h = (bid >> 4) & 3, b = bid >> 6;
  const int l = threadIdx.x;
  const int v = l & 15, hi = l >> 4;
  const int dv0 = sl * 16;
  const long bh = (long)(b * H_ + h);

  f32x4 St[16];
#pragma unroll
  for (int t = 0; t < 16; t++) St[t] = (f32x4){0.f, 0.f, 0.f, 0.f};

  uint4 WfA[2][8], QfA[2][8], WfB[2][8], QfB[2][8];
  uint4 KTf[16], ATh[2], ATl[2];
  float Uld[2][4];

  auto loadWQ = [&](uint4 (&W)[2][8], uint4 (&Q)[2][8], int ci) {
    const long cb = (bh * NCH + ci) * (CH * D_);
#pragma unroll
    for (int mt = 0; mt < 2; mt++)
#pragma unroll
      for (int kt = 0; kt < 8; kt++) {
        const long ro = cb + (long)(mt * 16 + v) * D_ + kt * 32 + hi * 8;
        W[mt][kt] = *(const uint4*)(wb + ro);
        Q[mt][kt] = *(const uint4*)(qn + ro);
      }
  };
  auto loadKT = [&](int ci) {
    const long kb = (bh * NCH + ci) * (D_ * CH);
#pragma unroll
    for (int t = 0; t < 16; t++)
      KTf[t] = *(const uint4*)(ktb + kb + (long)(t * 16 + v) * CH + hi * 8);
  };
  auto loadATU = [&](int ci) {
    const long ab = (bh * NCH + ci) * (CH * CH);
    const long cb = (bh * NCH + ci) * (CH * D_);
#pragma unroll
    for (int mt = 0; mt < 2; mt++) {
      ATh[mt] = *(const uint4*)(attnb + ab + (long)(mt * 16 + v) * CH + hi * 8);
      ATl[mt] = *(const uint4*)(attnlo + ab + (long)(mt * 16 + v) * CH + hi * 8);
    }
#pragma unroll
    for (int mt = 0; mt < 2; mt++)
#pragma unroll
      for (int r = 0; r < 4; r++)
        Uld[mt][r] = ub[cb + (long)(mt * 16 + hi * 4 + r) * D_ + dv0 + v];
  };

  auto step = [&](uint4 (&CW)[2][8], uint4 (&CQ)[2][8],
                  uint4 (&NW)[2][8], uint4 (&NQ)[2][8], int ci) {
    // prefetch next chunk's W/Q into the other buffer (hidden under MFMAs)
    loadWQ(NW, NQ, ci + 1);

    // aw = W@S, aq = Q@S with per-k-tile S conversion (hi+lo)
    f32x4 awt[2], aqt[2];
#pragma unroll
    for (int mt = 0; mt < 2; mt++) { awt[mt] = (f32x4){0.f,0.f,0.f,0.f}; aqt[mt] = (f32x4){0.f,0.f,0.f,0.f}; }
#pragma unroll
    for (int kt = 0; kt < 8; kt++) {
      s16x8 sh_, sl_;
      d2b2(St[2 * kt], St[2 * kt + 1], v, hi, &sh_, &sl_);
#pragma unroll
      for (int mt = 0; mt < 2; mt++) {
        awt[mt] = __builtin_amdgcn_mfma_f32_16x16x32_bf16(as_s16x8(CW[mt][kt]), sh_, awt[mt], 0, 0, 0);
        awt[mt] = __builtin_amdgcn_mfma_f32_16x16x32_bf16(as_s16x8(CW[mt][kt]), sl_, awt[mt], 0, 0, 0);
        aqt[mt] = __builtin_amdgcn_mfma_f32_16x16x32_bf16(as_s16x8(CQ[mt][kt]), sh_, aqt[mt], 0, 0, 0);
        aqt[mt] = __builtin_amdgcn_mfma_f32_16x16x32_bf16(as_s16x8(CQ[mt][kt]), sl_, aqt[mt], 0, 0, 0);
      }
    }

    // u_adj = u - aw  -> hi/lo fragments
    f32x4 ua0, ua1;
#pragma unroll
    for (int r = 0; r < 4; r++) { ua0[r] = Uld[0][r] - awt[0][r]; ua1[r] = Uld[1][r] - awt[1][r]; }
    s16x8 UAh, UAl;
    d2b2(ua0, ua1, v, hi, &UAh, &UAl);

    // o = aq + attn @ u_adj ; store
    f32x4 ot[2];
#pragma unroll
    for (int mt = 0; mt < 2; mt++) {
      ot[mt] = __builtin_amdgcn_mfma_f32_16x16x32_bf16(as_s16x8(ATh[mt]), UAh, aqt[mt], 0, 0, 0);
      ot[mt] = __builtin_amdgcn_mfma_f32_16x16x32_bf16(as_s16x8(ATh[mt]), UAl, ot[mt], 0, 0, 0);
      ot[mt] = __builtin_amdgcn_mfma_f32_16x16x32_bf16(as_s16x8(ATl[mt]), UAh, ot[mt], 0, 0, 0);
    }
#pragma unroll
    for (int mt = 0; mt < 2; mt++)
#pragma unroll
      for (int r = 0; r < 4; r++)
        dout[((long)b * L_ + ci * CH + mt * 16 + hi * 4 + r) * HID_ + h * D_ + dv0 + v] = ot[mt][r];

    // reload AT/U for next chunk (just consumed)
    loadATU(ci + 1);

    // S += K^T @ u_adj (hi+lo)
#pragma unroll
    for (int t = 0; t < 16; t++) {
      St[t] = __builtin_amdgcn_mfma_f32_16x16x32_bf16(as_s16x8(KTf[t]), UAh, St[t], 0, 0, 0);
      St[t] = __builtin_amdgcn_mfma_f32_16x16x32_bf16(as_s16x8(KTf[t]), UAl, St[t], 0, 0, 0);
    }
    // reload KT for next chunk (just consumed)
    loadKT(ci + 1);
  };

  loadWQ(WfA, QfA, 0);
  loadKT(0);
  loadATU(0);
#pragma unroll 1
  for (int c2 = 0; c2 < NCH / 2; c2++) {
    step(WfA, QfA, WfB, QfB, 2 * c2);
    step(WfB, QfB, WfA, QfA, 2 * c2 + 1);
  }
}

// ---------------------------------------------------------------------------
// Fused 3-FIR depthwise causal conv on v (K=3,31,64). Tile 32 tok x 64 ch.
// ---------------------------------------------------------------------------
__global__ __launch_bounds__(256)
void fir3(const float* __restrict__ v, const float* __restrict__ fs_g,
          const float* __restrict__ fl_g, const float* __restrict__ fw_g,
          float* __restrict__ os, float* __restrict__ ol, float* __restrict__ ow)
{
  __shared__ float xs[95][64];
  __shared__ float fs[64][3];
  __shared__ float fl[64][31];
  __shared__ float fw[64][65];
  int bid = blockIdx.x;
  int ct = bid & 15, lt = bid >> 4;
  int c0 = ct * 64, tok0 = lt * 32;
  int bstart = (tok0 / L_) * L_;
  int tid = threadIdx.x;

  for (int idx = tid; idx < 95 * 64; idx += 256) {
    int r = idx >> 6, cc = idx & 63;
    int tok = tok0 - 63 + r;
    xs[r][cc] = (tok >= bstart) ? v[(long)tok * HID_ + c0 + cc] : 0.f;
  }
  for (int idx = tid; idx < 64 * 3; idx += 256) fs[idx / 3][idx % 3] = fs_g[(long)(c0 + idx / 3) * 3 + idx % 3];
  for (int idx = tid; idx < 64 * 31; idx += 256) fl[idx / 31][idx % 31] = fl_g[(long)(c0 + idx / 31) * 31 + idx % 31];
  for (int idx = tid; idx < 64 * 64; idx += 256) fw[idx >> 6][idx & 63] = fw_g[(long)(c0 + (idx >> 6)) * 64 + (idx & 63)];
  __syncthreads();

  int cc = tid & 63, lq = tid >> 6;
  int rb = lq * 8;
  float as8[8] = {0}, al8[8] = {0}, aw8[8] = {0};
#pragma unroll 1
  for (int t = 0; t < 64; t++) {
    float fv = fw[cc][t];
#pragma unroll
    for (int i = 0; i < 8; i++) aw8[i] = fmaf(xs[rb + i + t][cc], fv, aw8[i]);
  }
#pragma unroll 1
  for (int t = 0; t < 31; t++) {
    float fv = fl[cc][t];
#pragma unroll
    for (int i = 0; i < 8; i++) al8[i] = fmaf(xs[rb + 33 + i + t][cc], fv, al8[i]);
  }
#pragma unroll 1
  for (int t = 0; t < 3; t++) {
    float fv = fs[cc][t];
#pragma unroll
    for (int i = 0; i < 8; i++) as8[i] = fmaf(xs[rb + 61 + i + t][cc], fv, as8[i]);
  }
#pragma unroll
  for (int i = 0; i < 8; i++) {
    long o = (long)(tok0 + lq * 8 + i) * HID_ + c0 + cc;
    os[o] = as8[i]; ol[o] = al8[i]; ow[o] = aw8[i];
  }
}

// ---------------------------------------------------------------------------
// gate_in (bf16) = [hs | stats x5], row stride 1088 (cols 1084..1087 zero)
// ---------------------------------------------------------------------------
__global__ __launch_bounds__(256)
void build_gate(const float* __restrict__ hs, const float* __restrict__ sb,
                const float* __restrict__ lb, const float* __restrict__ wbb,
                const float* __restrict__ db, const float* __restrict__ vb,
                u16* __restrict__ gate)
{
  int tok = blockIdx.x;
  int tid = threadIdx.x;
  u16* g = gate + (long)tok * 1088;
  const float* hrow = hs + (long)tok * HID_;
#pragma unroll
  for (int i = 0; i < 4; i++) g[tid + 256 * i] = f2b(hrow[tid + 256 * i]);
  if (tid < 4) g[1084 + tid] = 0;
  int h = tid >> 6, ln = tid & 63;
  const float* brs[5] = {sb, lb, wbb, db, vb};
#pragma unroll
  for (int bi = 0; bi < 5; bi++) {
    const float* x = brs[bi] + (long)tok * HID_ + h * D_;
    float s = 0.f, ss = 0.f, mx = 0.f;
#pragma unroll
    for (int i = 0; i < 4; i++) {
      float v = x[ln + 64 * i];
      s += v; ss += v * v; mx = fmaxf(mx, fabsf(v));
    }
#pragma unroll
    for (int off = 32; off >= 1; off >>= 1) {
      s += __shfl_xor(s, off);
      ss += __shfl_xor(ss, off);
      mx = fmaxf(mx, __shfl_xor(mx, off));
    }
    if (ln == 0) {
      g[1024 + bi * 12 + h] = f2b(s * (1.f / 256.f));
      g[1024 + bi * 12 + 4 + h] = f2b(sqrtf(fmaxf(ss * (1.f / 256.f), 1e-8f)));
      g[1024 + bi * 12 + 8 + h] = f2b(mx);
    }
  }
}

// ---------------------------------------------------------------------------
// Fused g2 (4096x20x2048) + softmax/temperature/floor mix + per-head RMSNorm
// ---------------------------------------------------------------------------
__global__ __launch_bounds__(256)
void g2_mix(const float* __restrict__ hdn, const float* __restrict__ g2w,
            const float* __restrict__ g2b, const float* __restrict__ vbias,
            const float* __restrict__ ltemp, const float* __restrict__ flog,
            const float* __restrict__ onw,
            const float* __restrict__ sb, const float* __restrict__ lb,
            const float* __restrict__ wbb, const float* __restrict__ db,
            const float* __restrict__ vb, u16* __restrict__ omix)
{
  __shared__ float hrow[2048];
  __shared__ float lg[20];
  int tok = blockIdx.x;
  int tid = threadIdx.x;
  const float* hp = hdn + (long)tok * 2048;
#pragma unroll
  for (int i = 0; i < 8; i++) hrow[tid + 256 * i] = hp[tid + 256 * i];
  __syncthreads();
  int w = tid >> 6, ln = tid & 63;
#pragma unroll 1
  for (int q = 0; q < 5; q++) {
    int jj = w * 5 + q;
    const float* wr = g2w + (long)jj * 2048;
    float s = 0.f;
    for (int i = 0; i < 32; i++) s += hrow[ln + 64 * i] * wr[ln + 64 * i];
#pragma unroll
    for (int off = 32; off >= 1; off >>= 1) s += __shfl_xor(s, off);
    if (ln == 0) lg[jj] = s + g2b[jj];
  }
  __syncthreads();
  int h = w;
  float l[5];
#pragma unroll
  for (int j = 0; j < 5; j++) l[j] = lg[h * 5 + j];
  l[4] += vbias[h];
  float it = expf(-ltemp[h]);
#pragma unroll
  for (int j = 0; j < 5; j++) l[j] *= it;
  float mx = fmaxf(fmaxf(fmaxf(l[0], l[1]), fmaxf(l[2], l[3])), l[4]);
  float e[5], se = 0.f;
#pragma unroll
  for (int j = 0; j < 5; j++) { e[j] = expf(l[j] - mx); se += e[j]; }
  float inv = 1.f / se;
  float f = 1.f / (1.f + expf(-flog[h]));
  float sc = 1.f - 4.f * f;
  float wt[5];
#pragma unroll
  for (int j = 0; j < 4; j++) wt[j] = f + sc * e[j] * inv;
  wt[4] = sc * e[4] * inv;

  long base = (long)tok * HID_ + h * D_;
  float o[4], ss = 0.f;
#pragma unroll
  for (int i = 0; i < 4; i++) {
    int d = ln + 64 * i;
    o[i] = wt[0] * sb[base + d] + wt[1] * lb[base + d] + wt[2] * wbb[base + d]
         + wt[3] * db[base + d] + wt[4] * vb[base + d];
    ss += o[i] * o[i];
  }
#pragma unroll
  for (int off = 32; off >= 1; off >>= 1) ss += __shfl_xor(ss, off);
  float r = rsqrtf(ss * (1.f / 256.f) + 1e-5f);
#pragma unroll
  for (int i = 0; i < 4; i++) {
    int d = ln + 64 * i;
    omix[base + d] = f2b(o[i] * r * onw[d]);
  }
}

// ---------------------------------------------------------------------------
extern "C" void kernel_launch(void* const* d_in, const int* in_sizes, int n_in,
                              void* d_out, int out_size, void* d_ws, size_t ws_size,
                              hipStream_t stream)
{
  const float* hs    = (const float*)d_in[0];
  const float* q_w   = (const float*)d_in[1];
  const float* k_w   = (const float*)d_in[2];
  const float* v_w   = (const float*)d_in[3];
  const float* b_w   = (const float*)d_in[4];
  const float* convq = (const float*)d_in[5];
  const float* convk = (const float*)d_in[6];
  const float* convv = (const float*)d_in[7];
  const float* fir_s = (const float*)d_in[8];
  const float* fir_l = (const float*)d_in[9];
  const float* fir_w = (const float*)d_in[10];
  const float* g1w   = (const float*)d_in[11];
  const float* g1b   = (const float*)d_in[12];
  const float* g2w   = (const float*)d_in[13];
  const float* g2b   = (const float*)d_in[14];
  const float* vbias = (const float*)d_in[15];
  const float* ltemp = (const float*)d_in[16];
  const float* flog  = (const float*)d_in[17];
  const float* onw   = (const float*)d_in[18];
  const float* o_w   = (const float*)d_in[19];

  float* ws = (float*)d_ws;
  const long S1 = (long)NTOK * HID_;          // 4,194,304 floats
  float* qkv3   = ws + 0 * S1;                // [4096][3072] f32 (3 S1)
  float* qcv    = ws + 3 * S1;
  float* kcv    = ws + 4 * S1;
  float* vcv    = ws + 5 * S1;
  float* ubb    = ws + 6 * S1;
  float* deltab = ws + 7 * S1;
  u16*   qn_bf  = (u16*)(ws + 8 * S1);                   // S1 u16
  u16*   kt_bf  = (u16*)(ws + 8 * S1 + S1 / 2);          // S1 u16 (transposed k)
  u16*   wb_bf  = (u16*)(ws + 9 * S1);                   // S1 u16
  u16*   attn_bf = (u16*)(ws + 9 * S1 + S1 / 2);         // 524288 u16
  float* betab  = (float*)(attn_bf + (long)B_ * H_ * NCH * CH * CH); // 16384 f32
  u16*   attn_lo = (u16*)(betab + 16384);                // 524288 u16
  u16*   hs_bf  = (u16*)(ws + 10 * S1);                  // 4M u16 (cast5 region start)
  u16*   qw_bf  = (u16*)(ws + 10 * S1 + S1 / 2);         // 1M u16 each, contiguous
  u16*   ow_bf  = qw_bf + 3 * (S1 / 4);
  u16*   g1w_bf = ow_bf + S1 / 4;                        // 2048*1088 u16
  // FIR outputs reuse qkv3 region (dead after conv):
  float* firs = ws + 0 * S1;
  float* firl = ws + 1 * S1;
  float* firw = ws + 2 * S1;
  // overlays (sources dead at time of write):
  u16*   gate_bf = (u16*)qcv;        // dead after delta_prep
  u16*   omix_bf = (u16*)kcv;        // dead after delta_prep
  float* hdnb    = ws + 8 * S1;      // over qn/kt/wb/attn/beta (dead after scan)
  (void)in_sizes; (void)n_in; (void)out_size; (void)ws_size;

  dim3 blk(256);
  // fused precast: hs + qw + kw + vw + ow into contiguous bf16
  cast5<<<(NTOK * HID_ + 4 * HID_ * HID_) / 1024, blk, 0, stream>>>(hs, q_w, k_w, v_w, o_w, hs_bf);
  pad_g1w<<<2048 * 1088 / 256, blk, 0, stream>>>(g1w, g1w_bf);
  // fused QKV projection (bf16 MFMA), N=3072
  gemm_bf16<0><<<dim3(24, 32), blk, 0, stream>>>(hs_bf, qw_bf, nullptr, qkv3, NTOK, 3072, HID_);
  // fused causal conv K=4 + silu
  conv4_silu3<<<(NTOK * 3072) / 256, blk, 0, stream>>>(qkv3, convq, convk, convv, qcv, kcv, vcv);
  // beta
  beta_proj<<<NTOK * H_ / 256, blk, 0, stream>>>(hs, b_w, betab);
  // delta rule
  delta_prep<<<B_ * H_ * NCH, blk, 0, stream>>>(qcv, kcv, vcv, betab, qn_bf, kt_bf, ubb, wb_bf, attn_bf, attn_lo);
  delta_scan<<<B_ * H_ * 16, dim3(64), 0, stream>>>(qn_bf, kt_bf, ubb, wb_bf, attn_bf, attn_lo, deltab);
  // FIR branches (write over qkv3 — dead after conv)
  fir3<<<(NTOK / 32) * (HID_ / 64), blk, 0, stream>>>(vcv, fir_s, fir_l, fir_w, firs, firl, firw);
  // gate input assembly (bf16)
  build_gate<<<NTOK, blk, 0, stream>>>(hs, firs, firl, firw, deltab, vcv, gate_bf);
  // gate MLP (bf16 MFMA + GELU)
  gemm_bf16<1><<<dim3(16, 32), blk, 0, stream>>>(gate_bf, g1w_bf, g1b, hdnb, NTOK, 2048, 1088);
  g2_mix<<<NTOK, blk, 0, stream>>>(hdnb, g2w, g2b, vbias, ltemp, flog, onw,
                                   firs, firl, firw, deltab, vcv, omix_bf);
  // output projection
  gemm_bf16<0><<<dim3(8, 32), blk, 0, stream>>>(omix_bf, ow_bf, nullptr, (float*)d_out, NTOK, HID_, HID_);
}

// Round 8
// 840.933 us; speedup vs baseline: 1.8942x; 1.0545x over previous
//
#include <hip/hip_runtime.h>

#define B_ 2
#define L_ 2048
#define HID_ 1024
#define H_ 4
#define D_ 256
#define NTOK 4096
#define CH 32
#define NCH 64

typedef short s16x8 __attribute__((ext_vector_type(8)));
typedef float f32x4 __attribute__((ext_vector_type(4)));
typedef unsigned short u16;
typedef unsigned int u32;

__device__ __forceinline__ u16 f2b(float f) {  // RNE fp32->bf16
  u32 u = __float_as_uint(f);
  u32 r = (u + 0x7fffu + ((u >> 16) & 1u)) >> 16;
  return (u16)r;
}
__device__ __forceinline__ float b2f(u16 h) { return __uint_as_float((u32)h << 16); }
__device__ __forceinline__ float blo(u32 u) { return __uint_as_float(u << 16); }
__device__ __forceinline__ float bhi(u32 u) { return __uint_as_float(u & 0xffff0000u); }

union U4S8 { uint4 u; s16x8 s; };
__device__ __forceinline__ s16x8 as_s16x8(uint4 u) { U4S8 x; x.u = u; return x.s; }

__device__ __forceinline__ u32 pkbf(float a, float b) {
  u32 r;
  asm("v_cvt_pk_bf16_f32 %0, %1, %2" : "=v"(r) : "v"(a), "v"(b));
  return r;
}
// 8 consecutive f32 -> bf16 A/B fragment
__device__ __forceinline__ s16x8 cvt8(const float* p) {
  float4 a = *(const float4*)p;
  float4 b = *(const float4*)(p + 4);
  return as_s16x8(make_uint4(pkbf(a.x, a.y), pkbf(a.z, a.w),
                             pkbf(b.x, b.y), pkbf(b.z, b.w)));
}

// ---------------------------------------------------------------------------
// Fused cast of hs + 4 weight matrices into one contiguous bf16 region.
// ---------------------------------------------------------------------------
__global__ __launch_bounds__(256)
void cast5(const float* __restrict__ hs, const float* __restrict__ qw,
           const float* __restrict__ kw, const float* __restrict__ vw,
           const float* __restrict__ ow, u16* __restrict__ out)
{
  const long M4 = (long)NTOK * HID_;
  const long M1 = (long)HID_ * HID_;
  long id = ((long)blockIdx.x * 256 + threadIdx.x) * 4;
  const float* src; long off;
  if (id < M4)               { src = hs; off = id; }
  else if (id < M4 + M1)     { src = qw; off = id - M4; }
  else if (id < M4 + 2 * M1) { src = kw; off = id - M4 - M1; }
  else if (id < M4 + 3 * M1) { src = vw; off = id - M4 - 2 * M1; }
  else                       { src = ow; off = id - M4 - 3 * M1; }
  float4 v = *(const float4*)(src + off);
  ushort4 o;
  o.x = f2b(v.x); o.y = f2b(v.y); o.z = f2b(v.z); o.w = f2b(v.w);
  *(ushort4*)(out + id) = o;
}

// ---------------------------------------------------------------------------
// bf16 MFMA GEMM: C[M][N](f32) = act(A_bf[M][K] @ W_bf[N][K]^T + bias)
// ---------------------------------------------------------------------------
template<int ACT>
__global__ __launch_bounds__(256)
void gemm_bf16(const u16* __restrict__ A, const u16* __restrict__ W,
               const float* __restrict__ bias, float* __restrict__ C,
               int M, int N, int K)
{
  __shared__ u16 Als[128][64];
  __shared__ u16 Bls[128][64];
  const int tid = threadIdx.x;
  const int n0 = blockIdx.x * 128;
  const int m0 = blockIdx.y * 128;
  const int l = tid & 63, w = tid >> 6;
  const int wm = w >> 1, wn = w & 1;
  const int r15 = l & 15, g = l >> 4;
  const int srow = tid >> 1, sh = tid & 1;

  f32x4 acc[4][4];
#pragma unroll
  for (int i = 0; i < 4; i++)
#pragma unroll
    for (int j = 0; j < 4; j++) acc[i][j] = (f32x4){0.f, 0.f, 0.f, 0.f};

  const long arowoff = (long)(m0 + srow) * K + sh * 32;
  const long browoff = (long)(n0 + srow) * K + sh * 32;
  uint4 ra[4], rb[4];
#pragma unroll
  for (int j2 = 0; j2 < 4; j2++) {
    ra[j2] = *(const uint4*)(A + arowoff + j2 * 8);
    rb[j2] = *(const uint4*)(W + browoff + j2 * 8);
  }
  const int NS = K >> 6;
  for (int s = 0; s < NS; ++s) {
    __syncthreads();
#pragma unroll
    for (int j2 = 0; j2 < 4; j2++) {
      int slot = (sh * 4 + j2) ^ (srow & 7);
      *(uint4*)&Als[srow][slot * 8] = ra[j2];
      *(uint4*)&Bls[srow][slot * 8] = rb[j2];
    }
    __syncthreads();
    if (s + 1 < NS) {
      long k0 = (long)(s + 1) * 64;
#pragma unroll
      for (int j2 = 0; j2 < 4; j2++) {
        ra[j2] = *(const uint4*)(A + arowoff + k0 + j2 * 8);
        rb[j2] = *(const uint4*)(W + browoff + k0 + j2 * 8);
      }
    }
#pragma unroll
    for (int kk2 = 0; kk2 < 2; kk2++) {
      s16x8 af[4], bf[4];
      int slot = ((kk2 * 4 + g) ^ (r15 & 7)) * 8;
#pragma unroll
      for (int mt = 0; mt < 4; mt++)
        af[mt] = *(const s16x8*)&Als[64 * wm + mt * 16 + r15][slot];
#pragma unroll
      for (int nt = 0; nt < 4; nt++)
        bf[nt] = *(const s16x8*)&Bls[64 * wn + nt * 16 + r15][slot];
#pragma unroll
      for (int mt = 0; mt < 4; mt++)
#pragma unroll
        for (int nt = 0; nt < 4; nt++)
          acc[mt][nt] = __builtin_amdgcn_mfma_f32_16x16x32_bf16(af[mt], bf[nt], acc[mt][nt], 0, 0, 0);
    }
  }

#pragma unroll
  for (int mt = 0; mt < 4; mt++) {
#pragma unroll
    for (int nt = 0; nt < 4; nt++) {
      int m = m0 + 64 * wm + mt * 16 + g * 4;
      int n = n0 + 64 * wn + nt * 16 + r15;
      float bv = (ACT == 1) ? bias[n] : 0.f;
#pragma unroll
      for (int r = 0; r < 4; r++) {
        float v = acc[mt][nt][r];
        if (ACT == 1) {
          v += bv;
          v = 0.5f * v * (1.f + erff(v * 0.70710678118654752f));
        }
        C[(long)(m + r) * N + n] = v;
      }
    }
  }
}

// ---------------------------------------------------------------------------
// Fused depthwise causal conv (K=4) + SiLU over the packed QKV buffer.
// ---------------------------------------------------------------------------
__global__ __launch_bounds__(256)
void conv4_silu3(const float* __restrict__ qkv, const float* __restrict__ wq,
                 const float* __restrict__ wk, const float* __restrict__ wv,
                 float* __restrict__ yq, float* __restrict__ yk, float* __restrict__ yv)
{
  long id = (long)blockIdx.x * 256 + threadIdx.x;
  int col = (int)(id % 3072);
  int tok = (int)(id / 3072);
  int g = col >> 10, c = col & 1023;
  int l = tok & (L_ - 1);
  const float* w4 = (g == 0 ? wq : g == 1 ? wk : wv) + c * 4;
  float s = 0.f;
#pragma unroll
  for (int t = 0; t < 4; t++) {
    int lt = l - 3 + t;
    if (lt >= 0) s += qkv[(long)(tok - 3 + t) * 3072 + col] * w4[t];
  }
  float r = s / (1.f + expf(-s));
  float* y = (g == 0 ? yq : g == 1 ? yk : yv);
  y[(long)tok * HID_ + c] = r;
}

// ---------------------------------------------------------------------------
// beta = sigmoid(hs @ b_w^T): [NTOK][4]
// ---------------------------------------------------------------------------
__global__ __launch_bounds__(256)
void beta_proj(const float* __restrict__ hs, const float* __restrict__ bw,
               float* __restrict__ beta)
{
  int id = blockIdx.x * 256 + threadIdx.x;
  int h = id & 3;
  int tok = id >> 2;
  const float4* a = (const float4*)(hs + (long)tok * HID_);
  const float4* w = (const float4*)(bw + (long)h * HID_);
  float s = 0.f;
  for (int k = 0; k < HID_ / 4; k++) {
    float4 av = a[k], wv = w[k];
    s += av.x * wv.x + av.y * wv.y + av.z * wv.z + av.w * wv.w;
  }
  beta[id] = 1.f / (1.f + expf(-s));
}

// ---------------------------------------------------------------------------
// g1 weight pad+cast: [2048][1084] f32 -> [2048][1088] bf16 (zero fill)
// ---------------------------------------------------------------------------
__global__ __launch_bounds__(256)
void pad_g1w(const float* __restrict__ g1w, u16* __restrict__ out)
{
  int id = blockIdx.x * 256 + threadIdx.x;
  int k = id % 1088;
  int n = id / 1088;
  out[id] = (k < 1084) ? f2b(g1w[(long)n * 1084 + k]) : (u16)0;
}

// ---------------------------------------------------------------------------
// Delta-rule chunk prep v2 (MFMA):
//  - A=stril(beta_i k_i.k_j), attn=tril(q_i.k_j) via 16x16x32 MFMA (bf16 in-reg)
//  - (I+A)^-1 serial forward substitution (threads 0..31)
//  - u = (Xh+Xl)@(vh+vl), w = (Xh+Xl)@kh via MFMA, X = inv*diag(beta)
// LDS overlays: vTh over qs, vTl over ks (both dead after phase 4).
// ---------------------------------------------------------------------------
#define QSP 264
__global__ __launch_bounds__(256)
void delta_prep(const float* __restrict__ qc, const float* __restrict__ kc,
                const float* __restrict__ vc, const float* __restrict__ beta,
                u16* __restrict__ qn, u16* __restrict__ ktb,
                float* __restrict__ ub, u16* __restrict__ wb,
                u16* __restrict__ attnb, u16* __restrict__ attnlo)
{
  __shared__ float qs_[CH * QSP];      // phase<=4: qs ; phase6: vTh overlay
  __shared__ float ks_[CH * QSP];      // phase<=4: ks ; phase6: vTl overlay
  __shared__ float vs_[CH * QSP];
  __shared__ u16   kTh[D_ * 40];
  __shared__ float As[CH][33];
  __shared__ float Xs[CH][33];
  __shared__ u16   Xh[CH][40];
  __shared__ u16   Xl[CH][40];
  __shared__ float bet[CH], nfq[CH], nfk[CH];

  float* qs = qs_;
  float* ks = ks_;
  float* vs = vs_;
  u16* vTh = (u16*)qs_;
  u16* vTl = (u16*)ks_;

  const int bid = blockIdx.x;
  const int ci = bid & 63, h = (bid >> 6) & 3, b = bid >> 8;
  const int tid = threadIdx.x;
  const long tok0 = (long)b * L_ + (long)ci * CH;
  const float* qsrc = qc + tok0 * HID_ + h * D_;
  const float* ksrc = kc + tok0 * HID_ + h * D_;
  const float* vsrc = vc + tok0 * HID_ + h * D_;
  const int lr = tid >> 6;             // 0..3
  const int dd = (tid & 63) << 2;      // 0..252
  const long cbase = ((long)(b * H_ + h) * NCH + ci) * (CH * D_);
  const long abase = ((long)(b * H_ + h) * NCH + ci) * (CH * CH);
  const long kbase = ((long)(b * H_ + h) * NCH + ci) * (D_ * CH);

  // ---- stage q,k,v (f32, coalesced) ----
#pragma unroll
  for (int it = 0; it < 8; it++) {
    int row = lr + it * 4;
    *(float4*)&qs[row * QSP + dd] = *(const float4*)(qsrc + (long)row * HID_ + dd);
    *(float4*)&ks[row * QSP + dd] = *(const float4*)(ksrc + (long)row * HID_ + dd);
    *(float4*)&vs[row * QSP + dd] = *(const float4*)(vsrc + (long)row * HID_ + dd);
  }
  if (tid < CH) bet[tid] = beta[(tok0 + tid) * H_ + h];
  __syncthreads();

  // ---- row norms for q and k (8 threads/row, shfl_xor reduce) ----
  {
    int c = tid >> 3, p = tid & 7;
    const float* qr = qs + c * QSP + p * 32;
    const float* kr = ks + c * QSP + p * 32;
    float sq = 0.f, sk = 0.f;
#pragma unroll
    for (int i = 0; i < 8; i++) {
      float4 a = *(const float4*)(qr + i * 4);
      float4 bq = *(const float4*)(kr + i * 4);
      sq += a.x * a.x + a.y * a.y + a.z * a.z + a.w * a.w;
      sk += bq.x * bq.x + bq.y * bq.y + bq.z * bq.z + bq.w * bq.w;
    }
#pragma unroll
    for (int off = 4; off >= 1; off >>= 1) {
      sq += __shfl_xor(sq, off);
      sk += __shfl_xor(sk, off);
    }
    if (p == 0) { nfq[c] = rsqrtf(sq + 1e-6f); nfk[c] = rsqrtf(sk + 1e-6f); }
  }
  __syncthreads();

  // ---- scale q,k in LDS; write qn (bf16) to global ----
#pragma unroll
  for (int it = 0; it < 8; it++) {
    int row = lr + it * 4;
    float fq = nfq[row], fk = nfk[row];
    float4 qv = *(float4*)&qs[row * QSP + dd];
    qv.x *= fq; qv.y *= fq; qv.z *= fq; qv.w *= fq;
    *(float4*)&qs[row * QSP + dd] = qv;
    ushort4 qo; qo.x = f2b(qv.x); qo.y = f2b(qv.y); qo.z = f2b(qv.z); qo.w = f2b(qv.w);
    *(ushort4*)(qn + cbase + (long)row * D_ + dd) = qo;
    float4 kv = *(float4*)&ks[row * QSP + dd];
    kv.x *= fk; kv.y *= fk; kv.z *= fk; kv.w *= fk;
    *(float4*)&ks[row * QSP + dd] = kv;
  }
  __syncthreads();

  // ---- phase 4: M1 = kn@kn^T, M2 = qn@kn^T via MFMA; mask; write attn; fill As
  {
    const int w = tid >> 6, l = tid & 63;
    const int v = l & 15, hi = l >> 4;
    const int ti = w >> 1, tj = w & 1;
    f32x4 m1 = (f32x4){0.f, 0.f, 0.f, 0.f};
    f32x4 m2 = (f32x4){0.f, 0.f, 0.f, 0.f};
#pragma unroll
    for (int kt = 0; kt < 8; kt++) {
      const int ko = kt * 32 + hi * 8;
      s16x8 a1 = cvt8(&ks[(ti * 16 + v) * QSP + ko]);
      s16x8 a2 = cvt8(&qs[(ti * 16 + v) * QSP + ko]);
      s16x8 bb = cvt8(&ks[(tj * 16 + v) * QSP + ko]);
      m1 = __builtin_amdgcn_mfma_f32_16x16x32_bf16(a1, bb, m1, 0, 0, 0);
      m2 = __builtin_amdgcn_mfma_f32_16x16x32_bf16(a2, bb, m2, 0, 0, 0);
    }
#pragma unroll
    for (int r = 0; r < 4; r++) {
      int i = ti * 16 + hi * 4 + r, j = tj * 16 + v;
      As[i][j] = (j < i) ? bet[i] * m1[r] : 0.f;
      float sv = (j <= i) ? m2[r] : 0.f;
      u16 hh = f2b(sv);
      attnb[abase + i * 32 + j] = hh;
      attnlo[abase + i * 32 + j] = f2b(sv - b2f(hh));
    }
  }
  __syncthreads();

  // ---- kT build from ks (conflict-free row reads, packed writes) + ktb global
  {
    u32 pk[16];
#pragma unroll
    for (int c2 = 0; c2 < 16; c2++)
      pk[c2] = pkbf(ks[(2 * c2) * QSP + tid], ks[(2 * c2 + 1) * QSP + tid]);
    uint4 p0 = make_uint4(pk[0], pk[1], pk[2], pk[3]);
    uint4 p1 = make_uint4(pk[4], pk[5], pk[6], pk[7]);
    uint4 p2 = make_uint4(pk[8], pk[9], pk[10], pk[11]);
    uint4 p3 = make_uint4(pk[12], pk[13], pk[14], pk[15]);
    *(uint4*)&kTh[tid * 40 + 0]  = p0;
    *(uint4*)&kTh[tid * 40 + 8]  = p1;
    *(uint4*)&kTh[tid * 40 + 16] = p2;
    *(uint4*)&kTh[tid * 40 + 24] = p3;
    u16* kq = ktb + kbase + (long)tid * CH;
    *(uint4*)(kq + 0)  = p0;
    *(uint4*)(kq + 8)  = p1;
    *(uint4*)(kq + 16) = p2;
    *(uint4*)(kq + 24) = p3;
  }
  __syncthreads();   // ks reads done -> vTl overlay safe after NEXT barrier

  // ---- vT hi/lo build from vs (destroys qs/ks overlays) ----
  {
    u32 ph[16], pl[16];
#pragma unroll
    for (int c2 = 0; c2 < 16; c2++) {
      float a = vs[(2 * c2) * QSP + tid];
      float bq = vs[(2 * c2 + 1) * QSP + tid];
      u32 hp = pkbf(a, bq);
      ph[c2] = hp;
      pl[c2] = pkbf(a - blo(hp), bq - bhi(hp));
    }
    *(uint4*)&vTh[tid * 40 + 0]  = make_uint4(ph[0], ph[1], ph[2], ph[3]);
    *(uint4*)&vTh[tid * 40 + 8]  = make_uint4(ph[4], ph[5], ph[6], ph[7]);
    *(uint4*)&vTh[tid * 40 + 16] = make_uint4(ph[8], ph[9], ph[10], ph[11]);
    *(uint4*)&vTh[tid * 40 + 24] = make_uint4(ph[12], ph[13], ph[14], ph[15]);
    *(uint4*)&vTl[tid * 40 + 0]  = make_uint4(pl[0], pl[1], pl[2], pl[3]);
    *(uint4*)&vTl[tid * 40 + 8]  = make_uint4(pl[4], pl[5], pl[6], pl[7]);
    *(uint4*)&vTl[tid * 40 + 16] = make_uint4(pl[8], pl[9], pl[10], pl[11]);
    *(uint4*)&vTl[tid * 40 + 24] = make_uint4(pl[12], pl[13], pl[14], pl[15]);
  }
  __syncthreads();

  // ---- (I+A)^-1: column-parallel forward substitution ----
  if (tid < CH) {
    int j = tid;
    for (int i = 0; i < CH; i++) {
      if (i < j) { Xs[i][j] = 0.f; continue; }
      float x = (i == j) ? 1.f : 0.f;
      for (int m = j; m < i; m++) x -= As[i][m] * Xs[m][j];
      Xs[i][j] = x;
    }
  }
  __syncthreads();

  // ---- X*diag(beta) -> hi/lo bf16 ----
#pragma unroll
  for (int r = 0; r < 4; r++) {
    int oid = tid + 256 * r;
    int i = oid >> 5, m = oid & 31;
    float a2 = Xs[i][m] * bet[m];
    u16 hh = f2b(a2);
    Xh[i][m] = hh;
    Xl[i][m] = f2b(a2 - b2f(hh));
  }
  __syncthreads();

  // ---- phase 6: u = (Xh+Xl)@(vh+vl), w = (Xh+Xl)@kh via MFMA ----
  {
    const int w = tid >> 6, l = tid & 63;
    const int v = l & 15, hi = l >> 4;
    const int ti = w >> 1;
    const int tjb = (w & 1) * 8;
    s16x8 xh = *(const s16x8*)&Xh[ti * 16 + v][hi * 8];
    s16x8 xl = *(const s16x8*)&Xl[ti * 16 + v][hi * 8];
#pragma unroll
    for (int tq = 0; tq < 8; tq++) {
      const int d0 = (tjb + tq) * 16;
      s16x8 bvh = *(const s16x8*)&vTh[(d0 + v) * 40 + hi * 8];
      s16x8 bvl = *(const s16x8*)&vTl[(d0 + v) * 40 + hi * 8];
      s16x8 bkh = *(const s16x8*)&kTh[(d0 + v) * 40 + hi * 8];
      f32x4 ua = (f32x4){0.f, 0.f, 0.f, 0.f};
      ua = __builtin_amdgcn_mfma_f32_16x16x32_bf16(xh, bvh, ua, 0, 0, 0);
      ua = __builtin_amdgcn_mfma_f32_16x16x32_bf16(xh, bvl, ua, 0, 0, 0);
      ua = __builtin_amdgcn_mfma_f32_16x16x32_bf16(xl, bvh, ua, 0, 0, 0);
      f32x4 wa = (f32x4){0.f, 0.f, 0.f, 0.f};
      wa = __builtin_amdgcn_mfma_f32_16x16x32_bf16(xh, bkh, wa, 0, 0, 0);
      wa = __builtin_amdgcn_mfma_f32_16x16x32_bf16(xl, bkh, wa, 0, 0, 0);
#pragma unroll
      for (int r = 0; r < 4; r++) {
        int c = ti * 16 + hi * 4 + r;
        ub[cbase + (long)c * D_ + d0 + v] = ua[r];
        wb[cbase + (long)c * D_ + d0 + v] = f2b(wa[r]);
      }
    }
  }
}

// ---------------------------------------------------------------------------
// D-layout (two 16x16 f32 tiles) -> hi/lo bf16 B-operand fragments.
// Tile select AFTER the shuffle (R5 lesson).
// ---------------------------------------------------------------------------
__device__ __forceinline__ void d2b2(f32x4 Ta, f32x4 Tb, int v, int hi,
                                     s16x8* hiF, s16x8* loF)
{
  const bool tb = (hi >> 1) != 0;
  const int base = v + ((hi & 1) << 5);
  float y[8];
#pragma unroll
  for (int r = 0; r < 4; r++) {
    float a0 = __shfl(Ta[r], base);
    float b0 = __shfl(Tb[r], base);
    float a1 = __shfl(Ta[r], base + 16);
    float b1 = __shfl(Tb[r], base + 16);
    y[r] = tb ? b0 : a0;
    y[4 + r] = tb ? b1 : a1;
  }
  u32 h0 = pkbf(y[0], y[1]), h1 = pkbf(y[2], y[3]);
  u32 h2 = pkbf(y[4], y[5]), h3 = pkbf(y[6], y[7]);
  u32 l0 = pkbf(y[0] - blo(h0), y[1] - bhi(h0));
  u32 l1 = pkbf(y[2] - blo(h1), y[3] - bhi(h1));
  u32 l2 = pkbf(y[4] - blo(h2), y[5] - bhi(h2));
  u32 l3 = pkbf(y[6] - blo(h3), y[7] - bhi(h3));
  U4S8 xh; xh.u = make_uint4(h0, h1, h2, h3);
  U4S8 xl; xl.u = make_uint4(l0, l1, l2, l3);
  *hiF = xh.s; *loF = xl.s;
}

// ---------------------------------------------------------------------------
// Delta-rule scan v7 (unchanged from R7): software-pipelined MFMA scan.
// ---------------------------------------------------------------------------
__global__ __launch_bounds__(64, 1)
void delta_scan(const u16* __restrict__ qn, const u16* __restrict__ ktb,
                const float* __restrict__ ub, const u16* __restrict__ wb,
                const u16* __restrict__ attnb, const u16* __restrict__ attnlo,
                float* __restrict__ dout)
{
  const int bid = blockIdx.x;
  const int sl = bid & 15, h = (bid >> 4) & 3, b = bid >> 6;
  const int l = threadIdx.x;
  const int v = l & 15, hi = l >> 4;
  const int dv0 = sl * 16;
  const long bh = (long)(b * H_ + h);

  f32x4 St[16];
#pragma unroll
  for (int t = 0; t < 16; t++) St[t] = (f32x4){0.f, 0.f, 0.f, 0.f};

  uint4 WfA[2][8], QfA[2][8], WfB[2][8], QfB[2][8];
  uint4 KTf[16], ATh[2], ATl[2];
  float Uld[2][4];

  auto loadWQ = [&](uint4 (&W)[2][8], uint4 (&Q)[2][8], int ci) {
    const long cb = (bh * NCH + ci) * (CH * D_);
#pragma unroll
    for (int mt = 0; mt < 2; mt++)
#pragma unroll
      for (int kt = 0; kt < 8; kt++) {
        const long ro = cb + (long)(mt * 16 + v) * D_ + kt * 32 + hi * 8;
        W[mt][kt] = *(const uint4*)(wb + ro);
        Q[mt][kt] = *(const uint4*)(qn + ro);
      }
  };
  auto loadKT = [&](int ci) {
    const long kb = (bh * NCH + ci) * (D_ * CH);
#pragma unroll
    for (int t = 0; t < 16; t++)
      KTf[t] = *(const uint4*)(ktb + kb + (long)(t * 16 + v) * CH + hi * 8);
  };
  auto loadATU = [&](int ci) {
    const long ab = (bh * NCH + ci) * (CH * CH);
    const long cb = (bh * NCH + ci) * (CH * D_);
#pragma unroll
    for (int mt = 0; mt < 2; mt++) {
      ATh[mt] = *(const uint4*)(attnb + ab + (long)(mt * 16 + v) * CH + hi * 8);
      ATl[mt] = *(const uint4*)(attnlo + ab + (long)(mt * 16 + v) * CH + hi * 8);
    }
#pragma unroll
    for (int mt = 0; mt < 2; mt++)
#pragma unroll
      for (int r = 0; r < 4; r++)
        Uld[mt][r] = ub[cb + (long)(mt * 16 + hi * 4 + r) * D_ + dv0 + v];
  };

  auto step = [&](uint4 (&CW)[2][8], uint4 (&CQ)[2][8],
                  uint4 (&NW)[2][8], uint4 (&NQ)[2][8], int ci) {
    loadWQ(NW, NQ, ci + 1);

    f32x4 awt[2], aqt[2];
#pragma unroll
    for (int mt = 0; mt < 2; mt++) { awt[mt] = (f32x4){0.f,0.f,0.f,0.f}; aqt[mt] = (f32x4){0.f,0.f,0.f,0.f}; }
#pragma unroll
    for (int kt = 0; kt < 8; kt++) {
      s16x8 sh_, sl_;
      d2b2(St[2 * kt], St[2 * kt + 1], v, hi, &sh_, &sl_);
#pragma unroll
      for (int mt = 0; mt < 2; mt++) {
        awt[mt] = __builtin_amdgcn_mfma_f32_16x16x32_bf16(as_s16x8(CW[mt][kt]), sh_, awt[mt], 0, 0, 0);
        awt[mt] = __builtin_amdgcn_mfma_f32_16x16x32_bf16(as_s16x8(CW[mt][kt]), sl_, awt[mt], 0, 0, 0);
        aqt[mt] = __builtin_amdgcn_mfma_f32_16x16x32_bf16(as_s16x8(CQ[mt][kt]), sh_, aqt[mt], 0, 0, 0);
        aqt[mt] = __builtin_amdgcn_mfma_f32_16x16x32_bf16(as_s16x8(CQ[mt][kt]), sl_, aqt[mt], 0, 0, 0);
      }
    }

    f32x4 ua0, ua1;
#pragma unroll
    for (int r = 0; r < 4; r++) { ua0[r] = Uld[0][r] - awt[0][r]; ua1[r] = Uld[1][r] - awt[1][r]; }
    s16x8 UAh, UAl;
    d2b2(ua0, ua1, v, hi, &UAh, &UAl);

    f32x4 ot[2];
#pragma unroll
    for (int mt = 0; mt < 2; mt++) {
      ot[mt] = __builtin_amdgcn_mfma_f32_16x16x32_bf16(as_s16x8(ATh[mt]), UAh, aqt[mt], 0, 0, 0);
      ot[mt] = __builtin_amdgcn_mfma_f32_16x16x32_bf16(as_s16x8(ATh[mt]), UAl, ot[mt], 0, 0, 0);
      ot[mt] = __builtin_amdgcn_mfma_f32_16x16x32_bf16(as_s16x8(ATl[mt]), UAh, ot[mt], 0, 0, 0);
    }
#pragma unroll
    for (int mt = 0; mt < 2; mt++)
#pragma unroll
      for (int r = 0; r < 4; r++)
        dout[((long)b * L_ + ci * CH + mt * 16 + hi * 4 + r) * HID_ + h * D_ + dv0 + v] = ot[mt][r];

    loadATU(ci + 1);

#pragma unroll
    for (int t = 0; t < 16; t++) {
      St[t] = __builtin_amdgcn_mfma_f32_16x16x32_bf16(as_s16x8(KTf[t]), UAh, St[t], 0, 0, 0);
      St[t] = __builtin_amdgcn_mfma_f32_16x16x32_bf16(as_s16x8(KTf[t]), UAl, St[t], 0, 0, 0);
    }
    loadKT(ci + 1);
  };

  loadWQ(WfA, QfA, 0);
  loadKT(0);
  loadATU(0);
#pragma unroll 1
  for (int c2 = 0; c2 < NCH / 2; c2++) {
    step(WfA, QfA, WfB, QfB, 2 * c2);
    step(WfB, QfB, WfA, QfA, 2 * c2 + 1);
  }
}

// ---------------------------------------------------------------------------
// Fused 3-FIR depthwise causal conv on v (K=3,31,64). Tile 32 tok x 64 ch.
// ---------------------------------------------------------------------------
__global__ __launch_bounds__(256)
void fir3(const float* __restrict__ v, const float* __restrict__ fs_g,
          const float* __restrict__ fl_g, const float* __restrict__ fw_g,
          float* __restrict__ os, float* __restrict__ ol, float* __restrict__ ow)
{
  __shared__ float xs[95][64];
  __shared__ float fs[64][3];
  __shared__ float fl[64][31];
  __shared__ float fw[64][65];
  int bid = blockIdx.x;
  int ct = bid & 15, lt = bid >> 4;
  int c0 = ct * 64, tok0 = lt * 32;
  int bstart = (tok0 / L_) * L_;
  int tid = threadIdx.x;

  for (int idx = tid; idx < 95 * 64; idx += 256) {
    int r = idx >> 6, cc = idx & 63;
    int tok = tok0 - 63 + r;
    xs[r][cc] = (tok >= bstart) ? v[(long)tok * HID_ + c0 + cc] : 0.f;
  }
  for (int idx = tid; idx < 64 * 3; idx += 256) fs[idx / 3][idx % 3] = fs_g[(long)(c0 + idx / 3) * 3 + idx % 3];
  for (int idx = tid; idx < 64 * 31; idx += 256) fl[idx / 31][idx % 31] = fl_g[(long)(c0 + idx / 31) * 31 + idx % 31];
  for (int idx = tid; idx < 64 * 64; idx += 256) fw[idx >> 6][idx & 63] = fw_g[(long)(c0 + (idx >> 6)) * 64 + (idx & 63)];
  __syncthreads();

  int cc = tid & 63, lq = tid >> 6;
  int rb = lq * 8;
  float as8[8] = {0}, al8[8] = {0}, aw8[8] = {0};
#pragma unroll 1
  for (int t = 0; t < 64; t++) {
    float fv = fw[cc][t];
#pragma unroll
    for (int i = 0; i < 8; i++) aw8[i] = fmaf(xs[rb + i + t][cc], fv, aw8[i]);
  }
#pragma unroll 1
  for (int t = 0; t < 31; t++) {
    float fv = fl[cc][t];
#pragma unroll
    for (int i = 0; i < 8; i++) al8[i] = fmaf(xs[rb + 33 + i + t][cc], fv, al8[i]);
  }
#pragma unroll 1
  for (int t = 0; t < 3; t++) {
    float fv = fs[cc][t];
#pragma unroll
    for (int i = 0; i < 8; i++) as8[i] = fmaf(xs[rb + 61 + i + t][cc], fv, as8[i]);
  }
#pragma unroll
  for (int i = 0; i < 8; i++) {
    long o = (long)(tok0 + lq * 8 + i) * HID_ + c0 + cc;
    os[o] = as8[i]; ol[o] = al8[i]; ow[o] = aw8[i];
  }
}

// ---------------------------------------------------------------------------
// gate_in (bf16) = [hs | stats x5], row stride 1088 (cols 1084..1087 zero)
// ---------------------------------------------------------------------------
__global__ __launch_bounds__(256)
void build_gate(const float* __restrict__ hs, const float* __restrict__ sb,
                const float* __restrict__ lb, const float* __restrict__ wbb,
                const float* __restrict__ db, const float* __restrict__ vb,
                u16* __restrict__ gate)
{
  int tok = blockIdx.x;
  int tid = threadIdx.x;
  u16* g = gate + (long)tok * 1088;
  const float* hrow = hs + (long)tok * HID_;
#pragma unroll
  for (int i = 0; i < 4; i++) g[tid + 256 * i] = f2b(hrow[tid + 256 * i]);
  if (tid < 4) g[1084 + tid] = 0;
  int h = tid >> 6, ln = tid & 63;
  const float* brs[5] = {sb, lb, wbb, db, vb};
#pragma unroll
  for (int bi = 0; bi < 5; bi++) {
    const float* x = brs[bi] + (long)tok * HID_ + h * D_;
    float s = 0.f, ss = 0.f, mx = 0.f;
#pragma unroll
    for (int i = 0; i < 4; i++) {
      float v = x[ln + 64 * i];
      s += v; ss += v * v; mx = fmaxf(mx, fabsf(v));
    }
#pragma unroll
    for (int off = 32; off >= 1; off >>= 1) {
      s += __shfl_xor(s, off);
      ss += __shfl_xor(ss, off);
      mx = fmaxf(mx, __shfl_xor(mx, off));
    }
    if (ln == 0) {
      g[1024 + bi * 12 + h] = f2b(s * (1.f / 256.f));
      g[1024 + bi * 12 + 4 + h] = f2b(sqrtf(fmaxf(ss * (1.f / 256.f), 1e-8f)));
      g[1024 + bi * 12 + 8 + h] = f2b(mx);
    }
  }
}

// ---------------------------------------------------------------------------
// Fused g2 (4096x20x2048) + softmax/temperature/floor mix + per-head RMSNorm
// ---------------------------------------------------------------------------
__global__ __launch_bounds__(256)
void g2_mix(const float* __restrict__ hdn, const float* __restrict__ g2w,
            const float* __restrict__ g2b, const float* __restrict__ vbias,
            const float* __restrict__ ltemp, const float* __restrict__ flog,
            const float* __restrict__ onw,
            const float* __restrict__ sb, const float* __restrict__ lb,
            const float* __restrict__ wbb, const float* __restrict__ db,
            const float* __restrict__ vb, u16* __restrict__ omix)
{
  __shared__ float hrow[2048];
  __shared__ float lg[20];
  int tok = blockIdx.x;
  int tid = threadIdx.x;
  const float* hp = hdn + (long)tok * 2048;
#pragma unroll
  for (int i = 0; i < 8; i++) hrow[tid + 256 * i] = hp[tid + 256 * i];
  __syncthreads();
  int w = tid >> 6, ln = tid & 63;
#pragma unroll 1
  for (int q = 0; q < 5; q++) {
    int jj = w * 5 + q;
    const float* wr = g2w + (long)jj * 2048;
    float s = 0.f;
    for (int i = 0; i < 32; i++) s += hrow[ln + 64 * i] * wr[ln + 64 * i];
#pragma unroll
    for (int off = 32; off >= 1; off >>= 1) s += __shfl_xor(s, off);
    if (ln == 0) lg[jj] = s + g2b[jj];
  }
  __syncthreads();
  int h = w;
  float l[5];
#pragma unroll
  for (int j = 0; j < 5; j++) l[j] = lg[h * 5 + j];
  l[4] += vbias[h];
  float it = expf(-ltemp[h]);
#pragma unroll
  for (int j = 0; j < 5; j++) l[j] *= it;
  float mx = fmaxf(fmaxf(fmaxf(l[0], l[1]), fmaxf(l[2], l[3])), l[4]);
  float e[5], se = 0.f;
#pragma unroll
  for (int j = 0; j < 5; j++) { e[j] = expf(l[j] - mx); se += e[j]; }
  float inv = 1.f / se;
  float f = 1.f / (1.f + expf(-flog[h]));
  float sc = 1.f - 4.f * f;
  float wt[5];
#pragma unroll
  for (int j = 0; j < 4; j++) wt[j] = f + sc * e[j] * inv;
  wt[4] = sc * e[4] * inv;

  long base = (long)tok * HID_ + h * D_;
  float o[4], ss = 0.f;
#pragma unroll
  for (int i = 0; i < 4; i++) {
    int d = ln + 64 * i;
    o[i] = wt[0] * sb[base + d] + wt[1] * lb[base + d] + wt[2] * wbb[base + d]
         + wt[3] * db[base + d] + wt[4] * vb[base + d];
    ss += o[i] * o[i];
  }
#pragma unroll
  for (int off = 32; off >= 1; off >>= 1) ss += __shfl_xor(ss, off);
  float r = rsqrtf(ss * (1.f / 256.f) + 1e-5f);
#pragma unroll
  for (int i = 0; i < 4; i++) {
    int d = ln + 64 * i;
    omix[base + d] = f2b(o[i] * r * onw[d]);
  }
}

// ---------------------------------------------------------------------------
extern "C" void kernel_launch(void* const* d_in, const int* in_sizes, int n_in,
                              void* d_out, int out_size, void* d_ws, size_t ws_size,
                              hipStream_t stream)
{
  const float* hs    = (const float*)d_in[0];
  const float* q_w   = (const float*)d_in[1];
  const float* k_w   = (const float*)d_in[2];
  const float* v_w   = (const float*)d_in[3];
  const float* b_w   = (const float*)d_in[4];
  const float* convq = (const float*)d_in[5];
  const float* convk = (const float*)d_in[6];
  const float* convv = (const float*)d_in[7];
  const float* fir_s = (const float*)d_in[8];
  const float* fir_l = (const float*)d_in[9];
  const float* fir_w = (const float*)d_in[10];
  const float* g1w   = (const float*)d_in[11];
  const float* g1b   = (const float*)d_in[12];
  const float* g2w   = (const float*)d_in[13];
  const float* g2b   = (const float*)d_in[14];
  const float* vbias = (const float*)d_in[15];
  const float* ltemp = (const float*)d_in[16];
  const float* flog  = (const float*)d_in[17];
  const float* onw   = (const float*)d_in[18];
  const float* o_w   = (const float*)d_in[19];

  float* ws = (float*)d_ws;
  const long S1 = (long)NTOK * HID_;
  float* qkv3   = ws + 0 * S1;
  float* qcv    = ws + 3 * S1;
  float* kcv    = ws + 4 * S1;
  float* vcv    = ws + 5 * S1;
  float* ubb    = ws + 6 * S1;
  float* deltab = ws + 7 * S1;
  u16*   qn_bf  = (u16*)(ws + 8 * S1);
  u16*   kt_bf  = (u16*)(ws + 8 * S1 + S1 / 2);
  u16*   wb_bf  = (u16*)(ws + 9 * S1);
  u16*   attn_bf = (u16*)(ws + 9 * S1 + S1 / 2);
  float* betab  = (float*)(attn_bf + (long)B_ * H_ * NCH * CH * CH);
  u16*   attn_lo = (u16*)(betab + 16384);
  u16*   hs_bf  = (u16*)(ws + 10 * S1);
  u16*   qw_bf  = (u16*)(ws + 10 * S1 + S1 / 2);
  u16*   ow_bf  = qw_bf + 3 * (S1 / 4);
  u16*   g1w_bf = ow_bf + S1 / 4;
  float* firs = ws + 0 * S1;
  float* firl = ws + 1 * S1;
  float* firw = ws + 2 * S1;
  u16*   gate_bf = (u16*)qcv;
  u16*   omix_bf = (u16*)kcv;
  float* hdnb    = ws + 8 * S1;
  (void)in_sizes; (void)n_in; (void)out_size; (void)ws_size;

  dim3 blk(256);
  cast5<<<(NTOK * HID_ + 4 * HID_ * HID_) / 1024, blk, 0, stream>>>(hs, q_w, k_w, v_w, o_w, hs_bf);
  pad_g1w<<<2048 * 1088 / 256, blk, 0, stream>>>(g1w, g1w_bf);
  gemm_bf16<0><<<dim3(24, 32), blk, 0, stream>>>(hs_bf, qw_bf, nullptr, qkv3, NTOK, 3072, HID_);
  conv4_silu3<<<(NTOK * 3072) / 256, blk, 0, stream>>>(qkv3, convq, convk, convv, qcv, kcv, vcv);
  beta_proj<<<NTOK * H_ / 256, blk, 0, stream>>>(hs, b_w, betab);
  delta_prep<<<B_ * H_ * NCH, blk, 0, stream>>>(qcv, kcv, vcv, betab, qn_bf, kt_bf, ubb, wb_bf, attn_bf, attn_lo);
  delta_scan<<<B_ * H_ * 16, dim3(64), 0, stream>>>(qn_bf, kt_bf, ubb, wb_bf, attn_bf, attn_lo, deltab);
  fir3<<<(NTOK / 32) * (HID_ / 64), blk, 0, stream>>>(vcv, fir_s, fir_l, fir_w, firs, firl, firw);
  build_gate<<<NTOK, blk, 0, stream>>>(hs, firs, firl, firw, deltab, vcv, gate_bf);
  gemm_bf16<1><<<dim3(16, 32), blk, 0, stream>>>(gate_bf, g1w_bf, g1b, hdnb, NTOK, 2048, 1088);
  g2_mix<<<NTOK, blk, 0, stream>>>(hdnb, g2w, g2b, vbias, ltemp, flog, onw,
                                   firs, firl, firw, deltab, vcv, omix_bf);
  gemm_bf16<0><<<dim3(8, 32), blk, 0, stream>>>(omix_bf, ow_bf, nullptr, (float*)d_out, NTOK, HID_, HID_);
}